// Round 1
// baseline (2630.908 us; speedup 1.0000x reference)
//
#include <hip/hip_runtime.h>

#define NN 50000
#define NE 800000
#define FIN 128
#define EDIM 16
#define EMB 64
#define NH 2
#define NLAYERS 3
#define NG 64
#define HCC 128
#define INV_SQRT_D 0.125f
#define EPS_BN 1e-5f

__device__ __forceinline__ unsigned encf(float f){
  unsigned u = __float_as_uint(f);
  return (u & 0x80000000u) ? ~u : (u | 0x80000000u);
}
__device__ __forceinline__ float decf(unsigned e){
  unsigned u = (e & 0x80000000u) ? (e ^ 0x80000000u) : ~e;
  return __uint_as_float(u);
}

__global__ void hist_k(const int* __restrict__ dst, int* __restrict__ deg){
  int i = blockIdx.x * 256 + threadIdx.x;
  if (i < NE) atomicAdd(&deg[dst[i]], 1);
}

__global__ void counts_k(const int* __restrict__ batch, int* __restrict__ counts){
  int i = blockIdx.x * 256 + threadIdx.x;
  if (i < NN) atomicAdd(&counts[batch[i]], 1);
}

__global__ void scan_k(const int* __restrict__ deg, int* __restrict__ row_ptr){
  __shared__ int lds[1024];
  __shared__ int carry;
  int t = threadIdx.x;
  if (t == 0) carry = 0;
  __syncthreads();
  for (int base = 0; base < NN + 1; base += 1024){
    int idx = base + t;
    int v = (idx < NN) ? deg[idx] : 0;
    int x = v;
    lds[t] = x;
    __syncthreads();
    for (int off = 1; off < 1024; off <<= 1){
      int y = (t >= off) ? lds[t - off] : 0;
      __syncthreads();
      x += y;
      lds[t] = x;
      __syncthreads();
    }
    if (idx <= NN) row_ptr[idx] = carry + x - v;
    int tot = lds[1023];
    __syncthreads();
    if (t == 0) carry += tot;
    __syncthreads();
  }
}

__global__ void cursor_k(const int* __restrict__ row_ptr, int* __restrict__ cur){
  int i = blockIdx.x * 256 + threadIdx.x;
  if (i < NN) cur[i] = row_ptr[i];
}

__global__ void scatter_k(const int* __restrict__ dst, int* __restrict__ cur, int* __restrict__ eid){
  int i = blockIdx.x * 256 + threadIdx.x;
  if (i < NE){
    int p = atomicAdd(&cur[dst[i]], 1);
    eid[p] = i;
  }
}

__global__ void pack_k(const float* __restrict__ qw, const float* __restrict__ kw,
                       const float* __restrict__ vw, const float* __restrict__ skw,
                       const float* __restrict__ qb, const float* __restrict__ kb,
                       const float* __restrict__ vb, const float* __restrict__ skb,
                       float* __restrict__ Wp, float* __restrict__ bp, int D){
  int i = blockIdx.x * 256 + threadIdx.x;
  if (i < 512 * D){
    int c = i / D, d = i - c * D;
    const float* w = (c < 128) ? qw : (c < 256) ? kw : (c < 384) ? vw : skw;
    Wp[i] = w[(c & 127) * D + d];
  }
  if (i < 512){
    const float* b = (i < 128) ? qb : (i < 256) ? kb : (i < 384) ? vb : skb;
    bp[i] = b[i & 127];
  }
}

// C[N,512] = A[N,D] @ Wp[512,D]^T + bp ; 64x64 tile, K staged by 64
template<int D>
__global__ __launch_bounds__(256) void gemm_k(const float* __restrict__ A,
                                              const float* __restrict__ W,
                                              const float* __restrict__ bp,
                                              float* __restrict__ C){
  __shared__ float As[64][65];
  __shared__ float Ws[64][65];
  int t = threadIdx.x;
  int tx = t & 15, ty = t >> 4;
  int brow = blockIdx.x * 64;
  int bcol = blockIdx.y * 64;
  float acc[4][4];
  #pragma unroll
  for (int i = 0; i < 4; i++)
    #pragma unroll
    for (int j = 0; j < 4; j++) acc[i][j] = 0.f;

  for (int kb = 0; kb < D; kb += 64){
    #pragma unroll
    for (int it = 0; it < 4; it++){
      int r = (t >> 4) + it * 16;     // 0..63
      int c4 = (t & 15) * 4;          // 0..60
      int gr = brow + r;
      float4 va = make_float4(0.f, 0.f, 0.f, 0.f);
      if (gr < NN) va = *(const float4*)(A + (size_t)gr * D + kb + c4);
      As[r][c4 + 0] = va.x; As[r][c4 + 1] = va.y; As[r][c4 + 2] = va.z; As[r][c4 + 3] = va.w;
      int wc = bcol + r;
      float4 vw = *(const float4*)(W + (size_t)wc * D + kb + c4);
      Ws[r][c4 + 0] = vw.x; Ws[r][c4 + 1] = vw.y; Ws[r][c4 + 2] = vw.z; Ws[r][c4 + 3] = vw.w;
    }
    __syncthreads();
    #pragma unroll 8
    for (int k = 0; k < 64; k++){
      float a0 = As[ty * 4 + 0][k], a1 = As[ty * 4 + 1][k];
      float a2 = As[ty * 4 + 2][k], a3 = As[ty * 4 + 3][k];
      float w0 = Ws[tx * 4 + 0][k], w1 = Ws[tx * 4 + 1][k];
      float w2 = Ws[tx * 4 + 2][k], w3 = Ws[tx * 4 + 3][k];
      acc[0][0] += a0 * w0; acc[0][1] += a0 * w1; acc[0][2] += a0 * w2; acc[0][3] += a0 * w3;
      acc[1][0] += a1 * w0; acc[1][1] += a1 * w1; acc[1][2] += a1 * w2; acc[1][3] += a1 * w3;
      acc[2][0] += a2 * w0; acc[2][1] += a2 * w1; acc[2][2] += a2 * w2; acc[2][3] += a2 * w3;
      acc[3][0] += a3 * w0; acc[3][1] += a3 * w1; acc[3][2] += a3 * w2; acc[3][3] += a3 * w3;
    }
    __syncthreads();
  }
  #pragma unroll
  for (int i = 0; i < 4; i++){
    int gr = brow + ty * 4 + i;
    if (gr < NN){
      #pragma unroll
      for (int j = 0; j < 4; j++){
        int gc = bcol + tx * 4 + j;
        C[(size_t)gr * 512 + gc] = acc[i][j] + bp[gc];
      }
    }
  }
}

// One wave per node: lane = channel c (head0 uses c, head1 uses 64+c).
// qkvs layout per node: [0:128)=q, [128:256)=k, [256:384)=v, [384:512)=skip
__global__ __launch_bounds__(256) void edge_k(const float* __restrict__ qkvs,
    const float* __restrict__ ea, const float* __restrict__ ew,
    const int* __restrict__ row_ptr, const int* __restrict__ eid,
    const int* __restrict__ srcs, float* __restrict__ attn){
  int wid = (blockIdx.x * 256 + threadIdx.x) >> 6;
  int lane = threadIdx.x & 63;
  if (wid >= NN) return;
  float ew0[16], ew1[16];
  #pragma unroll
  for (int d = 0; d < 16; d += 4){
    float4 a = *(const float4*)(ew + lane * 16 + d);
    ew0[d] = a.x; ew0[d + 1] = a.y; ew0[d + 2] = a.z; ew0[d + 3] = a.w;
    float4 b = *(const float4*)(ew + (lane + 64) * 16 + d);
    ew1[d] = b.x; ew1[d + 1] = b.y; ew1[d + 2] = b.z; ew1[d + 3] = b.w;
  }
  float q0 = qkvs[(size_t)wid * 512 + lane];
  float q1 = qkvs[(size_t)wid * 512 + 64 + lane];
  float acc0 = 0.f, acc1 = 0.f, den0 = 0.f, den1 = 0.f;
  int beg = row_ptr[wid], end = row_ptr[wid + 1];
  for (int i = beg; i < end; i++){
    int e = eid[i];
    int s = srcs[e];
    const float* eap = ea + (size_t)e * 16;
    float e0 = 0.f, e1 = 0.f;
    #pragma unroll
    for (int d = 0; d < 16; d += 4){
      float4 a = *(const float4*)(eap + d);
      e0 += a.x * ew0[d] + a.y * ew0[d + 1] + a.z * ew0[d + 2] + a.w * ew0[d + 3];
      e1 += a.x * ew1[d] + a.y * ew1[d + 1] + a.z * ew1[d + 2] + a.w * ew1[d + 3];
    }
    const float* base = qkvs + (size_t)s * 512;
    float k0 = base[128 + lane], k1 = base[192 + lane];
    float v0 = base[256 + lane], v1 = base[320 + lane];
    float p0 = q0 * (k0 + e0), p1 = q1 * (k1 + e1);
    #pragma unroll
    for (int off = 32; off >= 1; off >>= 1){
      p0 += __shfl_xor(p0, off);
      p1 += __shfl_xor(p1, off);
    }
    float w0 = __expf(p0 * INV_SQRT_D);
    float w1 = __expf(p1 * INV_SQRT_D);
    acc0 += (v0 + e0) * w0;
    acc1 += (v1 + e1) * w1;
    den0 += w0; den1 += w1;
  }
  attn[(size_t)wid * 128 + lane]      = den0 > 0.f ? acc0 / den0 : 0.f;
  attn[(size_t)wid * 128 + 64 + lane] = den1 > 0.f ? acc1 / den1 : 0.f;
}

// beta-gate combine + [128->64] proj + leaky relu + BN partial sums.
// 4 waves/block, 4 nodes per wave.
__global__ __launch_bounds__(256) void combine_k(const float* __restrict__ attn,
    const float* __restrict__ qkvs, const float* __restrict__ bw,
    const float* __restrict__ tw, const float* __restrict__ tb,
    float* __restrict__ h2, float* __restrict__ bn_acc){
  __shared__ float twT[128][65];   // twT[k][j] = tw[j][k]
  __shared__ float hcs[4][128];
  __shared__ float bsum[64], bsq[64];
  int t = threadIdx.x;
  int lane = t & 63, wv = t >> 6;
  for (int i = t; i < 64 * 128; i += 256){
    int j = i >> 7, k = i & 127;
    twT[k][j] = tw[i];
  }
  if (t < 64){ bsum[t] = 0.f; bsq[t] = 0.f; }
  __syncthreads();
  float bw0 = bw[lane],       bw1 = bw[64 + lane];
  float bwr0 = bw[128 + lane], bwr1 = bw[192 + lane];
  float bwd0 = bw[256 + lane], bwd1 = bw[320 + lane];
  float tbv = tb[lane];
  float rs = 0.f, rq = 0.f;
  int base_node = blockIdx.x * 16 + wv * 4;
  for (int it = 0; it < 4; it++){
    int n = base_node + it;
    bool valid = n < NN;
    float o0 = 0.f, o1 = 0.f, r0 = 0.f, r1 = 0.f;
    if (valid){
      o0 = attn[(size_t)n * 128 + lane];
      o1 = attn[(size_t)n * 128 + 64 + lane];
      r0 = qkvs[(size_t)n * 512 + 384 + lane];
      r1 = qkvs[(size_t)n * 512 + 448 + lane];
    }
    float p = o0 * bw0 + o1 * bw1 + r0 * bwr0 + r1 * bwr1 + (o0 - r0) * bwd0 + (o1 - r1) * bwd1;
    #pragma unroll
    for (int off = 32; off >= 1; off >>= 1) p += __shfl_xor(p, off);
    float beta = 1.f / (1.f + __expf(-p));
    float hc0 = beta * r0 + (1.f - beta) * o0;
    float hc1 = beta * r1 + (1.f - beta) * o1;
    hcs[wv][lane] = hc0;
    hcs[wv][64 + lane] = hc1;
    __syncthreads();
    float s = tbv;
    #pragma unroll 8
    for (int k = 0; k < 128; k++) s += hcs[wv][k] * twT[k][lane];
    __syncthreads();
    if (valid){
      float hv = s > 0.f ? s : 0.01f * s;
      h2[(size_t)n * 64 + lane] = hv;
      rs += hv; rq += hv * hv;
    }
  }
  atomicAdd(&bsum[lane], rs);
  atomicAdd(&bsq[lane], rq);
  __syncthreads();
  if (t < 64){
    atomicAdd(&bn_acc[t], bsum[t]);
    atomicAdd(&bn_acc[64 + t], bsq[t]);
  }
}

__global__ void bn_final_k(const float* __restrict__ bn_acc, const float* __restrict__ bnw,
                           const float* __restrict__ bnb, float* __restrict__ ss){
  int j = threadIdx.x;
  if (j < 64){
    float m = bn_acc[j] / (float)NN;
    float v = bn_acc[64 + j] / (float)NN - m * m;
    float sc = bnw[j] * rsqrtf(v + EPS_BN);
    ss[j] = sc;
    ss[64 + j] = bnb[j] - m * sc;
  }
}

// BN apply + (inner layers) pooled max/sum accumulation exploiting sorted batch_index
__global__ __launch_bounds__(256) void bn_apply_k(const float* __restrict__ h2,
    const float* __restrict__ ss, const int* __restrict__ batch,
    float* __restrict__ h, float* __restrict__ gsum, unsigned* __restrict__ gmax,
    int do_pool){
  int wid = (blockIdx.x * 256 + threadIdx.x) >> 6;
  int lane = threadIdx.x & 63;
  const int CH = (NN + 1023) / 1024;
  int start = wid * CH;
  int end = start + CH; if (end > NN) end = NN;
  float sc = ss[lane], sh = ss[64 + lane];
  int curg = -1; float lmax = 0.f, lsum = 0.f;
  for (int n = start; n < end; n++){
    float v = h2[(size_t)n * 64 + lane] * sc + sh;
    h[(size_t)n * 64 + lane] = v;
    if (do_pool){
      int g = batch[n];
      if (g != curg){
        if (curg >= 0){
          atomicAdd(&gsum[curg * 64 + lane], lsum);
          atomicMax(&gmax[curg * 64 + lane], encf(lmax));
        }
        curg = g; lmax = v; lsum = v;
      } else {
        lmax = fmaxf(lmax, v); lsum += v;
      }
    }
  }
  if (do_pool && curg >= 0){
    atomicAdd(&gsum[curg * 64 + lane], lsum);
    atomicMax(&gmax[curg * 64 + lane], encf(lmax));
  }
}

__global__ void pool_final_k(const float* __restrict__ gsum, const unsigned* __restrict__ gmax,
                             const int* __restrict__ counts, float* __restrict__ gr){
  int i = blockIdx.x * 256 + threadIdx.x;
  if (i < NG * 64){
    int g = i >> 6, j = i & 63;
    unsigned e = gmax[i];
    float mx = e ? decf(e) : 0.f;
    int c = counts[g]; if (c < 1) c = 1;
    gr[g * 128 + j]       += mx;
    gr[g * 128 + 64 + j]  += gsum[i] / (float)c;
  }
}

extern "C" void kernel_launch(void* const* d_in, const int* in_sizes, int n_in,
                              void* d_out, int out_size, void* d_ws, size_t ws_size,
                              hipStream_t stream){
  const float* x     = (const float*)d_in[0];
  const float* ea    = (const float*)d_in[1];
  const int*   eidx  = (const int*)d_in[2];
  const int*   batch = (const int*)d_in[3];
  const float* c1_qw = (const float*)d_in[4];
  const float* c1_qb = (const float*)d_in[5];
  const float* c1_kw = (const float*)d_in[6];
  const float* c1_kb = (const float*)d_in[7];
  const float* c1_vw = (const float*)d_in[8];
  const float* c1_vb = (const float*)d_in[9];
  const float* c1_ew = (const float*)d_in[10];
  const float* c1_skw= (const float*)d_in[11];
  const float* c1_skb= (const float*)d_in[12];
  const float* c1_bw = (const float*)d_in[13];
  const float* c1_tw = (const float*)d_in[14];
  const float* c1_tb = (const float*)d_in[15];
  const float* c1_bnw= (const float*)d_in[16];
  const float* c1_bnb= (const float*)d_in[17];
  const float* L_qw  = (const float*)d_in[18];
  const float* L_qb  = (const float*)d_in[19];
  const float* L_kw  = (const float*)d_in[20];
  const float* L_kb  = (const float*)d_in[21];
  const float* L_vw  = (const float*)d_in[22];
  const float* L_vb  = (const float*)d_in[23];
  const float* L_ew  = (const float*)d_in[24];
  const float* L_skw = (const float*)d_in[25];
  const float* L_skb = (const float*)d_in[26];
  const float* L_bw  = (const float*)d_in[27];
  const float* L_tw  = (const float*)d_in[28];
  const float* L_tb  = (const float*)d_in[29];
  const float* L_bnw = (const float*)d_in[30];
  const float* L_bnb = (const float*)d_in[31];
  const int* srcs = eidx;
  const int* dsts = eidx + NE;

  char* p = (char*)d_ws;
  auto carve = [&](size_t bytes) -> void* {
    void* r = (void*)p;
    p += (bytes + 255) & ~(size_t)255;
    return r;
  };
  float*    Wp     = (float*)carve(512 * 128 * sizeof(float));
  float*    bp     = (float*)carve(512 * sizeof(float));
  float*    qkvs   = (float*)carve((size_t)NN * 512 * sizeof(float));
  float*    attn   = (float*)carve((size_t)NN * 128 * sizeof(float));
  float*    h      = (float*)carve((size_t)NN * 64 * sizeof(float));
  float*    h2     = (float*)carve((size_t)NN * 64 * sizeof(float));
  float*    bn_acc = (float*)carve(128 * sizeof(float));
  float*    ss     = (float*)carve(128 * sizeof(float));
  float*    gsum   = (float*)carve((size_t)NG * 64 * sizeof(float));
  unsigned* gmax   = (unsigned*)carve((size_t)NG * 64 * sizeof(unsigned));
  int*      deg    = (int*)carve(NN * sizeof(int));
  int*      row_ptr= (int*)carve((NN + 1) * sizeof(int));
  int*      eid    = (int*)carve((size_t)NE * sizeof(int));
  int*      counts = (int*)carve(NG * sizeof(int));

  hipMemsetAsync(d_out, 0, (size_t)out_size * sizeof(float), stream);
  hipMemsetAsync(deg, 0, NN * sizeof(int), stream);
  hipMemsetAsync(counts, 0, NG * sizeof(int), stream);
  hist_k<<<(NE + 255) / 256, 256, 0, stream>>>(dsts, deg);
  counts_k<<<(NN + 255) / 256, 256, 0, stream>>>(batch, counts);
  scan_k<<<1, 1024, 0, stream>>>(deg, row_ptr);
  cursor_k<<<(NN + 255) / 256, 256, 0, stream>>>(row_ptr, deg);   // reuse deg as cursor
  scatter_k<<<(NE + 255) / 256, 256, 0, stream>>>(dsts, deg, eid);

  const float* hin = x;
  for (int L = 0; L < 4; L++){
    int D = (L == 0) ? FIN : EMB;
    const float *qw,*qb,*kw,*kb,*vw,*vb,*eww,*skw,*skb,*bww,*tw,*tb,*bnw,*bnb;
    if (L == 0){
      qw=c1_qw; qb=c1_qb; kw=c1_kw; kb=c1_kb; vw=c1_vw; vb=c1_vb;
      eww=c1_ew; skw=c1_skw; skb=c1_skb; bww=c1_bw; tw=c1_tw; tb=c1_tb;
      bnw=c1_bnw; bnb=c1_bnb;
    } else {
      int i = L - 1;
      qw = L_qw + (size_t)i * HCC * EMB;  qb = L_qb + (size_t)i * HCC;
      kw = L_kw + (size_t)i * HCC * EMB;  kb = L_kb + (size_t)i * HCC;
      vw = L_vw + (size_t)i * HCC * EMB;  vb = L_vb + (size_t)i * HCC;
      eww= L_ew + (size_t)i * HCC * EDIM;
      skw= L_skw+ (size_t)i * HCC * EMB;  skb= L_skb+ (size_t)i * HCC;
      bww= L_bw + (size_t)i * 3 * HCC;
      tw = L_tw + (size_t)i * EMB * HCC;  tb = L_tb + (size_t)i * EMB;
      bnw= L_bnw+ (size_t)i * EMB;        bnb= L_bnb+ (size_t)i * EMB;
    }
    pack_k<<<(512 * D + 255) / 256, 256, 0, stream>>>(qw, kw, vw, skw, qb, kb, vb, skb, Wp, bp, D);
    dim3 gg((NN + 63) / 64, 8);
    if (D == 128) gemm_k<128><<<gg, 256, 0, stream>>>(hin, Wp, bp, qkvs);
    else          gemm_k<64><<<gg, 256, 0, stream>>>(hin, Wp, bp, qkvs);
    edge_k<<<(NN * 64 + 255) / 256, 256, 0, stream>>>(qkvs, ea, eww, row_ptr, eid, srcs, attn);
    hipMemsetAsync(bn_acc, 0, 128 * sizeof(float), stream);
    combine_k<<<(NN + 15) / 16, 256, 0, stream>>>(attn, qkvs, bww, tw, tb, h2, bn_acc);
    bn_final_k<<<1, 64, 0, stream>>>(bn_acc, bnw, bnb, ss);
    if (L > 0) hipMemsetAsync(gsum, 0, 2 * NG * 64 * sizeof(float), stream);
    bn_apply_k<<<256, 256, 0, stream>>>(h2, ss, batch, h, gsum, gmax, (L > 0) ? 1 : 0);
    if (L > 0) pool_final_k<<<(NG * 64 + 255) / 256, 256, 0, stream>>>(gsum, gmax, counts, (float*)d_out);
    hin = h;
  }
}

// Round 2
// 2559.010 us; speedup vs baseline: 1.0281x; 1.0281x over previous
//
#include <hip/hip_runtime.h>

#define NN 50000
#define NE 800000
#define FIN 128
#define EDIM 16
#define EMB 64
#define NH 2
#define NLAYERS 3
#define NG 64
#define HCC 128
#define INV_SQRT_D 0.125f
#define EPS_BN 1e-5f
#define SCAN_B 196   // ceil(NN/256)

__device__ __forceinline__ unsigned encf(float f){
  unsigned u = __float_as_uint(f);
  return (u & 0x80000000u) ? ~u : (u | 0x80000000u);
}
__device__ __forceinline__ float decf(unsigned e){
  unsigned u = (e & 0x80000000u) ? (e ^ 0x80000000u) : ~e;
  return __uint_as_float(u);
}

__global__ void hist_k(const int* __restrict__ dst, int* __restrict__ deg){
  int i = blockIdx.x * 256 + threadIdx.x;
  if (i < NE) atomicAdd(&deg[dst[i]], 1);
}

__global__ void counts_k(const int* __restrict__ batch, int* __restrict__ counts){
  int i = blockIdx.x * 256 + threadIdx.x;
  if (i < NN) atomicAdd(&counts[batch[i]], 1);
}

__global__ void scan1_k(const int* __restrict__ deg, int* __restrict__ bsums){
  __shared__ int lds[256];
  int b = blockIdx.x, t = threadIdx.x;
  int idx = b * 256 + t;
  lds[t] = (idx < NN) ? deg[idx] : 0;
  __syncthreads();
  for (int off = 128; off >= 1; off >>= 1){
    if (t < off) lds[t] += lds[t + off];
    __syncthreads();
  }
  if (t == 0) bsums[b] = lds[0];
}

__global__ void scan2_k(int* __restrict__ bsums){
  __shared__ int lds[256];
  int t = threadIdx.x;
  int v = (t < SCAN_B) ? bsums[t] : 0;
  int x = v;
  lds[t] = x;
  __syncthreads();
  for (int off = 1; off < 256; off <<= 1){
    int y = (t >= off) ? lds[t - off] : 0;
    __syncthreads();
    x += y;
    lds[t] = x;
    __syncthreads();
  }
  if (t < SCAN_B) bsums[t] = x - v;   // exclusive
}

__global__ void scan3_k(const int* __restrict__ deg, const int* __restrict__ bsums,
                        int* __restrict__ row_ptr){
  __shared__ int lds[256];
  int b = blockIdx.x, t = threadIdx.x;
  int idx = b * 256 + t;
  int v = (idx < NN) ? deg[idx] : 0;
  int x = v;
  lds[t] = x;
  __syncthreads();
  for (int off = 1; off < 256; off <<= 1){
    int y = (t >= off) ? lds[t - off] : 0;
    __syncthreads();
    x += y;
    lds[t] = x;
    __syncthreads();
  }
  if (idx <= NN) row_ptr[idx] = bsums[b] + x - v;
}

__global__ void cursor_k(const int* __restrict__ row_ptr, int* __restrict__ cur){
  int i = blockIdx.x * 256 + threadIdx.x;
  if (i < NN) cur[i] = row_ptr[i];
}

__global__ void scatter_k(const int* __restrict__ dst, const int* __restrict__ src,
                          int* __restrict__ cur, int* __restrict__ eid,
                          int* __restrict__ src_s){
  int i = blockIdx.x * 256 + threadIdx.x;
  if (i < NE){
    int p = atomicAdd(&cur[dst[i]], 1);
    eid[p] = i;
    src_s[p] = src[i];
  }
}

__global__ void pack_k(const float* __restrict__ qw, const float* __restrict__ kw,
                       const float* __restrict__ vw, const float* __restrict__ skw,
                       const float* __restrict__ qb, const float* __restrict__ kb,
                       const float* __restrict__ vb, const float* __restrict__ skb,
                       float* __restrict__ Wp, float* __restrict__ bp, int D){
  int i = blockIdx.x * 256 + threadIdx.x;
  if (i < 512 * D){
    int c = i / D, d = i - c * D;
    const float* w = (c < 128) ? qw : (c < 256) ? kw : (c < 384) ? vw : skw;
    Wp[i] = w[(c & 127) * D + d];
  }
  if (i < 512){
    const float* b = (i < 128) ? qb : (i < 256) ? kb : (i < 384) ? vb : skb;
    bp[i] = b[i & 127];
  }
}

// C[N,512] = A[N,D] @ Wp[512,D]^T + bp ; 64x64 tile, K staged by 64
template<int D>
__global__ __launch_bounds__(256) void gemm_k(const float* __restrict__ A,
                                              const float* __restrict__ W,
                                              const float* __restrict__ bp,
                                              float* __restrict__ C){
  __shared__ float As[64][65];
  __shared__ float Ws[64][65];
  int t = threadIdx.x;
  int tx = t & 15, ty = t >> 4;
  int brow = blockIdx.x * 64;
  int bcol = blockIdx.y * 64;
  float acc[4][4];
  #pragma unroll
  for (int i = 0; i < 4; i++)
    #pragma unroll
    for (int j = 0; j < 4; j++) acc[i][j] = 0.f;

  for (int kb = 0; kb < D; kb += 64){
    #pragma unroll
    for (int it = 0; it < 4; it++){
      int r = (t >> 4) + it * 16;
      int c4 = (t & 15) * 4;
      int gr = brow + r;
      float4 va = make_float4(0.f, 0.f, 0.f, 0.f);
      if (gr < NN) va = *(const float4*)(A + (size_t)gr * D + kb + c4);
      As[r][c4 + 0] = va.x; As[r][c4 + 1] = va.y; As[r][c4 + 2] = va.z; As[r][c4 + 3] = va.w;
      int wc = bcol + r;
      float4 vw = *(const float4*)(W + (size_t)wc * D + kb + c4);
      Ws[r][c4 + 0] = vw.x; Ws[r][c4 + 1] = vw.y; Ws[r][c4 + 2] = vw.z; Ws[r][c4 + 3] = vw.w;
    }
    __syncthreads();
    #pragma unroll 8
    for (int k = 0; k < 64; k++){
      float a0 = As[ty * 4 + 0][k], a1 = As[ty * 4 + 1][k];
      float a2 = As[ty * 4 + 2][k], a3 = As[ty * 4 + 3][k];
      float w0 = Ws[tx * 4 + 0][k], w1 = Ws[tx * 4 + 1][k];
      float w2 = Ws[tx * 4 + 2][k], w3 = Ws[tx * 4 + 3][k];
      acc[0][0] += a0 * w0; acc[0][1] += a0 * w1; acc[0][2] += a0 * w2; acc[0][3] += a0 * w3;
      acc[1][0] += a1 * w0; acc[1][1] += a1 * w1; acc[1][2] += a1 * w2; acc[1][3] += a1 * w3;
      acc[2][0] += a2 * w0; acc[2][1] += a2 * w1; acc[2][2] += a2 * w2; acc[2][3] += a2 * w3;
      acc[3][0] += a3 * w0; acc[3][1] += a3 * w1; acc[3][2] += a3 * w2; acc[3][3] += a3 * w3;
    }
    __syncthreads();
  }
  #pragma unroll
  for (int i = 0; i < 4; i++){
    int gr = brow + ty * 4 + i;
    if (gr < NN){
      #pragma unroll
      for (int j = 0; j < 4; j++){
        int gc = bcol + tx * 4 + j;
        C[(size_t)gr * 512 + gc] = acc[i][j] + bp[gc];
      }
    }
  }
}

// One wave per node, lane = channel. Unroll-by-4 edge loop: issue all loads for
// 4 edges before computing, to stack gather latency (MLP x4).
__global__ __launch_bounds__(256) void edge_k(const float* __restrict__ qkvs,
    const float* __restrict__ ea, const float* __restrict__ ew,
    const int* __restrict__ row_ptr, const int* __restrict__ eid,
    const int* __restrict__ src_s, float* __restrict__ attn){
  int wid = (blockIdx.x * 256 + threadIdx.x) >> 6;
  int lane = threadIdx.x & 63;
  if (wid >= NN) return;
  float ew0[16], ew1[16];
  #pragma unroll
  for (int d = 0; d < 16; d += 4){
    float4 a = *(const float4*)(ew + lane * 16 + d);
    ew0[d] = a.x; ew0[d + 1] = a.y; ew0[d + 2] = a.z; ew0[d + 3] = a.w;
    float4 b = *(const float4*)(ew + (lane + 64) * 16 + d);
    ew1[d] = b.x; ew1[d + 1] = b.y; ew1[d + 2] = b.z; ew1[d + 3] = b.w;
  }
  float q0 = qkvs[(size_t)wid * 512 + lane];
  float q1 = qkvs[(size_t)wid * 512 + 64 + lane];
  float acc0 = 0.f, acc1 = 0.f, den0 = 0.f, den1 = 0.f;
  int beg = row_ptr[wid], end = row_ptr[wid + 1];
  int i = beg;
  for (; i + 4 <= end; i += 4){
    float4 eaq[4][4];
    float kv[4][4];
    #pragma unroll
    for (int u = 0; u < 4; u++){
      int e = eid[i + u];
      int s = src_s[i + u];
      const float* eap = ea + (size_t)e * 16;
      eaq[u][0] = *(const float4*)(eap);
      eaq[u][1] = *(const float4*)(eap + 4);
      eaq[u][2] = *(const float4*)(eap + 8);
      eaq[u][3] = *(const float4*)(eap + 12);
      const float* base = qkvs + (size_t)s * 512;
      kv[u][0] = base[128 + lane];
      kv[u][1] = base[192 + lane];
      kv[u][2] = base[256 + lane];
      kv[u][3] = base[320 + lane];
    }
    #pragma unroll
    for (int u = 0; u < 4; u++){
      float e0 = eaq[u][0].x * ew0[0] + eaq[u][0].y * ew0[1] + eaq[u][0].z * ew0[2] + eaq[u][0].w * ew0[3]
               + eaq[u][1].x * ew0[4] + eaq[u][1].y * ew0[5] + eaq[u][1].z * ew0[6] + eaq[u][1].w * ew0[7]
               + eaq[u][2].x * ew0[8] + eaq[u][2].y * ew0[9] + eaq[u][2].z * ew0[10] + eaq[u][2].w * ew0[11]
               + eaq[u][3].x * ew0[12] + eaq[u][3].y * ew0[13] + eaq[u][3].z * ew0[14] + eaq[u][3].w * ew0[15];
      float e1 = eaq[u][0].x * ew1[0] + eaq[u][0].y * ew1[1] + eaq[u][0].z * ew1[2] + eaq[u][0].w * ew1[3]
               + eaq[u][1].x * ew1[4] + eaq[u][1].y * ew1[5] + eaq[u][1].z * ew1[6] + eaq[u][1].w * ew1[7]
               + eaq[u][2].x * ew1[8] + eaq[u][2].y * ew1[9] + eaq[u][2].z * ew1[10] + eaq[u][2].w * ew1[11]
               + eaq[u][3].x * ew1[12] + eaq[u][3].y * ew1[13] + eaq[u][3].z * ew1[14] + eaq[u][3].w * ew1[15];
      float p0 = q0 * (kv[u][0] + e0);
      float p1 = q1 * (kv[u][1] + e1);
      #pragma unroll
      for (int off = 32; off >= 1; off >>= 1){
        p0 += __shfl_xor(p0, off);
        p1 += __shfl_xor(p1, off);
      }
      float w0 = __expf(p0 * INV_SQRT_D);
      float w1 = __expf(p1 * INV_SQRT_D);
      acc0 += (kv[u][2] + e0) * w0;
      acc1 += (kv[u][3] + e1) * w1;
      den0 += w0; den1 += w1;
    }
  }
  for (; i < end; i++){
    int e = eid[i];
    int s = src_s[i];
    const float* eap = ea + (size_t)e * 16;
    float e0 = 0.f, e1 = 0.f;
    #pragma unroll
    for (int d = 0; d < 16; d += 4){
      float4 a = *(const float4*)(eap + d);
      e0 += a.x * ew0[d] + a.y * ew0[d + 1] + a.z * ew0[d + 2] + a.w * ew0[d + 3];
      e1 += a.x * ew1[d] + a.y * ew1[d + 1] + a.z * ew1[d + 2] + a.w * ew1[d + 3];
    }
    const float* base = qkvs + (size_t)s * 512;
    float k0 = base[128 + lane], k1 = base[192 + lane];
    float v0 = base[256 + lane], v1 = base[320 + lane];
    float p0 = q0 * (k0 + e0), p1 = q1 * (k1 + e1);
    #pragma unroll
    for (int off = 32; off >= 1; off >>= 1){
      p0 += __shfl_xor(p0, off);
      p1 += __shfl_xor(p1, off);
    }
    float w0 = __expf(p0 * INV_SQRT_D);
    float w1 = __expf(p1 * INV_SQRT_D);
    acc0 += (v0 + e0) * w0;
    acc1 += (v1 + e1) * w1;
    den0 += w0; den1 += w1;
  }
  attn[(size_t)wid * 128 + lane]      = den0 > 0.f ? acc0 / den0 : 0.f;
  attn[(size_t)wid * 128 + 64 + lane] = den1 > 0.f ? acc1 / den1 : 0.f;
}

// beta-gate combine + [128->64] proj + leaky relu + BN partial sums.
__global__ __launch_bounds__(256) void combine_k(const float* __restrict__ attn,
    const float* __restrict__ qkvs, const float* __restrict__ bw,
    const float* __restrict__ tw, const float* __restrict__ tb,
    float* __restrict__ h2, float* __restrict__ bn_acc){
  __shared__ float twT[128][65];
  __shared__ float hcs[4][128];
  __shared__ float bsum[64], bsq[64];
  int t = threadIdx.x;
  int lane = t & 63, wv = t >> 6;
  for (int i = t; i < 64 * 128; i += 256){
    int j = i >> 7, k = i & 127;
    twT[k][j] = tw[i];
  }
  if (t < 64){ bsum[t] = 0.f; bsq[t] = 0.f; }
  __syncthreads();
  float bw0 = bw[lane],       bw1 = bw[64 + lane];
  float bwr0 = bw[128 + lane], bwr1 = bw[192 + lane];
  float bwd0 = bw[256 + lane], bwd1 = bw[320 + lane];
  float tbv = tb[lane];
  float rs = 0.f, rq = 0.f;
  int base_node = blockIdx.x * 16 + wv * 4;
  for (int it = 0; it < 4; it++){
    int n = base_node + it;
    bool valid = n < NN;
    float o0 = 0.f, o1 = 0.f, r0 = 0.f, r1 = 0.f;
    if (valid){
      o0 = attn[(size_t)n * 128 + lane];
      o1 = attn[(size_t)n * 128 + 64 + lane];
      r0 = qkvs[(size_t)n * 512 + 384 + lane];
      r1 = qkvs[(size_t)n * 512 + 448 + lane];
    }
    float p = o0 * bw0 + o1 * bw1 + r0 * bwr0 + r1 * bwr1 + (o0 - r0) * bwd0 + (o1 - r1) * bwd1;
    #pragma unroll
    for (int off = 32; off >= 1; off >>= 1) p += __shfl_xor(p, off);
    float beta = 1.f / (1.f + __expf(-p));
    float hc0 = beta * r0 + (1.f - beta) * o0;
    float hc1 = beta * r1 + (1.f - beta) * o1;
    hcs[wv][lane] = hc0;
    hcs[wv][64 + lane] = hc1;
    __syncthreads();
    float s = tbv;
    #pragma unroll 8
    for (int k = 0; k < 128; k++) s += hcs[wv][k] * twT[k][lane];
    __syncthreads();
    if (valid){
      float hv = s > 0.f ? s : 0.01f * s;
      h2[(size_t)n * 64 + lane] = hv;
      rs += hv; rq += hv * hv;
    }
  }
  atomicAdd(&bsum[lane], rs);
  atomicAdd(&bsq[lane], rq);
  __syncthreads();
  if (t < 64){
    atomicAdd(&bn_acc[t], bsum[t]);
    atomicAdd(&bn_acc[64 + t], bsq[t]);
  }
}

__global__ void bn_final_k(const float* __restrict__ bn_acc, const float* __restrict__ bnw,
                           const float* __restrict__ bnb, float* __restrict__ ss){
  int j = threadIdx.x;
  if (j < 64){
    float m = bn_acc[j] / (float)NN;
    float v = bn_acc[64 + j] / (float)NN - m * m;
    float sc = bnw[j] * rsqrtf(v + EPS_BN);
    ss[j] = sc;
    ss[64 + j] = bnb[j] - m * sc;
  }
}

__global__ __launch_bounds__(256) void bn_apply_k(const float* __restrict__ h2,
    const float* __restrict__ ss, const int* __restrict__ batch,
    float* __restrict__ h, float* __restrict__ gsum, unsigned* __restrict__ gmax,
    int do_pool){
  int wid = (blockIdx.x * 256 + threadIdx.x) >> 6;
  int lane = threadIdx.x & 63;
  const int CH = (NN + 1023) / 1024;
  int start = wid * CH;
  int end = start + CH; if (end > NN) end = NN;
  float sc = ss[lane], sh = ss[64 + lane];
  int curg = -1; float lmax = 0.f, lsum = 0.f;
  for (int n = start; n < end; n++){
    float v = h2[(size_t)n * 64 + lane] * sc + sh;
    h[(size_t)n * 64 + lane] = v;
    if (do_pool){
      int g = batch[n];
      if (g != curg){
        if (curg >= 0){
          atomicAdd(&gsum[curg * 64 + lane], lsum);
          atomicMax(&gmax[curg * 64 + lane], encf(lmax));
        }
        curg = g; lmax = v; lsum = v;
      } else {
        lmax = fmaxf(lmax, v); lsum += v;
      }
    }
  }
  if (do_pool && curg >= 0){
    atomicAdd(&gsum[curg * 64 + lane], lsum);
    atomicMax(&gmax[curg * 64 + lane], encf(lmax));
  }
}

__global__ void pool_final_k(const float* __restrict__ gsum, const unsigned* __restrict__ gmax,
                             const int* __restrict__ counts, float* __restrict__ gr){
  int i = blockIdx.x * 256 + threadIdx.x;
  if (i < NG * 64){
    int g = i >> 6, j = i & 63;
    unsigned e = gmax[i];
    float mx = e ? decf(e) : 0.f;
    int c = counts[g]; if (c < 1) c = 1;
    gr[g * 128 + j]       += mx;
    gr[g * 128 + 64 + j]  += gsum[i] / (float)c;
  }
}

extern "C" void kernel_launch(void* const* d_in, const int* in_sizes, int n_in,
                              void* d_out, int out_size, void* d_ws, size_t ws_size,
                              hipStream_t stream){
  const float* x     = (const float*)d_in[0];
  const float* ea    = (const float*)d_in[1];
  const int*   eidx  = (const int*)d_in[2];
  const int*   batch = (const int*)d_in[3];
  const float* c1_qw = (const float*)d_in[4];
  const float* c1_qb = (const float*)d_in[5];
  const float* c1_kw = (const float*)d_in[6];
  const float* c1_kb = (const float*)d_in[7];
  const float* c1_vw = (const float*)d_in[8];
  const float* c1_vb = (const float*)d_in[9];
  const float* c1_ew = (const float*)d_in[10];
  const float* c1_skw= (const float*)d_in[11];
  const float* c1_skb= (const float*)d_in[12];
  const float* c1_bw = (const float*)d_in[13];
  const float* c1_tw = (const float*)d_in[14];
  const float* c1_tb = (const float*)d_in[15];
  const float* c1_bnw= (const float*)d_in[16];
  const float* c1_bnb= (const float*)d_in[17];
  const float* L_qw  = (const float*)d_in[18];
  const float* L_qb  = (const float*)d_in[19];
  const float* L_kw  = (const float*)d_in[20];
  const float* L_kb  = (const float*)d_in[21];
  const float* L_vw  = (const float*)d_in[22];
  const float* L_vb  = (const float*)d_in[23];
  const float* L_ew  = (const float*)d_in[24];
  const float* L_skw = (const float*)d_in[25];
  const float* L_skb = (const float*)d_in[26];
  const float* L_bw  = (const float*)d_in[27];
  const float* L_tw  = (const float*)d_in[28];
  const float* L_tb  = (const float*)d_in[29];
  const float* L_bnw = (const float*)d_in[30];
  const float* L_bnb = (const float*)d_in[31];
  const int* srcs = eidx;
  const int* dsts = eidx + NE;

  char* p = (char*)d_ws;
  auto carve = [&](size_t bytes) -> void* {
    void* r = (void*)p;
    p += (bytes + 255) & ~(size_t)255;
    return r;
  };
  float*    Wp     = (float*)carve(512 * 128 * sizeof(float));
  float*    bp     = (float*)carve(512 * sizeof(float));
  float*    qkvs   = (float*)carve((size_t)NN * 512 * sizeof(float));
  float*    attn   = (float*)carve((size_t)NN * 128 * sizeof(float));
  float*    h      = (float*)carve((size_t)NN * 64 * sizeof(float));
  float*    h2     = (float*)carve((size_t)NN * 64 * sizeof(float));
  float*    bn_acc = (float*)carve(128 * sizeof(float));
  float*    ss     = (float*)carve(128 * sizeof(float));
  float*    gsum   = (float*)carve((size_t)NG * 64 * sizeof(float));
  unsigned* gmax   = (unsigned*)carve((size_t)NG * 64 * sizeof(unsigned));
  int*      deg    = (int*)carve(NN * sizeof(int));
  int*      row_ptr= (int*)carve((NN + 1) * sizeof(int));
  int*      eid    = (int*)carve((size_t)NE * sizeof(int));
  int*      src_s  = (int*)carve((size_t)NE * sizeof(int));
  int*      counts = (int*)carve(NG * sizeof(int));
  int*      bsums  = (int*)carve(256 * sizeof(int));

  hipMemsetAsync(d_out, 0, (size_t)out_size * sizeof(float), stream);
  hipMemsetAsync(deg, 0, NN * sizeof(int), stream);
  hipMemsetAsync(counts, 0, NG * sizeof(int), stream);
  hist_k<<<(NE + 255) / 256, 256, 0, stream>>>(dsts, deg);
  counts_k<<<(NN + 255) / 256, 256, 0, stream>>>(batch, counts);
  scan1_k<<<SCAN_B, 256, 0, stream>>>(deg, bsums);
  scan2_k<<<1, 256, 0, stream>>>(bsums);
  scan3_k<<<SCAN_B, 256, 0, stream>>>(deg, bsums, row_ptr);
  cursor_k<<<(NN + 255) / 256, 256, 0, stream>>>(row_ptr, deg);   // reuse deg as cursor
  scatter_k<<<(NE + 255) / 256, 256, 0, stream>>>(dsts, srcs, deg, eid, src_s);

  const float* hin = x;
  for (int L = 0; L < 4; L++){
    int D = (L == 0) ? FIN : EMB;
    const float *qw,*qb,*kw,*kb,*vw,*vb,*eww,*skw,*skb,*bww,*tw,*tb,*bnw,*bnb;
    if (L == 0){
      qw=c1_qw; qb=c1_qb; kw=c1_kw; kb=c1_kb; vw=c1_vw; vb=c1_vb;
      eww=c1_ew; skw=c1_skw; skb=c1_skb; bww=c1_bw; tw=c1_tw; tb=c1_tb;
      bnw=c1_bnw; bnb=c1_bnb;
    } else {
      int i = L - 1;
      qw = L_qw + (size_t)i * HCC * EMB;  qb = L_qb + (size_t)i * HCC;
      kw = L_kw + (size_t)i * HCC * EMB;  kb = L_kb + (size_t)i * HCC;
      vw = L_vw + (size_t)i * HCC * EMB;  vb = L_vb + (size_t)i * HCC;
      eww= L_ew + (size_t)i * HCC * EDIM;
      skw= L_skw+ (size_t)i * HCC * EMB;  skb= L_skb+ (size_t)i * HCC;
      bww= L_bw + (size_t)i * 3 * HCC;
      tw = L_tw + (size_t)i * EMB * HCC;  tb = L_tb + (size_t)i * EMB;
      bnw= L_bnw+ (size_t)i * EMB;        bnb= L_bnb+ (size_t)i * EMB;
    }
    pack_k<<<(512 * D + 255) / 256, 256, 0, stream>>>(qw, kw, vw, skw, qb, kb, vb, skb, Wp, bp, D);
    dim3 gg((NN + 63) / 64, 8);
    if (D == 128) gemm_k<128><<<gg, 256, 0, stream>>>(hin, Wp, bp, qkvs);
    else          gemm_k<64><<<gg, 256, 0, stream>>>(hin, Wp, bp, qkvs);
    edge_k<<<(NN * 64 + 255) / 256, 256, 0, stream>>>(qkvs, ea, eww, row_ptr, eid, src_s, attn);
    hipMemsetAsync(bn_acc, 0, 128 * sizeof(float), stream);
    combine_k<<<(NN + 15) / 16, 256, 0, stream>>>(attn, qkvs, bww, tw, tb, h2, bn_acc);
    bn_final_k<<<1, 64, 0, stream>>>(bn_acc, bnw, bnb, ss);
    if (L > 0) hipMemsetAsync(gsum, 0, 2 * NG * 64 * sizeof(float), stream);
    bn_apply_k<<<256, 256, 0, stream>>>(h2, ss, batch, h, gsum, gmax, (L > 0) ? 1 : 0);
    if (L > 0) pool_final_k<<<(NG * 64 + 255) / 256, 256, 0, stream>>>(gsum, gmax, counts, (float*)d_out);
    hin = h;
  }
}

// Round 3
// 2306.655 us; speedup vs baseline: 1.1406x; 1.1094x over previous
//
#include <hip/hip_runtime.h>

#define NN 50000
#define NE 800000
#define FIN 128
#define EDIM 16
#define EMB 64
#define NH 2
#define NLAYERS 3
#define NG 64
#define HCC 128
#define INV_SQRT_D 0.125f
#define EPS_BN 1e-5f
#define SCAN_B 196   // ceil(NN/256)

__device__ __forceinline__ unsigned encf(float f){
  unsigned u = __float_as_uint(f);
  return (u & 0x80000000u) ? ~u : (u | 0x80000000u);
}
__device__ __forceinline__ float decf(unsigned e){
  unsigned u = (e & 0x80000000u) ? (e ^ 0x80000000u) : ~e;
  return __uint_as_float(u);
}
__device__ __forceinline__ unsigned f2bf(float x){   // RNE bf16, returned in low 16
  unsigned u = __float_as_uint(x);
  return (u + 0x7fffu + ((u >> 16) & 1u)) >> 16;
}

__global__ void hist_k(const int* __restrict__ dst, int* __restrict__ deg){
  int i = blockIdx.x * 256 + threadIdx.x;
  if (i < NE) atomicAdd(&deg[dst[i]], 1);
}

__global__ void counts_k(const int* __restrict__ batch, int* __restrict__ counts){
  int i = blockIdx.x * 256 + threadIdx.x;
  if (i < NN) atomicAdd(&counts[batch[i]], 1);
}

__global__ void scan1_k(const int* __restrict__ deg, int* __restrict__ bsums){
  __shared__ int lds[256];
  int b = blockIdx.x, t = threadIdx.x;
  int idx = b * 256 + t;
  lds[t] = (idx < NN) ? deg[idx] : 0;
  __syncthreads();
  for (int off = 128; off >= 1; off >>= 1){
    if (t < off) lds[t] += lds[t + off];
    __syncthreads();
  }
  if (t == 0) bsums[b] = lds[0];
}

__global__ void scan2_k(int* __restrict__ bsums){
  __shared__ int lds[256];
  int t = threadIdx.x;
  int v = (t < SCAN_B) ? bsums[t] : 0;
  int x = v;
  lds[t] = x;
  __syncthreads();
  for (int off = 1; off < 256; off <<= 1){
    int y = (t >= off) ? lds[t - off] : 0;
    __syncthreads();
    x += y;
    lds[t] = x;
    __syncthreads();
  }
  if (t < SCAN_B) bsums[t] = x - v;   // exclusive
}

__global__ void scan3_k(const int* __restrict__ deg, const int* __restrict__ bsums,
                        int* __restrict__ row_ptr){
  __shared__ int lds[256];
  int b = blockIdx.x, t = threadIdx.x;
  int idx = b * 256 + t;
  int v = (idx < NN) ? deg[idx] : 0;
  int x = v;
  lds[t] = x;
  __syncthreads();
  for (int off = 1; off < 256; off <<= 1){
    int y = (t >= off) ? lds[t - off] : 0;
    __syncthreads();
    x += y;
    lds[t] = x;
    __syncthreads();
  }
  if (idx <= NN) row_ptr[idx] = bsums[b] + x - v;
}

__global__ void cursor_k(const int* __restrict__ row_ptr, int* __restrict__ cur){
  int i = blockIdx.x * 256 + threadIdx.x;
  if (i < NN) cur[i] = row_ptr[i];
}

__global__ void scatter_k(const int* __restrict__ dst, const int* __restrict__ src,
                          int* __restrict__ cur, int* __restrict__ eid,
                          int* __restrict__ src_s){
  int i = blockIdx.x * 256 + threadIdx.x;
  if (i < NE){
    int p = atomicAdd(&cur[dst[i]], 1);
    eid[p] = i;
    src_s[p] = src[i];
  }
}

// edge_attr -> bf16, reordered into CSR position order. thread = (p, half-row)
__global__ void pack_ea_k(const float* __restrict__ ea, const int* __restrict__ eid,
                          unsigned* __restrict__ eab){
  int i = blockIdx.x * 256 + threadIdx.x;
  if (i >= NE * 2) return;
  int p = i >> 1, half = i & 1;
  int e = eid[p];
  const float* s = ea + (size_t)e * 16 + half * 8;
  float4 a = *(const float4*)(s);
  float4 b = *(const float4*)(s + 4);
  uint4 o;
  o.x = f2bf(a.x) | (f2bf(a.y) << 16);
  o.y = f2bf(a.z) | (f2bf(a.w) << 16);
  o.z = f2bf(b.x) | (f2bf(b.y) << 16);
  o.w = f2bf(b.z) | (f2bf(b.w) << 16);
  ((uint4*)eab)[(size_t)p * 2 + half] = o;
}

__global__ void pack_k(const float* __restrict__ qw, const float* __restrict__ kw,
                       const float* __restrict__ vw, const float* __restrict__ skw,
                       const float* __restrict__ qb, const float* __restrict__ kb,
                       const float* __restrict__ vb, const float* __restrict__ skb,
                       float* __restrict__ Wp, float* __restrict__ bp, int D){
  int i = blockIdx.x * 256 + threadIdx.x;
  if (i < 512 * D){
    int c = i / D, d = i - c * D;
    const float* w = (c < 128) ? qw : (c < 256) ? kw : (c < 384) ? vw : skw;
    Wp[i] = w[(c & 127) * D + d];
  }
  if (i < 512){
    const float* b = (i < 128) ? qb : (i < 256) ? kb : (i < 384) ? vb : skb;
    bp[i] = b[i & 127];
  }
}

// pack k,v (bf16 pair in one uint) per (node, head, channel)
__global__ __launch_bounds__(256) void pack_kv_k(const float* __restrict__ qkvs,
                                                 unsigned* __restrict__ kvb){
  int i = blockIdx.x * 256 + threadIdx.x;
  if (i >= NN * 128) return;
  int n = i >> 7;
  int hl = i & 127;                 // h*64 + lane
  const float* base = qkvs + (size_t)n * 512;
  float k = base[128 + hl];
  float v = base[256 + hl];
  kvb[i] = f2bf(k) | (f2bf(v) << 16);
}

// C[N,512] = A[N,D] @ Wp[512,D]^T + bp ; 64x64 tile, K staged by 64
template<int D>
__global__ __launch_bounds__(256) void gemm_k(const float* __restrict__ A,
                                              const float* __restrict__ W,
                                              const float* __restrict__ bp,
                                              float* __restrict__ C){
  __shared__ float As[64][65];
  __shared__ float Ws[64][65];
  int t = threadIdx.x;
  int tx = t & 15, ty = t >> 4;
  int brow = blockIdx.x * 64;
  int bcol = blockIdx.y * 64;
  float acc[4][4];
  #pragma unroll
  for (int i = 0; i < 4; i++)
    #pragma unroll
    for (int j = 0; j < 4; j++) acc[i][j] = 0.f;

  for (int kb = 0; kb < D; kb += 64){
    #pragma unroll
    for (int it = 0; it < 4; it++){
      int r = (t >> 4) + it * 16;
      int c4 = (t & 15) * 4;
      int gr = brow + r;
      float4 va = make_float4(0.f, 0.f, 0.f, 0.f);
      if (gr < NN) va = *(const float4*)(A + (size_t)gr * D + kb + c4);
      As[r][c4 + 0] = va.x; As[r][c4 + 1] = va.y; As[r][c4 + 2] = va.z; As[r][c4 + 3] = va.w;
      int wc = bcol + r;
      float4 vw = *(const float4*)(W + (size_t)wc * D + kb + c4);
      Ws[r][c4 + 0] = vw.x; Ws[r][c4 + 1] = vw.y; Ws[r][c4 + 2] = vw.z; Ws[r][c4 + 3] = vw.w;
    }
    __syncthreads();
    #pragma unroll 8
    for (int k = 0; k < 64; k++){
      float a0 = As[ty * 4 + 0][k], a1 = As[ty * 4 + 1][k];
      float a2 = As[ty * 4 + 2][k], a3 = As[ty * 4 + 3][k];
      float w0 = Ws[tx * 4 + 0][k], w1 = Ws[tx * 4 + 1][k];
      float w2 = Ws[tx * 4 + 2][k], w3 = Ws[tx * 4 + 3][k];
      acc[0][0] += a0 * w0; acc[0][1] += a0 * w1; acc[0][2] += a0 * w2; acc[0][3] += a0 * w3;
      acc[1][0] += a1 * w0; acc[1][1] += a1 * w1; acc[1][2] += a1 * w2; acc[1][3] += a1 * w3;
      acc[2][0] += a2 * w0; acc[2][1] += a2 * w1; acc[2][2] += a2 * w2; acc[2][3] += a2 * w3;
      acc[3][0] += a3 * w0; acc[3][1] += a3 * w1; acc[3][2] += a3 * w2; acc[3][3] += a3 * w3;
    }
    __syncthreads();
  }
  #pragma unroll
  for (int i = 0; i < 4; i++){
    int gr = brow + ty * 4 + i;
    if (gr < NN){
      #pragma unroll
      for (int j = 0; j < 4; j++){
        int gc = bcol + tx * 4 + j;
        C[(size_t)gr * 512 + gc] = acc[i][j] + bp[gc];
      }
    }
  }
}

// One wave per (node, head). lane = channel within head.
// Per edge: 1x4B bf16 k/v gather + 1x32B sequential bf16 ea read.
__global__ __launch_bounds__(256) void edge_k(const float* __restrict__ qkvs,
    const unsigned* __restrict__ kvb, const unsigned* __restrict__ eab,
    const float* __restrict__ ew, const int* __restrict__ row_ptr,
    const int* __restrict__ src_s, float* __restrict__ attn){
  int wv = (blockIdx.x * 256 + threadIdx.x) >> 6;
  if (wv >= NN * 2) return;
  int lane = threadIdx.x & 63;
  int n = wv >> 1, h = wv & 1;
  float ewv[16];
  const float* ewrow = ew + ((size_t)(h * 64 + lane)) * 16;
  #pragma unroll
  for (int d = 0; d < 16; d += 4){
    float4 a = *(const float4*)(ewrow + d);
    ewv[d] = a.x; ewv[d + 1] = a.y; ewv[d + 2] = a.z; ewv[d + 3] = a.w;
  }
  float q = qkvs[(size_t)n * 512 + h * 64 + lane];
  int beg = row_ptr[n], end = row_ptr[n + 1];
  int nb = end - beg;
  float acc = 0.f, den = 0.f;
  const unsigned* kvh = kvb + h * 64;
  for (int cb = 0; cb < nb; cb += 64){
    int sv = (cb + lane < nb) ? src_s[beg + cb + lane] : 0;
    int m = min(64, nb - cb);
    int u = 0;
    for (; u + 4 <= m; u += 4){
      unsigned kvr[4], er[4];
      #pragma unroll
      for (int j = 0; j < 4; j++){
        int s = __shfl(sv, u + j);
        kvr[j] = kvh[(size_t)s * 128 + lane];
        er[j] = eab[((size_t)(beg + cb + u + j)) * 8 + (lane & 7)];
      }
      #pragma unroll
      for (int j = 0; j < 4; j++){
        float e = 0.f;
        #pragma unroll
        for (int d = 0; d < 8; d++){
          unsigned u2 = __shfl(er[j], d);
          e += __uint_as_float(u2 << 16) * ewv[2 * d]
             + __uint_as_float(u2 & 0xffff0000u) * ewv[2 * d + 1];
        }
        float kk = __uint_as_float(kvr[j] << 16);
        float vv = __uint_as_float(kvr[j] & 0xffff0000u);
        float p = q * (kk + e);
        #pragma unroll
        for (int off = 32; off >= 1; off >>= 1) p += __shfl_xor(p, off);
        float w = __expf(p * INV_SQRT_D);
        acc += (vv + e) * w;
        den += w;
      }
    }
    for (; u < m; u++){
      int s = __shfl(sv, u);
      unsigned kv = kvh[(size_t)s * 128 + lane];
      unsigned er0 = eab[((size_t)(beg + cb + u)) * 8 + (lane & 7)];
      float e = 0.f;
      #pragma unroll
      for (int d = 0; d < 8; d++){
        unsigned u2 = __shfl(er0, d);
        e += __uint_as_float(u2 << 16) * ewv[2 * d]
           + __uint_as_float(u2 & 0xffff0000u) * ewv[2 * d + 1];
      }
      float kk = __uint_as_float(kv << 16);
      float vv = __uint_as_float(kv & 0xffff0000u);
      float p = q * (kk + e);
      #pragma unroll
      for (int off = 32; off >= 1; off >>= 1) p += __shfl_xor(p, off);
      float w = __expf(p * INV_SQRT_D);
      acc += (vv + e) * w;
      den += w;
    }
  }
  attn[(size_t)n * 128 + h * 64 + lane] = den > 0.f ? acc / den : 0.f;
}

// beta-gate combine + [128->64] proj + leaky relu + BN partial sums.
__global__ __launch_bounds__(256) void combine_k(const float* __restrict__ attn,
    const float* __restrict__ qkvs, const float* __restrict__ bw,
    const float* __restrict__ tw, const float* __restrict__ tb,
    float* __restrict__ h2, float* __restrict__ bn_acc){
  __shared__ float twT[128][65];
  __shared__ float hcs[4][128];
  __shared__ float bsum[64], bsq[64];
  int t = threadIdx.x;
  int lane = t & 63, wv = t >> 6;
  for (int i = t; i < 64 * 128; i += 256){
    int j = i >> 7, k = i & 127;
    twT[k][j] = tw[i];
  }
  if (t < 64){ bsum[t] = 0.f; bsq[t] = 0.f; }
  __syncthreads();
  float bw0 = bw[lane],       bw1 = bw[64 + lane];
  float bwr0 = bw[128 + lane], bwr1 = bw[192 + lane];
  float bwd0 = bw[256 + lane], bwd1 = bw[320 + lane];
  float tbv = tb[lane];
  float rs = 0.f, rq = 0.f;
  int base_node = blockIdx.x * 16 + wv * 4;
  for (int it = 0; it < 4; it++){
    int n = base_node + it;
    bool valid = n < NN;
    float o0 = 0.f, o1 = 0.f, r0 = 0.f, r1 = 0.f;
    if (valid){
      o0 = attn[(size_t)n * 128 + lane];
      o1 = attn[(size_t)n * 128 + 64 + lane];
      r0 = qkvs[(size_t)n * 512 + 384 + lane];
      r1 = qkvs[(size_t)n * 512 + 448 + lane];
    }
    float p = o0 * bw0 + o1 * bw1 + r0 * bwr0 + r1 * bwr1 + (o0 - r0) * bwd0 + (o1 - r1) * bwd1;
    #pragma unroll
    for (int off = 32; off >= 1; off >>= 1) p += __shfl_xor(p, off);
    float beta = 1.f / (1.f + __expf(-p));
    float hc0 = beta * r0 + (1.f - beta) * o0;
    float hc1 = beta * r1 + (1.f - beta) * o1;
    hcs[wv][lane] = hc0;
    hcs[wv][64 + lane] = hc1;
    __syncthreads();
    float s = tbv;
    #pragma unroll 8
    for (int k = 0; k < 128; k++) s += hcs[wv][k] * twT[k][lane];
    __syncthreads();
    if (valid){
      float hv = s > 0.f ? s : 0.01f * s;
      h2[(size_t)n * 64 + lane] = hv;
      rs += hv; rq += hv * hv;
    }
  }
  atomicAdd(&bsum[lane], rs);
  atomicAdd(&bsq[lane], rq);
  __syncthreads();
  if (t < 64){
    atomicAdd(&bn_acc[t], bsum[t]);
    atomicAdd(&bn_acc[64 + t], bsq[t]);
  }
}

__global__ void bn_final_k(const float* __restrict__ bn_acc, const float* __restrict__ bnw,
                           const float* __restrict__ bnb, float* __restrict__ ss){
  int j = threadIdx.x;
  if (j < 64){
    float m = bn_acc[j] / (float)NN;
    float v = bn_acc[64 + j] / (float)NN - m * m;
    float sc = bnw[j] * rsqrtf(v + EPS_BN);
    ss[j] = sc;
    ss[64 + j] = bnb[j] - m * sc;
  }
}

__global__ __launch_bounds__(256) void bn_apply_k(const float* __restrict__ h2,
    const float* __restrict__ ss, const int* __restrict__ batch,
    float* __restrict__ h, float* __restrict__ gsum, unsigned* __restrict__ gmax,
    int do_pool){
  int wid = (blockIdx.x * 256 + threadIdx.x) >> 6;
  int lane = threadIdx.x & 63;
  const int CH = (NN + 1023) / 1024;
  int start = wid * CH;
  int end = start + CH; if (end > NN) end = NN;
  float sc = ss[lane], sh = ss[64 + lane];
  int curg = -1; float lmax = 0.f, lsum = 0.f;
  for (int n = start; n < end; n++){
    float v = h2[(size_t)n * 64 + lane] * sc + sh;
    h[(size_t)n * 64 + lane] = v;
    if (do_pool){
      int g = batch[n];
      if (g != curg){
        if (curg >= 0){
          atomicAdd(&gsum[curg * 64 + lane], lsum);
          atomicMax(&gmax[curg * 64 + lane], encf(lmax));
        }
        curg = g; lmax = v; lsum = v;
      } else {
        lmax = fmaxf(lmax, v); lsum += v;
      }
    }
  }
  if (do_pool && curg >= 0){
    atomicAdd(&gsum[curg * 64 + lane], lsum);
    atomicMax(&gmax[curg * 64 + lane], encf(lmax));
  }
}

__global__ void pool_final_k(const float* __restrict__ gsum, const unsigned* __restrict__ gmax,
                             const int* __restrict__ counts, float* __restrict__ gr){
  int i = blockIdx.x * 256 + threadIdx.x;
  if (i < NG * 64){
    int g = i >> 6, j = i & 63;
    unsigned e = gmax[i];
    float mx = e ? decf(e) : 0.f;
    int c = counts[g]; if (c < 1) c = 1;
    gr[g * 128 + j]       += mx;
    gr[g * 128 + 64 + j]  += gsum[i] / (float)c;
  }
}

extern "C" void kernel_launch(void* const* d_in, const int* in_sizes, int n_in,
                              void* d_out, int out_size, void* d_ws, size_t ws_size,
                              hipStream_t stream){
  const float* x     = (const float*)d_in[0];
  const float* ea    = (const float*)d_in[1];
  const int*   eidx  = (const int*)d_in[2];
  const int*   batch = (const int*)d_in[3];
  const float* c1_qw = (const float*)d_in[4];
  const float* c1_qb = (const float*)d_in[5];
  const float* c1_kw = (const float*)d_in[6];
  const float* c1_kb = (const float*)d_in[7];
  const float* c1_vw = (const float*)d_in[8];
  const float* c1_vb = (const float*)d_in[9];
  const float* c1_ew = (const float*)d_in[10];
  const float* c1_skw= (const float*)d_in[11];
  const float* c1_skb= (const float*)d_in[12];
  const float* c1_bw = (const float*)d_in[13];
  const float* c1_tw = (const float*)d_in[14];
  const float* c1_tb = (const float*)d_in[15];
  const float* c1_bnw= (const float*)d_in[16];
  const float* c1_bnb= (const float*)d_in[17];
  const float* L_qw  = (const float*)d_in[18];
  const float* L_qb  = (const float*)d_in[19];
  const float* L_kw  = (const float*)d_in[20];
  const float* L_kb  = (const float*)d_in[21];
  const float* L_vw  = (const float*)d_in[22];
  const float* L_vb  = (const float*)d_in[23];
  const float* L_ew  = (const float*)d_in[24];
  const float* L_skw = (const float*)d_in[25];
  const float* L_skb = (const float*)d_in[26];
  const float* L_bw  = (const float*)d_in[27];
  const float* L_tw  = (const float*)d_in[28];
  const float* L_tb  = (const float*)d_in[29];
  const float* L_bnw = (const float*)d_in[30];
  const float* L_bnb = (const float*)d_in[31];
  const int* srcs = eidx;
  const int* dsts = eidx + NE;

  char* p = (char*)d_ws;
  auto carve = [&](size_t bytes) -> void* {
    void* r = (void*)p;
    p += (bytes + 255) & ~(size_t)255;
    return r;
  };
  float*    Wp     = (float*)carve(512 * 128 * sizeof(float));
  float*    bp     = (float*)carve(512 * sizeof(float));
  float*    qkvs   = (float*)carve((size_t)NN * 512 * sizeof(float));
  unsigned* kvb    = (unsigned*)carve((size_t)NN * 128 * sizeof(unsigned));
  unsigned* eab    = (unsigned*)carve((size_t)NE * 8 * sizeof(unsigned));
  float*    attn   = (float*)carve((size_t)NN * 128 * sizeof(float));
  float*    h      = (float*)carve((size_t)NN * 64 * sizeof(float));
  float*    h2     = (float*)carve((size_t)NN * 64 * sizeof(float));
  float*    bn_acc = (float*)carve(128 * sizeof(float));
  float*    ss     = (float*)carve(128 * sizeof(float));
  float*    gsum   = (float*)carve((size_t)NG * 64 * sizeof(float));
  unsigned* gmax   = (unsigned*)carve((size_t)NG * 64 * sizeof(unsigned));
  int*      deg    = (int*)carve(NN * sizeof(int));
  int*      row_ptr= (int*)carve((NN + 1) * sizeof(int));
  int*      eid    = (int*)carve((size_t)NE * sizeof(int));
  int*      src_s  = (int*)carve((size_t)NE * sizeof(int));
  int*      counts = (int*)carve(NG * sizeof(int));
  int*      bsums  = (int*)carve(256 * sizeof(int));

  hipMemsetAsync(d_out, 0, (size_t)out_size * sizeof(float), stream);
  hipMemsetAsync(deg, 0, NN * sizeof(int), stream);
  hipMemsetAsync(counts, 0, NG * sizeof(int), stream);
  hist_k<<<(NE + 255) / 256, 256, 0, stream>>>(dsts, deg);
  counts_k<<<(NN + 255) / 256, 256, 0, stream>>>(batch, counts);
  scan1_k<<<SCAN_B, 256, 0, stream>>>(deg, bsums);
  scan2_k<<<1, 256, 0, stream>>>(bsums);
  scan3_k<<<SCAN_B, 256, 0, stream>>>(deg, bsums, row_ptr);
  cursor_k<<<(NN + 255) / 256, 256, 0, stream>>>(row_ptr, deg);   // reuse deg as cursor
  scatter_k<<<(NE + 255) / 256, 256, 0, stream>>>(dsts, srcs, deg, eid, src_s);
  pack_ea_k<<<(NE * 2 + 255) / 256, 256, 0, stream>>>(ea, eid, eab);

  const float* hin = x;
  for (int L = 0; L < 4; L++){
    int D = (L == 0) ? FIN : EMB;
    const float *qw,*qb,*kw,*kb,*vw,*vb,*eww,*skw,*skb,*bww,*tw,*tb,*bnw,*bnb;
    if (L == 0){
      qw=c1_qw; qb=c1_qb; kw=c1_kw; kb=c1_kb; vw=c1_vw; vb=c1_vb;
      eww=c1_ew; skw=c1_skw; skb=c1_skb; bww=c1_bw; tw=c1_tw; tb=c1_tb;
      bnw=c1_bnw; bnb=c1_bnb;
    } else {
      int i = L - 1;
      qw = L_qw + (size_t)i * HCC * EMB;  qb = L_qb + (size_t)i * HCC;
      kw = L_kw + (size_t)i * HCC * EMB;  kb = L_kb + (size_t)i * HCC;
      vw = L_vw + (size_t)i * HCC * EMB;  vb = L_vb + (size_t)i * HCC;
      eww= L_ew + (size_t)i * HCC * EDIM;
      skw= L_skw+ (size_t)i * HCC * EMB;  skb= L_skb+ (size_t)i * HCC;
      bww= L_bw + (size_t)i * 3 * HCC;
      tw = L_tw + (size_t)i * EMB * HCC;  tb = L_tb + (size_t)i * EMB;
      bnw= L_bnw+ (size_t)i * EMB;        bnb= L_bnb+ (size_t)i * EMB;
    }
    pack_k<<<(512 * D + 255) / 256, 256, 0, stream>>>(qw, kw, vw, skw, qb, kb, vb, skb, Wp, bp, D);
    dim3 gg((NN + 63) / 64, 8);
    if (D == 128) gemm_k<128><<<gg, 256, 0, stream>>>(hin, Wp, bp, qkvs);
    else          gemm_k<64><<<gg, 256, 0, stream>>>(hin, Wp, bp, qkvs);
    pack_kv_k<<<(NN * 128 + 255) / 256, 256, 0, stream>>>(qkvs, kvb);
    edge_k<<<(NN * 2 * 64 + 255) / 256, 256, 0, stream>>>(qkvs, kvb, eab, eww, row_ptr, src_s, attn);
    hipMemsetAsync(bn_acc, 0, 128 * sizeof(float), stream);
    combine_k<<<(NN + 15) / 16, 256, 0, stream>>>(attn, qkvs, bww, tw, tb, h2, bn_acc);
    bn_final_k<<<1, 64, 0, stream>>>(bn_acc, bnw, bnb, ss);
    if (L > 0) hipMemsetAsync(gsum, 0, 2 * NG * 64 * sizeof(float), stream);
    bn_apply_k<<<256, 256, 0, stream>>>(h2, ss, batch, h, gsum, gmax, (L > 0) ? 1 : 0);
    if (L > 0) pool_final_k<<<(NG * 64 + 255) / 256, 256, 0, stream>>>(gsum, gmax, counts, (float*)d_out);
    hin = h;
  }
}

// Round 4
// 2068.477 us; speedup vs baseline: 1.2719x; 1.1151x over previous
//
#include <hip/hip_runtime.h>

#define NN 50000
#define NE 800000
#define FIN 128
#define EDIM 16
#define EMB 64
#define NH 2
#define NLAYERS 3
#define NG 64
#define HCC 128
#define INV_SQRT_D 0.125f
#define EPS_BN 1e-5f
#define SCAN_B 196   // ceil(NN/256)
#define SCALE_L2E 0.18033688f   // 0.125 * log2(e)

__device__ __forceinline__ unsigned encf(float f){
  unsigned u = __float_as_uint(f);
  return (u & 0x80000000u) ? ~u : (u | 0x80000000u);
}
__device__ __forceinline__ float decf(unsigned e){
  unsigned u = (e & 0x80000000u) ? (e ^ 0x80000000u) : ~e;
  return __uint_as_float(u);
}
__device__ __forceinline__ unsigned f2bf(float x){   // RNE bf16, returned in low 16
  unsigned u = __float_as_uint(x);
  return (u + 0x7fffu + ((u >> 16) & 1u)) >> 16;
}

__global__ void hist_k(const int* __restrict__ dst, int* __restrict__ deg){
  int i = blockIdx.x * 256 + threadIdx.x;
  if (i < NE) atomicAdd(&deg[dst[i]], 1);
}

__global__ void counts_k(const int* __restrict__ batch, int* __restrict__ counts){
  int i = blockIdx.x * 256 + threadIdx.x;
  if (i < NN) atomicAdd(&counts[batch[i]], 1);
}

__global__ void scan1_k(const int* __restrict__ deg, int* __restrict__ bsums){
  __shared__ int lds[256];
  int b = blockIdx.x, t = threadIdx.x;
  int idx = b * 256 + t;
  lds[t] = (idx < NN) ? deg[idx] : 0;
  __syncthreads();
  for (int off = 128; off >= 1; off >>= 1){
    if (t < off) lds[t] += lds[t + off];
    __syncthreads();
  }
  if (t == 0) bsums[b] = lds[0];
}

__global__ void scan2_k(int* __restrict__ bsums){
  __shared__ int lds[256];
  int t = threadIdx.x;
  int v = (t < SCAN_B) ? bsums[t] : 0;
  int x = v;
  lds[t] = x;
  __syncthreads();
  for (int off = 1; off < 256; off <<= 1){
    int y = (t >= off) ? lds[t - off] : 0;
    __syncthreads();
    x += y;
    lds[t] = x;
    __syncthreads();
  }
  if (t < SCAN_B) bsums[t] = x - v;   // exclusive
}

__global__ void scan3_k(const int* __restrict__ deg, const int* __restrict__ bsums,
                        int* __restrict__ row_ptr){
  __shared__ int lds[256];
  int b = blockIdx.x, t = threadIdx.x;
  int idx = b * 256 + t;
  int v = (idx < NN) ? deg[idx] : 0;
  int x = v;
  lds[t] = x;
  __syncthreads();
  for (int off = 1; off < 256; off <<= 1){
    int y = (t >= off) ? lds[t - off] : 0;
    __syncthreads();
    x += y;
    lds[t] = x;
    __syncthreads();
  }
  if (idx <= NN) row_ptr[idx] = bsums[b] + x - v;
}

__global__ void cursor_k(const int* __restrict__ row_ptr, int* __restrict__ cur){
  int i = blockIdx.x * 256 + threadIdx.x;
  if (i < NN) cur[i] = row_ptr[i];
}

__global__ void scatter_k(const int* __restrict__ dst, const int* __restrict__ src,
                          int* __restrict__ cur, int* __restrict__ eid,
                          int* __restrict__ src_s){
  int i = blockIdx.x * 256 + threadIdx.x;
  if (i < NE){
    int p = atomicAdd(&cur[dst[i]], 1);
    eid[p] = i;
    src_s[p] = src[i];
  }
}

// edge_attr -> bf16, reordered into CSR position order. thread = (p, half-row)
__global__ void pack_ea_k(const float* __restrict__ ea, const int* __restrict__ eid,
                          unsigned* __restrict__ eab){
  int i = blockIdx.x * 256 + threadIdx.x;
  if (i >= NE * 2) return;
  int p = i >> 1, half = i & 1;
  int e = eid[p];
  const float* s = ea + (size_t)e * 16 + half * 8;
  float4 a = *(const float4*)(s);
  float4 b = *(const float4*)(s + 4);
  uint4 o;
  o.x = f2bf(a.x) | (f2bf(a.y) << 16);
  o.y = f2bf(a.z) | (f2bf(a.w) << 16);
  o.z = f2bf(b.x) | (f2bf(b.y) << 16);
  o.w = f2bf(b.z) | (f2bf(b.w) << 16);
  ((uint4*)eab)[(size_t)p * 2 + half] = o;
}

__global__ void pack_k(const float* __restrict__ qw, const float* __restrict__ kw,
                       const float* __restrict__ vw, const float* __restrict__ skw,
                       const float* __restrict__ qb, const float* __restrict__ kb,
                       const float* __restrict__ vb, const float* __restrict__ skb,
                       float* __restrict__ Wp, float* __restrict__ bp, int D){
  int i = blockIdx.x * 256 + threadIdx.x;
  if (i < 512 * D){
    int c = i / D, d = i - c * D;
    const float* w = (c < 128) ? qw : (c < 256) ? kw : (c < 384) ? vw : skw;
    Wp[i] = w[(c & 127) * D + d];
  }
  if (i < 512){
    const float* b = (i < 128) ? qb : (i < 256) ? kb : (i < 384) ? vb : skb;
    bp[i] = b[i & 127];
  }
}

// pack k,v (bf16 pair in one uint) per (node, head, channel)
__global__ __launch_bounds__(256) void pack_kv_k(const float* __restrict__ qkvs,
                                                 unsigned* __restrict__ kvb){
  int i = blockIdx.x * 256 + threadIdx.x;
  if (i >= NN * 128) return;
  int n = i >> 7;
  int hl = i & 127;                 // h*64 + lane
  const float* base = qkvs + (size_t)n * 512;
  float k = base[128 + hl];
  float v = base[256 + hl];
  kvb[i] = f2bf(k) | (f2bf(v) << 16);
}

// qe[n, h, d] = (sum_c q[n,h,c] * ew[h*64+c, d]) * SCALE_L2E/8
__global__ __launch_bounds__(256) void qe_k(const float* __restrict__ qkvs,
    const float* __restrict__ ew, float* __restrict__ qe){
  __shared__ float ews[2048];
  int t = threadIdx.x;
  for (int i = t; i < 2048; i += 256) ews[i] = ew[i];
  __syncthreads();
  int g = t >> 5;            // node within block (8 nodes/block)
  int hd = t & 31;           // h*16 + d
  int h = hd >> 4, d = hd & 15;
  int n = blockIdx.x * 8 + g;
  if (n >= NN) return;
  const float* qp = qkvs + (size_t)n * 512 + h * 64;
  float s = 0.f;
  #pragma unroll 8
  for (int c = 0; c < 64; c++)
    s += qp[c] * ews[(h * 64 + c) * 16 + d];
  qe[(size_t)n * 32 + hd] = s * (SCALE_L2E / 8.0f);
}

// C[N,512] = A[N,D] @ Wp[512,D]^T + bp ; 64x64 tile, K staged by 64
template<int D>
__global__ __launch_bounds__(256) void gemm_k(const float* __restrict__ A,
                                              const float* __restrict__ W,
                                              const float* __restrict__ bp,
                                              float* __restrict__ C){
  __shared__ float As[64][65];
  __shared__ float Ws[64][65];
  int t = threadIdx.x;
  int tx = t & 15, ty = t >> 4;
  int brow = blockIdx.x * 64;
  int bcol = blockIdx.y * 64;
  float acc[4][4];
  #pragma unroll
  for (int i = 0; i < 4; i++)
    #pragma unroll
    for (int j = 0; j < 4; j++) acc[i][j] = 0.f;

  for (int kb = 0; kb < D; kb += 64){
    #pragma unroll
    for (int it = 0; it < 4; it++){
      int r = (t >> 4) + it * 16;
      int c4 = (t & 15) * 4;
      int gr = brow + r;
      float4 va = make_float4(0.f, 0.f, 0.f, 0.f);
      if (gr < NN) va = *(const float4*)(A + (size_t)gr * D + kb + c4);
      As[r][c4 + 0] = va.x; As[r][c4 + 1] = va.y; As[r][c4 + 2] = va.z; As[r][c4 + 3] = va.w;
      int wc = bcol + r;
      float4 vw = *(const float4*)(W + (size_t)wc * D + kb + c4);
      Ws[r][c4 + 0] = vw.x; Ws[r][c4 + 1] = vw.y; Ws[r][c4 + 2] = vw.z; Ws[r][c4 + 3] = vw.w;
    }
    __syncthreads();
    #pragma unroll 8
    for (int k = 0; k < 64; k++){
      float a0 = As[ty * 4 + 0][k], a1 = As[ty * 4 + 1][k];
      float a2 = As[ty * 4 + 2][k], a3 = As[ty * 4 + 3][k];
      float w0 = Ws[tx * 4 + 0][k], w1 = Ws[tx * 4 + 1][k];
      float w2 = Ws[tx * 4 + 2][k], w3 = Ws[tx * 4 + 3][k];
      acc[0][0] += a0 * w0; acc[0][1] += a0 * w1; acc[0][2] += a0 * w2; acc[0][3] += a0 * w3;
      acc[1][0] += a1 * w0; acc[1][1] += a1 * w1; acc[1][2] += a1 * w2; acc[1][3] += a1 * w3;
      acc[2][0] += a2 * w0; acc[2][1] += a2 * w1; acc[2][2] += a2 * w2; acc[2][3] += a2 * w3;
      acc[3][0] += a3 * w0; acc[3][1] += a3 * w1; acc[3][2] += a3 * w2; acc[3][3] += a3 * w3;
    }
    __syncthreads();
  }
  #pragma unroll
  for (int i = 0; i < 4; i++){
    int gr = brow + ty * 4 + i;
    if (gr < NN){
      #pragma unroll
      for (int j = 0; j < 4; j++){
        int gc = bcol + tx * 4 + j;
        C[(size_t)gr * 512 + gc] = acc[i][j] + bp[gc];
      }
    }
  }
}

// One wave per (node, head). lane = channel within head.
// logit = q.k + ea.qe (qe = ew^T q, precomputed, prescaled by log2e*scale/8).
// output e-contribution deferred: t[16] = sum_e w_e * ea_e, applied as ew @ t.
__global__ __launch_bounds__(256) void edge_k(const float* __restrict__ qkvs,
    const unsigned* __restrict__ kvb, const unsigned* __restrict__ eab,
    const float2* __restrict__ qe, const float* __restrict__ ew,
    const int* __restrict__ row_ptr, const int* __restrict__ src_s,
    float* __restrict__ attn){
  int wv = (blockIdx.x * 256 + threadIdx.x) >> 6;
  if (wv >= NN * 2) return;
  int lane = threadIdx.x & 63;
  int n = wv >> 1, h = wv & 1;
  float ewv[16];
  const float* ewrow = ew + ((size_t)(h * 64 + lane)) * 16;
  #pragma unroll
  for (int d = 0; d < 16; d += 4){
    float4 a = *(const float4*)(ewrow + d);
    ewv[d] = a.x; ewv[d + 1] = a.y; ewv[d + 2] = a.z; ewv[d + 3] = a.w;
  }
  float qsc = qkvs[(size_t)n * 512 + h * 64 + lane] * SCALE_L2E;
  float2 qev = qe[(size_t)wv * 8 + (lane & 7)];
  int beg = row_ptr[n], end = row_ptr[n + 1];
  int nb = end - beg;
  float acc = 0.f, den = 0.f, t0 = 0.f, t1 = 0.f;
  const unsigned* kvh = kvb + h * 64;
  const unsigned* eap = eab + (size_t)beg * 8 + (lane & 7);
  for (int cb = 0; cb < nb; cb += 64){
    int sv = (cb + lane < nb) ? src_s[beg + cb + lane] : 0;
    int m = min(64, nb - cb);
    int u = 0;
    for (; u + 8 <= m; u += 8){
      unsigned kvr[8], er[8];
      #pragma unroll
      for (int j = 0; j < 8; j++){
        int s = __shfl(sv, u + j);
        kvr[j] = kvh[(size_t)s * 128 + lane];
        er[j] = eap[(size_t)(cb + u + j) * 8];
      }
      #pragma unroll
      for (int j = 0; j < 8; j++){
        float kk  = __uint_as_float(kvr[j] << 16);
        float vv  = __uint_as_float(kvr[j] & 0xffff0000u);
        float ea0 = __uint_as_float(er[j] << 16);
        float ea1 = __uint_as_float(er[j] & 0xffff0000u);
        float p = qsc * kk + ea0 * qev.x + ea1 * qev.y;
        #pragma unroll
        for (int off = 32; off >= 1; off >>= 1) p += __shfl_xor(p, off);
        float w = exp2f(p);
        acc += vv * w; den += w;
        t0 += ea0 * w; t1 += ea1 * w;
      }
    }
    for (; u < m; u++){
      int s = __shfl(sv, u);
      unsigned kv = kvh[(size_t)s * 128 + lane];
      unsigned er0 = eap[(size_t)(cb + u) * 8];
      float kk  = __uint_as_float(kv << 16);
      float vv  = __uint_as_float(kv & 0xffff0000u);
      float ea0 = __uint_as_float(er0 << 16);
      float ea1 = __uint_as_float(er0 & 0xffff0000u);
      float p = qsc * kk + ea0 * qev.x + ea1 * qev.y;
      #pragma unroll
      for (int off = 32; off >= 1; off >>= 1) p += __shfl_xor(p, off);
      float w = exp2f(p);
      acc += vv * w; den += w;
      t0 += ea0 * w; t1 += ea1 * w;
    }
  }
  // out_c = (acc_c + sum_d ew[c,d] * t_d) / den ; t replicated per 8-lane group
  float extra = 0.f;
  #pragma unroll
  for (int j = 0; j < 8; j++){
    float tt0 = __shfl(t0, j);
    float tt1 = __shfl(t1, j);
    extra += ewv[2 * j] * tt0 + ewv[2 * j + 1] * tt1;
  }
  attn[(size_t)n * 128 + h * 64 + lane] = den > 0.f ? (acc + extra) / den : 0.f;
}

// beta-gate combine + [128->64] proj + leaky relu + BN partial sums.
__global__ __launch_bounds__(256) void combine_k(const float* __restrict__ attn,
    const float* __restrict__ qkvs, const float* __restrict__ bw,
    const float* __restrict__ tw, const float* __restrict__ tb,
    float* __restrict__ h2, float* __restrict__ bn_acc){
  __shared__ float twT[128][65];
  __shared__ float hcs[4][128];
  __shared__ float bsum[64], bsq[64];
  int t = threadIdx.x;
  int lane = t & 63, wv = t >> 6;
  for (int i = t; i < 64 * 128; i += 256){
    int j = i >> 7, k = i & 127;
    twT[k][j] = tw[i];
  }
  if (t < 64){ bsum[t] = 0.f; bsq[t] = 0.f; }
  __syncthreads();
  float bw0 = bw[lane],       bw1 = bw[64 + lane];
  float bwr0 = bw[128 + lane], bwr1 = bw[192 + lane];
  float bwd0 = bw[256 + lane], bwd1 = bw[320 + lane];
  float tbv = tb[lane];
  float rs = 0.f, rq = 0.f;
  int base_node = blockIdx.x * 16 + wv * 4;
  for (int it = 0; it < 4; it++){
    int n = base_node + it;
    bool valid = n < NN;
    float o0 = 0.f, o1 = 0.f, r0 = 0.f, r1 = 0.f;
    if (valid){
      o0 = attn[(size_t)n * 128 + lane];
      o1 = attn[(size_t)n * 128 + 64 + lane];
      r0 = qkvs[(size_t)n * 512 + 384 + lane];
      r1 = qkvs[(size_t)n * 512 + 448 + lane];
    }
    float p = o0 * bw0 + o1 * bw1 + r0 * bwr0 + r1 * bwr1 + (o0 - r0) * bwd0 + (o1 - r1) * bwd1;
    #pragma unroll
    for (int off = 32; off >= 1; off >>= 1) p += __shfl_xor(p, off);
    float beta = 1.f / (1.f + __expf(-p));
    float hc0 = beta * r0 + (1.f - beta) * o0;
    float hc1 = beta * r1 + (1.f - beta) * o1;
    hcs[wv][lane] = hc0;
    hcs[wv][64 + lane] = hc1;
    __syncthreads();
    float s = tbv;
    #pragma unroll 8
    for (int k = 0; k < 128; k++) s += hcs[wv][k] * twT[k][lane];
    __syncthreads();
    if (valid){
      float hv = s > 0.f ? s : 0.01f * s;
      h2[(size_t)n * 64 + lane] = hv;
      rs += hv; rq += hv * hv;
    }
  }
  atomicAdd(&bsum[lane], rs);
  atomicAdd(&bsq[lane], rq);
  __syncthreads();
  if (t < 64){
    atomicAdd(&bn_acc[t], bsum[t]);
    atomicAdd(&bn_acc[64 + t], bsq[t]);
  }
}

__global__ void bn_final_k(const float* __restrict__ bn_acc, const float* __restrict__ bnw,
                           const float* __restrict__ bnb, float* __restrict__ ss){
  int j = threadIdx.x;
  if (j < 64){
    float m = bn_acc[j] / (float)NN;
    float v = bn_acc[64 + j] / (float)NN - m * m;
    float sc = bnw[j] * rsqrtf(v + EPS_BN);
    ss[j] = sc;
    ss[64 + j] = bnb[j] - m * sc;
  }
}

__global__ __launch_bounds__(256) void bn_apply_k(const float* __restrict__ h2,
    const float* __restrict__ ss, const int* __restrict__ batch,
    float* __restrict__ h, float* __restrict__ gsum, unsigned* __restrict__ gmax,
    int do_pool){
  int wid = (blockIdx.x * 256 + threadIdx.x) >> 6;
  int lane = threadIdx.x & 63;
  const int CH = (NN + 1023) / 1024;
  int start = wid * CH;
  int end = start + CH; if (end > NN) end = NN;
  float sc = ss[lane], sh = ss[64 + lane];
  int curg = -1; float lmax = 0.f, lsum = 0.f;
  for (int n = start; n < end; n++){
    float v = h2[(size_t)n * 64 + lane] * sc + sh;
    h[(size_t)n * 64 + lane] = v;
    if (do_pool){
      int g = batch[n];
      if (g != curg){
        if (curg >= 0){
          atomicAdd(&gsum[curg * 64 + lane], lsum);
          atomicMax(&gmax[curg * 64 + lane], encf(lmax));
        }
        curg = g; lmax = v; lsum = v;
      } else {
        lmax = fmaxf(lmax, v); lsum += v;
      }
    }
  }
  if (do_pool && curg >= 0){
    atomicAdd(&gsum[curg * 64 + lane], lsum);
    atomicMax(&gmax[curg * 64 + lane], encf(lmax));
  }
}

__global__ void pool_final_k(const float* __restrict__ gsum, const unsigned* __restrict__ gmax,
                             const int* __restrict__ counts, float* __restrict__ gr){
  int i = blockIdx.x * 256 + threadIdx.x;
  if (i < NG * 64){
    int g = i >> 6, j = i & 63;
    unsigned e = gmax[i];
    float mx = e ? decf(e) : 0.f;
    int c = counts[g]; if (c < 1) c = 1;
    gr[g * 128 + j]       += mx;
    gr[g * 128 + 64 + j]  += gsum[i] / (float)c;
  }
}

extern "C" void kernel_launch(void* const* d_in, const int* in_sizes, int n_in,
                              void* d_out, int out_size, void* d_ws, size_t ws_size,
                              hipStream_t stream){
  const float* x     = (const float*)d_in[0];
  const float* ea    = (const float*)d_in[1];
  const int*   eidx  = (const int*)d_in[2];
  const int*   batch = (const int*)d_in[3];
  const float* c1_qw = (const float*)d_in[4];
  const float* c1_qb = (const float*)d_in[5];
  const float* c1_kw = (const float*)d_in[6];
  const float* c1_kb = (const float*)d_in[7];
  const float* c1_vw = (const float*)d_in[8];
  const float* c1_vb = (const float*)d_in[9];
  const float* c1_ew = (const float*)d_in[10];
  const float* c1_skw= (const float*)d_in[11];
  const float* c1_skb= (const float*)d_in[12];
  const float* c1_bw = (const float*)d_in[13];
  const float* c1_tw = (const float*)d_in[14];
  const float* c1_tb = (const float*)d_in[15];
  const float* c1_bnw= (const float*)d_in[16];
  const float* c1_bnb= (const float*)d_in[17];
  const float* L_qw  = (const float*)d_in[18];
  const float* L_qb  = (const float*)d_in[19];
  const float* L_kw  = (const float*)d_in[20];
  const float* L_kb  = (const float*)d_in[21];
  const float* L_vw  = (const float*)d_in[22];
  const float* L_vb  = (const float*)d_in[23];
  const float* L_ew  = (const float*)d_in[24];
  const float* L_skw = (const float*)d_in[25];
  const float* L_skb = (const float*)d_in[26];
  const float* L_bw  = (const float*)d_in[27];
  const float* L_tw  = (const float*)d_in[28];
  const float* L_tb  = (const float*)d_in[29];
  const float* L_bnw = (const float*)d_in[30];
  const float* L_bnb = (const float*)d_in[31];
  const int* srcs = eidx;
  const int* dsts = eidx + NE;

  char* p = (char*)d_ws;
  auto carve = [&](size_t bytes) -> void* {
    void* r = (void*)p;
    p += (bytes + 255) & ~(size_t)255;
    return r;
  };
  float*    Wp     = (float*)carve(512 * 128 * sizeof(float));
  float*    bp     = (float*)carve(512 * sizeof(float));
  float*    qkvs   = (float*)carve((size_t)NN * 512 * sizeof(float));
  unsigned* kvb    = (unsigned*)carve((size_t)NN * 128 * sizeof(unsigned));
  unsigned* eab    = (unsigned*)carve((size_t)NE * 8 * sizeof(unsigned));
  float*    qe     = (float*)carve((size_t)NN * 32 * sizeof(float));
  float*    attn   = (float*)carve((size_t)NN * 128 * sizeof(float));
  float*    h      = (float*)carve((size_t)NN * 64 * sizeof(float));
  float*    h2     = (float*)carve((size_t)NN * 64 * sizeof(float));
  float*    bn_acc = (float*)carve(128 * sizeof(float));
  float*    ss     = (float*)carve(128 * sizeof(float));
  float*    gsum   = (float*)carve((size_t)NG * 64 * sizeof(float));
  unsigned* gmax   = (unsigned*)carve((size_t)NG * 64 * sizeof(unsigned));
  int*      deg    = (int*)carve(NN * sizeof(int));
  int*      row_ptr= (int*)carve((NN + 1) * sizeof(int));
  int*      eid    = (int*)carve((size_t)NE * sizeof(int));
  int*      src_s  = (int*)carve((size_t)NE * sizeof(int));
  int*      counts = (int*)carve(NG * sizeof(int));
  int*      bsums  = (int*)carve(256 * sizeof(int));

  hipMemsetAsync(d_out, 0, (size_t)out_size * sizeof(float), stream);
  hipMemsetAsync(deg, 0, NN * sizeof(int), stream);
  hipMemsetAsync(counts, 0, NG * sizeof(int), stream);
  hist_k<<<(NE + 255) / 256, 256, 0, stream>>>(dsts, deg);
  counts_k<<<(NN + 255) / 256, 256, 0, stream>>>(batch, counts);
  scan1_k<<<SCAN_B, 256, 0, stream>>>(deg, bsums);
  scan2_k<<<1, 256, 0, stream>>>(bsums);
  scan3_k<<<SCAN_B, 256, 0, stream>>>(deg, bsums, row_ptr);
  cursor_k<<<(NN + 255) / 256, 256, 0, stream>>>(row_ptr, deg);   // reuse deg as cursor
  scatter_k<<<(NE + 255) / 256, 256, 0, stream>>>(dsts, srcs, deg, eid, src_s);
  pack_ea_k<<<(NE * 2 + 255) / 256, 256, 0, stream>>>(ea, eid, eab);

  const float* hin = x;
  for (int L = 0; L < 4; L++){
    int D = (L == 0) ? FIN : EMB;
    const float *qw,*qb,*kw,*kb,*vw,*vb,*eww,*skw,*skb,*bww,*tw,*tb,*bnw,*bnb;
    if (L == 0){
      qw=c1_qw; qb=c1_qb; kw=c1_kw; kb=c1_kb; vw=c1_vw; vb=c1_vb;
      eww=c1_ew; skw=c1_skw; skb=c1_skb; bww=c1_bw; tw=c1_tw; tb=c1_tb;
      bnw=c1_bnw; bnb=c1_bnb;
    } else {
      int i = L - 1;
      qw = L_qw + (size_t)i * HCC * EMB;  qb = L_qb + (size_t)i * HCC;
      kw = L_kw + (size_t)i * HCC * EMB;  kb = L_kb + (size_t)i * HCC;
      vw = L_vw + (size_t)i * HCC * EMB;  vb = L_vb + (size_t)i * HCC;
      eww= L_ew + (size_t)i * HCC * EDIM;
      skw= L_skw+ (size_t)i * HCC * EMB;  skb= L_skb+ (size_t)i * HCC;
      bww= L_bw + (size_t)i * 3 * HCC;
      tw = L_tw + (size_t)i * EMB * HCC;  tb = L_tb + (size_t)i * EMB;
      bnw= L_bnw+ (size_t)i * EMB;        bnb= L_bnb+ (size_t)i * EMB;
    }
    pack_k<<<(512 * D + 255) / 256, 256, 0, stream>>>(qw, kw, vw, skw, qb, kb, vb, skb, Wp, bp, D);
    dim3 gg((NN + 63) / 64, 8);
    if (D == 128) gemm_k<128><<<gg, 256, 0, stream>>>(hin, Wp, bp, qkvs);
    else          gemm_k<64><<<gg, 256, 0, stream>>>(hin, Wp, bp, qkvs);
    pack_kv_k<<<(NN * 128 + 255) / 256, 256, 0, stream>>>(qkvs, kvb);
    qe_k<<<(NN + 7) / 8, 256, 0, stream>>>(qkvs, eww, qe);
    edge_k<<<(NN * 2 * 64 + 255) / 256, 256, 0, stream>>>(qkvs, kvb, eab, (const float2*)qe, eww, row_ptr, src_s, attn);
    hipMemsetAsync(bn_acc, 0, 128 * sizeof(float), stream);
    combine_k<<<(NN + 15) / 16, 256, 0, stream>>>(attn, qkvs, bww, tw, tb, h2, bn_acc);
    bn_final_k<<<1, 64, 0, stream>>>(bn_acc, bnw, bnb, ss);
    if (L > 0) hipMemsetAsync(gsum, 0, 2 * NG * 64 * sizeof(float), stream);
    bn_apply_k<<<256, 256, 0, stream>>>(h2, ss, batch, h, gsum, gmax, (L > 0) ? 1 : 0);
    if (L > 0) pool_final_k<<<(NG * 64 + 255) / 256, 256, 0, stream>>>(gsum, gmax, counts, (float*)d_out);
    hin = h;
  }
}

// Round 6
// 1855.682 us; speedup vs baseline: 1.4178x; 1.1147x over previous
//
#include <hip/hip_runtime.h>

#define NN 50000
#define NE 800000
#define FIN 128
#define EDIM 16
#define EMB 64
#define NH 2
#define NLAYERS 3
#define NG 64
#define HCC 128
#define INV_SQRT_D 0.125f
#define EPS_BN 1e-5f
#define SCAN_B 196   // ceil(NN/256)
#define SCALE_L2E 0.18033688f   // 0.125 * log2(e)

typedef __attribute__((ext_vector_type(8))) short bf16x8;
typedef __attribute__((ext_vector_type(4))) float f32x4;

__device__ __forceinline__ unsigned encf(float f){
  unsigned u = __float_as_uint(f);
  return (u & 0x80000000u) ? ~u : (u | 0x80000000u);
}
__device__ __forceinline__ float decf(unsigned e){
  unsigned u = (e & 0x80000000u) ? (e ^ 0x80000000u) : ~e;
  return __uint_as_float(u);
}
__device__ __forceinline__ unsigned f2bf(float x){   // RNE bf16, returned in low 16
  unsigned u = __float_as_uint(x);
  return (u + 0x7fffu + ((u >> 16) & 1u)) >> 16;
}
// split fp32 -> hi + lo bf16 (a ~= hi + lo, |lo| <= 2^-9 |a|)
__device__ __forceinline__ void f2bf_split(float x, unsigned short* hi, unsigned short* lo){
  unsigned h = f2bf(x);
  float hf = __uint_as_float(h << 16);
  *hi = (unsigned short)h;
  *lo = (unsigned short)f2bf(x - hf);
}

__global__ void hist_k(const int* __restrict__ dst, int* __restrict__ deg){
  int i = blockIdx.x * 256 + threadIdx.x;
  if (i < NE) atomicAdd(&deg[dst[i]], 1);
}

// batch_index is sorted: group starts via boundary detection, no atomics.
__global__ void bounds_k(const int* __restrict__ batch, int* __restrict__ starts){
  int i = blockIdx.x * 256 + threadIdx.x;
  if (i >= NN) return;
  int g = batch[i];
  int gp = (i == 0) ? -1 : batch[i - 1];
  for (int gg = gp + 1; gg <= g; gg++) starts[gg] = i;
  if (i == NN - 1){
    for (int gg = g + 1; gg <= NG; gg++) starts[gg] = NN;
  }
}

__global__ void counts_from_starts_k(const int* __restrict__ starts, int* __restrict__ counts){
  int g = threadIdx.x;
  if (g < NG) counts[g] = starts[g + 1] - starts[g];
}

__global__ void scan1_k(const int* __restrict__ deg, int* __restrict__ bsums){
  __shared__ int lds[256];
  int b = blockIdx.x, t = threadIdx.x;
  int idx = b * 256 + t;
  lds[t] = (idx < NN) ? deg[idx] : 0;
  __syncthreads();
  for (int off = 128; off >= 1; off >>= 1){
    if (t < off) lds[t] += lds[t + off];
    __syncthreads();
  }
  if (t == 0) bsums[b] = lds[0];
}

__global__ void scan2_k(int* __restrict__ bsums){
  __shared__ int lds[256];
  int t = threadIdx.x;
  int v = (t < SCAN_B) ? bsums[t] : 0;
  int x = v;
  lds[t] = x;
  __syncthreads();
  for (int off = 1; off < 256; off <<= 1){
    int y = (t >= off) ? lds[t - off] : 0;
    __syncthreads();
    x += y;
    lds[t] = x;
    __syncthreads();
  }
  if (t < SCAN_B) bsums[t] = x - v;   // exclusive
}

__global__ void scan3_k(const int* __restrict__ deg, const int* __restrict__ bsums,
                        int* __restrict__ row_ptr){
  __shared__ int lds[256];
  int b = blockIdx.x, t = threadIdx.x;
  int idx = b * 256 + t;
  int v = (idx < NN) ? deg[idx] : 0;
  int x = v;
  lds[t] = x;
  __syncthreads();
  for (int off = 1; off < 256; off <<= 1){
    int y = (t >= off) ? lds[t - off] : 0;
    __syncthreads();
    x += y;
    lds[t] = x;
    __syncthreads();
  }
  if (idx <= NN) row_ptr[idx] = bsums[b] + x - v;
}

__global__ void cursor_k(const int* __restrict__ row_ptr, int* __restrict__ cur){
  int i = blockIdx.x * 256 + threadIdx.x;
  if (i < NN) cur[i] = row_ptr[i];
}

__global__ void scatter_k(const int* __restrict__ dst, const int* __restrict__ src,
                          int* __restrict__ cur, int* __restrict__ eid,
                          int* __restrict__ src_s){
  int i = blockIdx.x * 256 + threadIdx.x;
  if (i < NE){
    int p = atomicAdd(&cur[dst[i]], 1);
    eid[p] = i;
    src_s[p] = src[i];
  }
}

// edge_attr -> bf16, reordered into CSR position order. thread = (p, half-row)
__global__ void pack_ea_k(const float* __restrict__ ea, const int* __restrict__ eid,
                          unsigned* __restrict__ eab){
  int i = blockIdx.x * 256 + threadIdx.x;
  if (i >= NE * 2) return;
  int p = i >> 1, half = i & 1;
  int e = eid[p];
  const float* s = ea + (size_t)e * 16 + half * 8;
  float4 a = *(const float4*)(s);
  float4 b = *(const float4*)(s + 4);
  uint4 o;
  o.x = f2bf(a.x) | (f2bf(a.y) << 16);
  o.y = f2bf(a.z) | (f2bf(a.w) << 16);
  o.z = f2bf(b.x) | (f2bf(b.y) << 16);
  o.w = f2bf(b.z) | (f2bf(b.w) << 16);
  ((uint4*)eab)[(size_t)p * 2 + half] = o;
}

// fp32 -> split bf16 (x once per call)
__global__ void tobf_k(const float* __restrict__ in, unsigned short* __restrict__ hi,
                       unsigned short* __restrict__ lo, int n){
  int i = blockIdx.x * 256 + threadIdx.x;
  if (i < n) f2bf_split(in[i], &hi[i], &lo[i]);
}

// pack q/k/v/skip weights into split bf16 Wp_hi/Wp_lo[512][D] + fp32 bias bp[512]
__global__ void pack_k(const float* __restrict__ qw, const float* __restrict__ kw,
                       const float* __restrict__ vw, const float* __restrict__ skw,
                       const float* __restrict__ qb, const float* __restrict__ kb,
                       const float* __restrict__ vb, const float* __restrict__ skb,
                       unsigned short* __restrict__ Wh, unsigned short* __restrict__ Wl,
                       float* __restrict__ bp, int D){
  int i = blockIdx.x * 256 + threadIdx.x;
  if (i < 512 * D){
    int c = i / D, d = i - c * D;
    const float* w = (c < 128) ? qw : (c < 256) ? kw : (c < 384) ? vw : skw;
    f2bf_split(w[(c & 127) * D + d], &Wh[i], &Wl[i]);
  }
  if (i < 512){
    const float* b = (i < 128) ? qb : (i < 256) ? kb : (i < 384) ? vb : skb;
    bp[i] = b[i & 127];
  }
}

// pack k,v (bf16 pair in one uint) per (node, head, channel)
__global__ __launch_bounds__(256) void pack_kv_k(const float* __restrict__ qkvs,
                                                 unsigned* __restrict__ kvb){
  int i = blockIdx.x * 256 + threadIdx.x;
  if (i >= NN * 128) return;
  int n = i >> 7;
  int hl = i & 127;                 // h*64 + lane
  const float* base = qkvs + (size_t)n * 512;
  float k = base[128 + hl];
  float v = base[256 + hl];
  kvb[i] = f2bf(k) | (f2bf(v) << 16);
}

// qe[n, h, d] = (sum_c q[n,h,c] * ew[h*64+c, d]) * SCALE_L2E/8
__global__ __launch_bounds__(256) void qe_k(const float* __restrict__ qkvs,
    const float* __restrict__ ew, float* __restrict__ qe){
  __shared__ float ews[2048];
  int t = threadIdx.x;
  for (int i = t; i < 2048; i += 256) ews[i] = ew[i];
  __syncthreads();
  int g = t >> 5;            // node within block (8 nodes/block)
  int hd = t & 31;           // h*16 + d
  int h = hd >> 4, d = hd & 15;
  int n = blockIdx.x * 8 + g;
  if (n >= NN) return;
  const float* qp = qkvs + (size_t)n * 512 + h * 64;
  float s = 0.f;
  #pragma unroll 8
  for (int c = 0; c < 64; c++)
    s += qp[c] * ews[(h * 64 + c) * 16 + d];
  qe[(size_t)n * 32 + hd] = s * (SCALE_L2E / 8.0f);
}

// C[N,512] = A[N,D] @ W[512,D]^T + bp via split-bf16 MFMA:
// A ~= Ah+Al, W ~= Wh+Wl ; C ~= Ah*Wh + Al*Wh + Ah*Wl (al*wl dropped, ~1.6e-5 rel)
// Block = 4 waves; wave w computes rows [bx*64+w*16, +16) x 64 cols.
// A frag: row = lane&15, k = (lane>>4)*8 + j ; B frag: col = lane&15, same k.
// C/D: col = lane&15, row = (lane>>4)*4 + j  [verified layout, learn_hip m89]
template<int D>
__global__ __launch_bounds__(256) void gemm_k(const unsigned short* __restrict__ Ah,
                                              const unsigned short* __restrict__ Al,
                                              const unsigned short* __restrict__ Wh,
                                              const unsigned short* __restrict__ Wl,
                                              const float* __restrict__ bp,
                                              float* __restrict__ C){
  int t = threadIdx.x;
  int w = t >> 6, lane = t & 63;
  int brow = blockIdx.x * 64 + w * 16;
  int bcol = blockIdx.y * 64;
  int r = lane & 15, kg = lane >> 4;
  f32x4 acc0 = {0.f,0.f,0.f,0.f}, acc1 = {0.f,0.f,0.f,0.f};
  f32x4 acc2 = {0.f,0.f,0.f,0.f}, acc3 = {0.f,0.f,0.f,0.f};
  int arow = brow + r; if (arow >= NN) arow = NN - 1;
  size_t aoff = (size_t)arow * D + kg * 8;
  #pragma unroll
  for (int kb = 0; kb < D; kb += 32){
    bf16x8 avh = *(const bf16x8*)(Ah + aoff + kb);
    bf16x8 avl = *(const bf16x8*)(Al + aoff + kb);
    size_t woff = (size_t)(bcol + r) * D + kg * 8 + kb;
    bf16x8 bh0 = *(const bf16x8*)(Wh + woff);
    bf16x8 bh1 = *(const bf16x8*)(Wh + woff + (size_t)16 * D);
    bf16x8 bh2 = *(const bf16x8*)(Wh + woff + (size_t)32 * D);
    bf16x8 bh3 = *(const bf16x8*)(Wh + woff + (size_t)48 * D);
    bf16x8 bl0 = *(const bf16x8*)(Wl + woff);
    bf16x8 bl1 = *(const bf16x8*)(Wl + woff + (size_t)16 * D);
    bf16x8 bl2 = *(const bf16x8*)(Wl + woff + (size_t)32 * D);
    bf16x8 bl3 = *(const bf16x8*)(Wl + woff + (size_t)48 * D);
    acc0 = __builtin_amdgcn_mfma_f32_16x16x32_bf16(avh, bh0, acc0, 0, 0, 0);
    acc1 = __builtin_amdgcn_mfma_f32_16x16x32_bf16(avh, bh1, acc1, 0, 0, 0);
    acc2 = __builtin_amdgcn_mfma_f32_16x16x32_bf16(avh, bh2, acc2, 0, 0, 0);
    acc3 = __builtin_amdgcn_mfma_f32_16x16x32_bf16(avh, bh3, acc3, 0, 0, 0);
    acc0 = __builtin_amdgcn_mfma_f32_16x16x32_bf16(avl, bh0, acc0, 0, 0, 0);
    acc1 = __builtin_amdgcn_mfma_f32_16x16x32_bf16(avl, bh1, acc1, 0, 0, 0);
    acc2 = __builtin_amdgcn_mfma_f32_16x16x32_bf16(avl, bh2, acc2, 0, 0, 0);
    acc3 = __builtin_amdgcn_mfma_f32_16x16x32_bf16(avl, bh3, acc3, 0, 0, 0);
    acc0 = __builtin_amdgcn_mfma_f32_16x16x32_bf16(avh, bl0, acc0, 0, 0, 0);
    acc1 = __builtin_amdgcn_mfma_f32_16x16x32_bf16(avh, bl1, acc1, 0, 0, 0);
    acc2 = __builtin_amdgcn_mfma_f32_16x16x32_bf16(avh, bl2, acc2, 0, 0, 0);
    acc3 = __builtin_amdgcn_mfma_f32_16x16x32_bf16(avh, bl3, acc3, 0, 0, 0);
  }
  f32x4 accs[4] = {acc0, acc1, acc2, acc3};
  #pragma unroll
  for (int nf = 0; nf < 4; nf++){
    int col = bcol + nf * 16 + r;
    float bias = bp[col];
    #pragma unroll
    for (int j = 0; j < 4; j++){
      int row = brow + kg * 4 + j;
      if (row < NN) C[(size_t)row * 512 + col] = accs[nf][j] + bias;
    }
  }
}

// One wave per (node, head). lane = channel within head.
// logit = q.k + ea.qe (qe = ew^T q, precomputed, prescaled by log2e*scale/8).
// output e-contribution deferred: t[16] = sum_e w_e * ea_e, applied as ew @ t.
__global__ __launch_bounds__(256) void edge_k(const float* __restrict__ qkvs,
    const unsigned* __restrict__ kvb, const unsigned* __restrict__ eab,
    const float2* __restrict__ qe, const float* __restrict__ ew,
    const int* __restrict__ row_ptr, const int* __restrict__ src_s,
    float* __restrict__ attn){
  int wv = (blockIdx.x * 256 + threadIdx.x) >> 6;
  if (wv >= NN * 2) return;
  int lane = threadIdx.x & 63;
  int n = wv >> 1, h = wv & 1;
  float ewv[16];
  const float* ewrow = ew + ((size_t)(h * 64 + lane)) * 16;
  #pragma unroll
  for (int d = 0; d < 16; d += 4){
    float4 a = *(const float4*)(ewrow + d);
    ewv[d] = a.x; ewv[d + 1] = a.y; ewv[d + 2] = a.z; ewv[d + 3] = a.w;
  }
  float qsc = qkvs[(size_t)n * 512 + h * 64 + lane] * SCALE_L2E;
  float2 qev = qe[(size_t)wv * 8 + (lane & 7)];
  int beg = row_ptr[n], end = row_ptr[n + 1];
  int nb = end - beg;
  float acc = 0.f, den = 0.f, t0 = 0.f, t1 = 0.f;
  const unsigned* kvh = kvb + h * 64;
  const unsigned* eap = eab + (size_t)beg * 8 + (lane & 7);
  for (int cb = 0; cb < nb; cb += 64){
    int sv = (cb + lane < nb) ? src_s[beg + cb + lane] : 0;
    int m = min(64, nb - cb);
    int u = 0;
    for (; u + 8 <= m; u += 8){
      unsigned kvr[8], er[8];
      #pragma unroll
      for (int j = 0; j < 8; j++){
        int s = __shfl(sv, u + j);
        kvr[j] = kvh[(size_t)s * 128 + lane];
        er[j] = eap[(size_t)(cb + u + j) * 8];
      }
      #pragma unroll
      for (int j = 0; j < 8; j++){
        float kk  = __uint_as_float(kvr[j] << 16);
        float vv  = __uint_as_float(kvr[j] & 0xffff0000u);
        float ea0 = __uint_as_float(er[j] << 16);
        float ea1 = __uint_as_float(er[j] & 0xffff0000u);
        float p = qsc * kk + ea0 * qev.x + ea1 * qev.y;
        #pragma unroll
        for (int off = 32; off >= 1; off >>= 1) p += __shfl_xor(p, off);
        float w = exp2f(p);
        acc += vv * w; den += w;
        t0 += ea0 * w; t1 += ea1 * w;
      }
    }
    for (; u < m; u++){
      int s = __shfl(sv, u);
      unsigned kv = kvh[(size_t)s * 128 + lane];
      unsigned er0 = eap[(size_t)(cb + u) * 8];
      float kk  = __uint_as_float(kv << 16);
      float vv  = __uint_as_float(kv & 0xffff0000u);
      float ea0 = __uint_as_float(er0 << 16);
      float ea1 = __uint_as_float(er0 & 0xffff0000u);
      float p = qsc * kk + ea0 * qev.x + ea1 * qev.y;
      #pragma unroll
      for (int off = 32; off >= 1; off >>= 1) p += __shfl_xor(p, off);
      float w = exp2f(p);
      acc += vv * w; den += w;
      t0 += ea0 * w; t1 += ea1 * w;
    }
  }
  // out_c = (acc_c + sum_d ew[c,d] * t_d) / den ; t replicated per 8-lane group
  float extra = 0.f;
  #pragma unroll
  for (int j = 0; j < 8; j++){
    float tt0 = __shfl(t0, j);
    float tt1 = __shfl(t1, j);
    extra += ewv[2 * j] * tt0 + ewv[2 * j + 1] * tt1;
  }
  attn[(size_t)n * 128 + h * 64 + lane] = den > 0.f ? (acc + extra) / den : 0.f;
}

// beta-gate combine + [128->64] proj + leaky relu + BN partial sums.
__global__ __launch_bounds__(256) void combine_k(const float* __restrict__ attn,
    const float* __restrict__ qkvs, const float* __restrict__ bw,
    const float* __restrict__ tw, const float* __restrict__ tb,
    float* __restrict__ h2, float* __restrict__ bn_acc){
  __shared__ float twT[128][65];
  __shared__ float hcs[4][128];
  __shared__ float bsum[64], bsq[64];
  int t = threadIdx.x;
  int lane = t & 63, wv = t >> 6;
  for (int i = t; i < 64 * 128; i += 256){
    int j = i >> 7, k = i & 127;
    twT[k][j] = tw[i];
  }
  if (t < 64){ bsum[t] = 0.f; bsq[t] = 0.f; }
  __syncthreads();
  float bw0 = bw[lane],       bw1 = bw[64 + lane];
  float bwr0 = bw[128 + lane], bwr1 = bw[192 + lane];
  float bwd0 = bw[256 + lane], bwd1 = bw[320 + lane];
  float tbv = tb[lane];
  float rs = 0.f, rq = 0.f;
  int base_node = blockIdx.x * 16 + wv * 4;
  for (int it = 0; it < 4; it++){
    int n = base_node + it;
    bool valid = n < NN;
    float o0 = 0.f, o1 = 0.f, r0 = 0.f, r1 = 0.f;
    if (valid){
      o0 = attn[(size_t)n * 128 + lane];
      o1 = attn[(size_t)n * 128 + 64 + lane];
      r0 = qkvs[(size_t)n * 512 + 384 + lane];
      r1 = qkvs[(size_t)n * 512 + 448 + lane];
    }
    float p = o0 * bw0 + o1 * bw1 + r0 * bwr0 + r1 * bwr1 + (o0 - r0) * bwd0 + (o1 - r1) * bwd1;
    #pragma unroll
    for (int off = 32; off >= 1; off >>= 1) p += __shfl_xor(p, off);
    float beta = 1.f / (1.f + __expf(-p));
    float hc0 = beta * r0 + (1.f - beta) * o0;
    float hc1 = beta * r1 + (1.f - beta) * o1;
    hcs[wv][lane] = hc0;
    hcs[wv][64 + lane] = hc1;
    __syncthreads();
    float s = tbv;
    #pragma unroll 8
    for (int k = 0; k < 128; k++) s += hcs[wv][k] * twT[k][lane];
    __syncthreads();
    if (valid){
      float hv = s > 0.f ? s : 0.01f * s;
      h2[(size_t)n * 64 + lane] = hv;
      rs += hv; rq += hv * hv;
    }
  }
  atomicAdd(&bsum[lane], rs);
  atomicAdd(&bsq[lane], rq);
  __syncthreads();
  if (t < 64){
    atomicAdd(&bn_acc[t], bsum[t]);
    atomicAdd(&bn_acc[64 + t], bsq[t]);
  }
}

__global__ void bn_final_k(const float* __restrict__ bn_acc, const float* __restrict__ bnw,
                           const float* __restrict__ bnb, float* __restrict__ ss){
  int j = threadIdx.x;
  if (j < 64){
    float m = bn_acc[j] / (float)NN;
    float v = bn_acc[64 + j] / (float)NN - m * m;
    float sc = bnw[j] * rsqrtf(v + EPS_BN);
    ss[j] = sc;
    ss[64 + j] = bnb[j] - m * sc;
  }
}

// BN apply -> split bf16 h (next-layer GEMM input) + pooled max/sum (sorted batch)
__global__ __launch_bounds__(256) void bn_apply_k(const float* __restrict__ h2,
    const float* __restrict__ ss, const int* __restrict__ batch,
    unsigned short* __restrict__ hbh, unsigned short* __restrict__ hbl,
    float* __restrict__ gsum, unsigned* __restrict__ gmax,
    int do_pool){
  int wid = (blockIdx.x * 256 + threadIdx.x) >> 6;
  int lane = threadIdx.x & 63;
  const int CH = (NN + 1023) / 1024;
  int start = wid * CH;
  int end = start + CH; if (end > NN) end = NN;
  float sc = ss[lane], sh = ss[64 + lane];
  int curg = -1; float lmax = 0.f, lsum = 0.f;
  for (int n = start; n < end; n++){
    float v = h2[(size_t)n * 64 + lane] * sc + sh;
    f2bf_split(v, &hbh[(size_t)n * 64 + lane], &hbl[(size_t)n * 64 + lane]);
    if (do_pool){
      int g = batch[n];
      if (g != curg){
        if (curg >= 0){
          atomicAdd(&gsum[curg * 64 + lane], lsum);
          atomicMax(&gmax[curg * 64 + lane], encf(lmax));
        }
        curg = g; lmax = v; lsum = v;
      } else {
        lmax = fmaxf(lmax, v); lsum += v;
      }
    }
  }
  if (do_pool && curg >= 0){
    atomicAdd(&gsum[curg * 64 + lane], lsum);
    atomicMax(&gmax[curg * 64 + lane], encf(lmax));
  }
}

__global__ void pool_final_k(const float* __restrict__ gsum, const unsigned* __restrict__ gmax,
                             const int* __restrict__ counts, float* __restrict__ gr){
  int i = blockIdx.x * 256 + threadIdx.x;
  if (i < NG * 64){
    int g = i >> 6, j = i & 63;
    unsigned e = gmax[i];
    float mx = e ? decf(e) : 0.f;
    int c = counts[g]; if (c < 1) c = 1;
    gr[g * 128 + j]       += mx;
    gr[g * 128 + 64 + j]  += gsum[i] / (float)c;
  }
}

extern "C" void kernel_launch(void* const* d_in, const int* in_sizes, int n_in,
                              void* d_out, int out_size, void* d_ws, size_t ws_size,
                              hipStream_t stream){
  const float* x     = (const float*)d_in[0];
  const float* ea    = (const float*)d_in[1];
  const int*   eidx  = (const int*)d_in[2];
  const int*   batch = (const int*)d_in[3];
  const float* c1_qw = (const float*)d_in[4];
  const float* c1_qb = (const float*)d_in[5];
  const float* c1_kw = (const float*)d_in[6];
  const float* c1_kb = (const float*)d_in[7];
  const float* c1_vw = (const float*)d_in[8];
  const float* c1_vb = (const float*)d_in[9];
  const float* c1_ew = (const float*)d_in[10];
  const float* c1_skw= (const float*)d_in[11];
  const float* c1_skb= (const float*)d_in[12];
  const float* c1_bw = (const float*)d_in[13];
  const float* c1_tw = (const float*)d_in[14];
  const float* c1_tb = (const float*)d_in[15];
  const float* c1_bnw= (const float*)d_in[16];
  const float* c1_bnb= (const float*)d_in[17];
  const float* L_qw  = (const float*)d_in[18];
  const float* L_qb  = (const float*)d_in[19];
  const float* L_kw  = (const float*)d_in[20];
  const float* L_kb  = (const float*)d_in[21];
  const float* L_vw  = (const float*)d_in[22];
  const float* L_vb  = (const float*)d_in[23];
  const float* L_ew  = (const float*)d_in[24];
  const float* L_skw = (const float*)d_in[25];
  const float* L_skb = (const float*)d_in[26];
  const float* L_bw  = (const float*)d_in[27];
  const float* L_tw  = (const float*)d_in[28];
  const float* L_tb  = (const float*)d_in[29];
  const float* L_bnw = (const float*)d_in[30];
  const float* L_bnb = (const float*)d_in[31];
  const int* srcs = eidx;
  const int* dsts = eidx + NE;

  char* p = (char*)d_ws;
  auto carve = [&](size_t bytes) -> void* {
    void* r = (void*)p;
    p += (bytes + 255) & ~(size_t)255;
    return r;
  };
  unsigned short* Wh = (unsigned short*)carve(512 * 128 * sizeof(unsigned short));
  unsigned short* Wl = (unsigned short*)carve(512 * 128 * sizeof(unsigned short));
  float*    bp     = (float*)carve(512 * sizeof(float));
  float*    qkvs   = (float*)carve((size_t)NN * 512 * sizeof(float));
  unsigned* kvb    = (unsigned*)carve((size_t)NN * 128 * sizeof(unsigned));
  unsigned* eab    = (unsigned*)carve((size_t)NE * 8 * sizeof(unsigned));
  float*    qe     = (float*)carve((size_t)NN * 32 * sizeof(float));
  float*    attn   = (float*)carve((size_t)NN * 128 * sizeof(float));
  unsigned short* xbh = (unsigned short*)carve((size_t)NN * FIN * sizeof(unsigned short));
  unsigned short* xbl = (unsigned short*)carve((size_t)NN * FIN * sizeof(unsigned short));
  unsigned short* hbh = (unsigned short*)carve((size_t)NN * 64 * sizeof(unsigned short));
  unsigned short* hbl = (unsigned short*)carve((size_t)NN * 64 * sizeof(unsigned short));
  float*    h2     = (float*)carve((size_t)NN * 64 * sizeof(float));
  float*    bn_acc = (float*)carve(128 * sizeof(float));
  float*    ss     = (float*)carve(128 * sizeof(float));
  float*    gsum   = (float*)carve((size_t)NG * 64 * sizeof(float));
  unsigned* gmax   = (unsigned*)carve((size_t)NG * 64 * sizeof(unsigned));
  int*      deg    = (int*)carve(NN * sizeof(int));
  int*      row_ptr= (int*)carve((NN + 1) * sizeof(int));
  int*      eid    = (int*)carve((size_t)NE * sizeof(int));
  int*      src_s  = (int*)carve((size_t)NE * sizeof(int));
  int*      counts = (int*)carve(NG * sizeof(int));
  int*      starts = (int*)carve((NG + 1) * sizeof(int));
  int*      bsums  = (int*)carve(256 * sizeof(int));

  hipMemsetAsync(d_out, 0, (size_t)out_size * sizeof(float), stream);
  hipMemsetAsync(deg, 0, NN * sizeof(int), stream);
  hist_k<<<(NE + 255) / 256, 256, 0, stream>>>(dsts, deg);
  bounds_k<<<(NN + 255) / 256, 256, 0, stream>>>(batch, starts);
  counts_from_starts_k<<<1, 64, 0, stream>>>(starts, counts);
  scan1_k<<<SCAN_B, 256, 0, stream>>>(deg, bsums);
  scan2_k<<<1, 256, 0, stream>>>(bsums);
  scan3_k<<<SCAN_B, 256, 0, stream>>>(deg, bsums, row_ptr);
  cursor_k<<<(NN + 255) / 256, 256, 0, stream>>>(row_ptr, deg);   // reuse deg as cursor
  scatter_k<<<(NE + 255) / 256, 256, 0, stream>>>(dsts, srcs, deg, eid, src_s);
  pack_ea_k<<<(NE * 2 + 255) / 256, 256, 0, stream>>>(ea, eid, eab);
  tobf_k<<<(NN * FIN + 255) / 256, 256, 0, stream>>>(x, xbh, xbl, NN * FIN);

  const unsigned short* hin_h = xbh;
  const unsigned short* hin_l = xbl;
  for (int L = 0; L < 4; L++){
    int D = (L == 0) ? FIN : EMB;
    const float *qw,*qb,*kw,*kb,*vw,*vb,*eww,*skw,*skb,*bww,*tw,*tb,*bnw,*bnb;
    if (L == 0){
      qw=c1_qw; qb=c1_qb; kw=c1_kw; kb=c1_kb; vw=c1_vw; vb=c1_vb;
      eww=c1_ew; skw=c1_skw; skb=c1_skb; bww=c1_bw; tw=c1_tw; tb=c1_tb;
      bnw=c1_bnw; bnb=c1_bnb;
    } else {
      int i = L - 1;
      qw = L_qw + (size_t)i * HCC * EMB;  qb = L_qb + (size_t)i * HCC;
      kw = L_kw + (size_t)i * HCC * EMB;  kb = L_kb + (size_t)i * HCC;
      vw = L_vw + (size_t)i * HCC * EMB;  vb = L_vb + (size_t)i * HCC;
      eww= L_ew + (size_t)i * HCC * EDIM;
      skw= L_skw+ (size_t)i * HCC * EMB;  skb= L_skb+ (size_t)i * HCC;
      bww= L_bw + (size_t)i * 3 * HCC;
      tw = L_tw + (size_t)i * EMB * HCC;  tb = L_tb + (size_t)i * EMB;
      bnw= L_bnw+ (size_t)i * EMB;        bnb= L_bnb+ (size_t)i * EMB;
    }
    pack_k<<<(512 * D + 255) / 256, 256, 0, stream>>>(qw, kw, vw, skw, qb, kb, vb, skb, Wh, Wl, bp, D);
    dim3 gg((NN + 63) / 64, 8);
    if (D == 128) gemm_k<128><<<gg, 256, 0, stream>>>(hin_h, hin_l, Wh, Wl, bp, qkvs);
    else          gemm_k<64><<<gg, 256, 0, stream>>>(hin_h, hin_l, Wh, Wl, bp, qkvs);
    pack_kv_k<<<(NN * 128 + 255) / 256, 256, 0, stream>>>(qkvs, kvb);
    qe_k<<<(NN + 7) / 8, 256, 0, stream>>>(qkvs, eww, qe);
    edge_k<<<(NN * 2 * 64 + 255) / 256, 256, 0, stream>>>(qkvs, kvb, eab, (const float2*)qe, eww, row_ptr, src_s, attn);
    hipMemsetAsync(bn_acc, 0, 128 * sizeof(float), stream);
    combine_k<<<(NN + 15) / 16, 256, 0, stream>>>(attn, qkvs, bww, tw, tb, h2, bn_acc);
    bn_final_k<<<1, 64, 0, stream>>>(bn_acc, bnw, bnb, ss);
    if (L > 0) hipMemsetAsync(gsum, 0, 2 * NG * 64 * sizeof(float), stream);
    bn_apply_k<<<256, 256, 0, stream>>>(h2, ss, batch, hbh, hbl, gsum, gmax, (L > 0) ? 1 : 0);
    if (L > 0) pool_final_k<<<(NG * 64 + 255) / 256, 256, 0, stream>>>(gsum, gmax, counts, (float*)d_out);
    hin_h = hbh; hin_l = hbl;
  }
}

// Round 7
// 1474.433 us; speedup vs baseline: 1.7844x; 1.2586x over previous
//
#include <hip/hip_runtime.h>

#define NN 50000
#define NE 800000
#define FIN 128
#define EDIM 16
#define EMB 64
#define NH 2
#define NLAYERS 3
#define NG 64
#define HCC 128
#define INV_SQRT_D 0.125f
#define EPS_BN 1e-5f
#define SCAN_B 196   // ceil(NN/256)
#define SCALE_L2E 0.18033688f   // 0.125 * log2(e)

typedef __attribute__((ext_vector_type(8))) short bf16x8;
typedef __attribute__((ext_vector_type(4))) float f32x4;

__device__ __forceinline__ unsigned encf(float f){
  unsigned u = __float_as_uint(f);
  return (u & 0x80000000u) ? ~u : (u | 0x80000000u);
}
__device__ __forceinline__ float decf(unsigned e){
  unsigned u = (e & 0x80000000u) ? (e ^ 0x80000000u) : ~e;
  return __uint_as_float(u);
}
__device__ __forceinline__ unsigned f2bf(float x){   // RNE bf16, returned in low 16
  unsigned u = __float_as_uint(x);
  return (u + 0x7fffu + ((u >> 16) & 1u)) >> 16;
}
// split fp32 -> hi + lo bf16 (a ~= hi + lo, |lo| <= 2^-9 |a|)
__device__ __forceinline__ void f2bf_split(float x, unsigned short* hi, unsigned short* lo){
  unsigned h = f2bf(x);
  float hf = __uint_as_float(h << 16);
  *hi = (unsigned short)h;
  *lo = (unsigned short)f2bf(x - hf);
}

__global__ void hist_k(const int* __restrict__ dst, int* __restrict__ deg){
  int i = blockIdx.x * 256 + threadIdx.x;
  if (i < NE) atomicAdd(&deg[dst[i]], 1);
}

// batch_index is sorted: group starts via boundary detection, no atomics.
__global__ void bounds_k(const int* __restrict__ batch, int* __restrict__ starts){
  int i = blockIdx.x * 256 + threadIdx.x;
  if (i >= NN) return;
  int g = batch[i];
  int gp = (i == 0) ? -1 : batch[i - 1];
  for (int gg = gp + 1; gg <= g; gg++) starts[gg] = i;
  if (i == NN - 1){
    for (int gg = g + 1; gg <= NG; gg++) starts[gg] = NN;
  }
}

__global__ void counts_from_starts_k(const int* __restrict__ starts, int* __restrict__ counts){
  int g = threadIdx.x;
  if (g < NG) counts[g] = starts[g + 1] - starts[g];
}

__global__ void scan1_k(const int* __restrict__ deg, int* __restrict__ bsums){
  __shared__ int lds[256];
  int b = blockIdx.x, t = threadIdx.x;
  int idx = b * 256 + t;
  lds[t] = (idx < NN) ? deg[idx] : 0;
  __syncthreads();
  for (int off = 128; off >= 1; off >>= 1){
    if (t < off) lds[t] += lds[t + off];
    __syncthreads();
  }
  if (t == 0) bsums[b] = lds[0];
}

__global__ void scan2_k(int* __restrict__ bsums){
  __shared__ int lds[256];
  int t = threadIdx.x;
  int v = (t < SCAN_B) ? bsums[t] : 0;
  int x = v;
  lds[t] = x;
  __syncthreads();
  for (int off = 1; off < 256; off <<= 1){
    int y = (t >= off) ? lds[t - off] : 0;
    __syncthreads();
    x += y;
    lds[t] = x;
    __syncthreads();
  }
  if (t < SCAN_B) bsums[t] = x - v;   // exclusive
}

__global__ void scan3_k(const int* __restrict__ deg, const int* __restrict__ bsums,
                        int* __restrict__ row_ptr){
  __shared__ int lds[256];
  int b = blockIdx.x, t = threadIdx.x;
  int idx = b * 256 + t;
  int v = (idx < NN) ? deg[idx] : 0;
  int x = v;
  lds[t] = x;
  __syncthreads();
  for (int off = 1; off < 256; off <<= 1){
    int y = (t >= off) ? lds[t - off] : 0;
    __syncthreads();
    x += y;
    lds[t] = x;
    __syncthreads();
  }
  if (idx <= NN) row_ptr[idx] = bsums[b] + x - v;
}

__global__ void cursor_k(const int* __restrict__ row_ptr, int* __restrict__ cur){
  int i = blockIdx.x * 256 + threadIdx.x;
  if (i < NN) cur[i] = row_ptr[i];
}

__global__ void scatter_k(const int* __restrict__ dst, const int* __restrict__ src,
                          int* __restrict__ cur, int* __restrict__ eid,
                          int* __restrict__ src_s){
  int i = blockIdx.x * 256 + threadIdx.x;
  if (i < NE){
    int p = atomicAdd(&cur[dst[i]], 1);
    eid[p] = i;
    src_s[p] = src[i];
  }
}

// edge_attr -> bf16, reordered into CSR position order. thread = (p, half-row)
__global__ void pack_ea_k(const float* __restrict__ ea, const int* __restrict__ eid,
                          unsigned* __restrict__ eab){
  int i = blockIdx.x * 256 + threadIdx.x;
  if (i >= NE * 2) return;
  int p = i >> 1, half = i & 1;
  int e = eid[p];
  const float* s = ea + (size_t)e * 16 + half * 8;
  float4 a = *(const float4*)(s);
  float4 b = *(const float4*)(s + 4);
  uint4 o;
  o.x = f2bf(a.x) | (f2bf(a.y) << 16);
  o.y = f2bf(a.z) | (f2bf(a.w) << 16);
  o.z = f2bf(b.x) | (f2bf(b.y) << 16);
  o.w = f2bf(b.z) | (f2bf(b.w) << 16);
  ((uint4*)eab)[(size_t)p * 2 + half] = o;
}

// fp32 -> split bf16 (x once per call)
__global__ void tobf_k(const float* __restrict__ in, unsigned short* __restrict__ hi,
                       unsigned short* __restrict__ lo, int n){
  int i = blockIdx.x * 256 + threadIdx.x;
  if (i < n) f2bf_split(in[i], &hi[i], &lo[i]);
}

// pack q/k/v/skip weights into split bf16 Wp_hi/Wp_lo[512][D] + fp32 bias bp[512]
__global__ void pack_k(const float* __restrict__ qw, const float* __restrict__ kw,
                       const float* __restrict__ vw, const float* __restrict__ skw,
                       const float* __restrict__ qb, const float* __restrict__ kb,
                       const float* __restrict__ vb, const float* __restrict__ skb,
                       unsigned short* __restrict__ Wh, unsigned short* __restrict__ Wl,
                       float* __restrict__ bp, int D){
  int i = blockIdx.x * 256 + threadIdx.x;
  if (i < 512 * D){
    int c = i / D, d = i - c * D;
    const float* w = (c < 128) ? qw : (c < 256) ? kw : (c < 384) ? vw : skw;
    f2bf_split(w[(c & 127) * D + d], &Wh[i], &Wl[i]);
  }
  if (i < 512){
    const float* b = (i < 128) ? qb : (i < 256) ? kb : (i < 384) ? vb : skb;
    bp[i] = b[i & 127];
  }
}

// pack k,v (bf16 pair in one uint) per (node, head, channel)
__global__ __launch_bounds__(256) void pack_kv_k(const float* __restrict__ qkvs,
                                                 unsigned* __restrict__ kvb){
  int i = blockIdx.x * 256 + threadIdx.x;
  if (i >= NN * 128) return;
  int n = i >> 7;
  int hl = i & 127;                 // h*64 + lane
  const float* base = qkvs + (size_t)n * 512;
  float k = base[128 + hl];
  float v = base[256 + hl];
  kvb[i] = f2bf(k) | (f2bf(v) << 16);
}

// qe[n, h, d] = (sum_c q[n,h,c] * ew[h*64+c, d]) * SCALE_L2E
__global__ __launch_bounds__(256) void qe_k(const float* __restrict__ qkvs,
    const float* __restrict__ ew, float* __restrict__ qe){
  __shared__ float ews[2048];
  int t = threadIdx.x;
  for (int i = t; i < 2048; i += 256) ews[i] = ew[i];
  __syncthreads();
  int g = t >> 5;            // node within block (8 nodes/block)
  int hd = t & 31;           // h*16 + d
  int h = hd >> 4, d = hd & 15;
  int n = blockIdx.x * 8 + g;
  if (n >= NN) return;
  const float* qp = qkvs + (size_t)n * 512 + h * 64;
  float s = 0.f;
  #pragma unroll 8
  for (int c = 0; c < 64; c++)
    s += qp[c] * ews[(h * 64 + c) * 16 + d];
  qe[(size_t)n * 32 + hd] = s * SCALE_L2E;
}

// ewT[h][d][c] = ew[h*64+c][d]  (transposed, for edge_k epilogue float4 loads)
__global__ void ewt_k(const float* __restrict__ ew, float* __restrict__ ewT){
  int i = blockIdx.x * 256 + threadIdx.x;
  if (i < 2048){
    int c = i >> 4, d = i & 15;          // c = h*64 + ch
    ewT[((c >> 6) * 16 + d) * 64 + (c & 63)] = ew[i];
  }
}

// C[N,512] = A[N,D] @ W[512,D]^T + bp via split-bf16 MFMA:
// A ~= Ah+Al, W ~= Wh+Wl ; C ~= Ah*Wh + Al*Wh + Ah*Wl (al*wl dropped, ~1.6e-5 rel)
template<int D>
__global__ __launch_bounds__(256) void gemm_k(const unsigned short* __restrict__ Ah,
                                              const unsigned short* __restrict__ Al,
                                              const unsigned short* __restrict__ Wh,
                                              const unsigned short* __restrict__ Wl,
                                              const float* __restrict__ bp,
                                              float* __restrict__ C){
  int t = threadIdx.x;
  int w = t >> 6, lane = t & 63;
  int brow = blockIdx.x * 64 + w * 16;
  int bcol = blockIdx.y * 64;
  int r = lane & 15, kg = lane >> 4;
  f32x4 acc0 = {0.f,0.f,0.f,0.f}, acc1 = {0.f,0.f,0.f,0.f};
  f32x4 acc2 = {0.f,0.f,0.f,0.f}, acc3 = {0.f,0.f,0.f,0.f};
  int arow = brow + r; if (arow >= NN) arow = NN - 1;
  size_t aoff = (size_t)arow * D + kg * 8;
  #pragma unroll
  for (int kb = 0; kb < D; kb += 32){
    bf16x8 avh = *(const bf16x8*)(Ah + aoff + kb);
    bf16x8 avl = *(const bf16x8*)(Al + aoff + kb);
    size_t woff = (size_t)(bcol + r) * D + kg * 8 + kb;
    bf16x8 bh0 = *(const bf16x8*)(Wh + woff);
    bf16x8 bh1 = *(const bf16x8*)(Wh + woff + (size_t)16 * D);
    bf16x8 bh2 = *(const bf16x8*)(Wh + woff + (size_t)32 * D);
    bf16x8 bh3 = *(const bf16x8*)(Wh + woff + (size_t)48 * D);
    bf16x8 bl0 = *(const bf16x8*)(Wl + woff);
    bf16x8 bl1 = *(const bf16x8*)(Wl + woff + (size_t)16 * D);
    bf16x8 bl2 = *(const bf16x8*)(Wl + woff + (size_t)32 * D);
    bf16x8 bl3 = *(const bf16x8*)(Wl + woff + (size_t)48 * D);
    acc0 = __builtin_amdgcn_mfma_f32_16x16x32_bf16(avh, bh0, acc0, 0, 0, 0);
    acc1 = __builtin_amdgcn_mfma_f32_16x16x32_bf16(avh, bh1, acc1, 0, 0, 0);
    acc2 = __builtin_amdgcn_mfma_f32_16x16x32_bf16(avh, bh2, acc2, 0, 0, 0);
    acc3 = __builtin_amdgcn_mfma_f32_16x16x32_bf16(avh, bh3, acc3, 0, 0, 0);
    acc0 = __builtin_amdgcn_mfma_f32_16x16x32_bf16(avl, bh0, acc0, 0, 0, 0);
    acc1 = __builtin_amdgcn_mfma_f32_16x16x32_bf16(avl, bh1, acc1, 0, 0, 0);
    acc2 = __builtin_amdgcn_mfma_f32_16x16x32_bf16(avl, bh2, acc2, 0, 0, 0);
    acc3 = __builtin_amdgcn_mfma_f32_16x16x32_bf16(avl, bh3, acc3, 0, 0, 0);
    acc0 = __builtin_amdgcn_mfma_f32_16x16x32_bf16(avh, bl0, acc0, 0, 0, 0);
    acc1 = __builtin_amdgcn_mfma_f32_16x16x32_bf16(avh, bl1, acc1, 0, 0, 0);
    acc2 = __builtin_amdgcn_mfma_f32_16x16x32_bf16(avh, bl2, acc2, 0, 0, 0);
    acc3 = __builtin_amdgcn_mfma_f32_16x16x32_bf16(avh, bl3, acc3, 0, 0, 0);
  }
  f32x4 accs[4] = {acc0, acc1, acc2, acc3};
  #pragma unroll
  for (int nf = 0; nf < 4; nf++){
    int col = bcol + nf * 16 + r;
    float bias = bp[col];
    #pragma unroll
    for (int j = 0; j < 4; j++){
      int row = brow + kg * 4 + j;
      if (row < NN) C[(size_t)row * 512 + col] = accs[nf][j] + bias;
    }
  }
}

// One wave per (node, head). 4 edges per wave iteration: 16 lanes per edge
// (grp = lane>>4 picks the edge, l = lane&15 picks 4 channels 4l..4l+3).
// Logit: p = sum_{16 lanes}(4ch q.k + ea[l]*qe[l]) via 4-step group reduce.
// One exp2 per 4 edges. PV + den + t accumulate lane-local; cross-group
// reduce (xor16/32) once per node; deferred ew@t via ewT + 16 broadcasts.
__global__ __launch_bounds__(256) void edge_k(const float* __restrict__ qkvs,
    const unsigned* __restrict__ kvb, const unsigned short* __restrict__ eab_us,
    const float* __restrict__ qe, const float* __restrict__ ewT,
    const int* __restrict__ row_ptr, const int* __restrict__ src_s,
    float* __restrict__ attn){
  int wv = (blockIdx.x * 256 + threadIdx.x) >> 6;
  if (wv >= NN * 2) return;
  int lane = threadIdx.x & 63;
  int n = wv >> 1, h = wv & 1;
  int grp = lane >> 4, l = lane & 15;
  float4 qv = *(const float4*)(qkvs + (size_t)n * 512 + h * 64 + 4 * l);
  float q0 = qv.x * SCALE_L2E, q1 = qv.y * SCALE_L2E;
  float q2 = qv.z * SCALE_L2E, q3 = qv.w * SCALE_L2E;
  float qel = qe[(size_t)n * 32 + h * 16 + l];
  int beg = row_ptr[n], end = row_ptr[n + 1];
  int nb = end - beg;
  float a0 = 0.f, a1 = 0.f, a2 = 0.f, a3 = 0.f, den = 0.f, tl = 0.f;
  int hoff = h * 64 + 4 * l;
  for (int cb = 0; cb < nb; cb += 64){
    int sv = (cb + lane < nb) ? src_s[beg + cb + lane] : 0;
    int m = min(64, nb - cb);
    for (int u = 0; u < m; u += 8){
      int eA = u + grp, eB = u + 4 + grp;        // both < 64 (u <= 56)
      int sA = __shfl(sv, eA);
      int sB = __shfl(sv, eB);
      uint4 kvA = *(const uint4*)(kvb + (size_t)sA * 128 + hoff);
      uint4 kvB = *(const uint4*)(kvb + (size_t)sB * 128 + hoff);
      size_t gA = (size_t)(beg + cb + eA); if (gA >= NE) gA = NE - 1;
      size_t gB = (size_t)(beg + cb + eB); if (gB >= NE) gB = NE - 1;
      unsigned short eaAu = eab_us[gA * 16 + l];
      unsigned short eaBu = eab_us[gB * 16 + l];
      {
        float eaf = __uint_as_float((unsigned)eaAu << 16);
        float k0 = __uint_as_float(kvA.x << 16), v0 = __uint_as_float(kvA.x & 0xffff0000u);
        float k1 = __uint_as_float(kvA.y << 16), v1 = __uint_as_float(kvA.y & 0xffff0000u);
        float k2 = __uint_as_float(kvA.z << 16), v2 = __uint_as_float(kvA.z & 0xffff0000u);
        float k3 = __uint_as_float(kvA.w << 16), v3 = __uint_as_float(kvA.w & 0xffff0000u);
        float p = fmaf(q0, k0, fmaf(q1, k1, fmaf(q2, k2, fmaf(q3, k3, qel * eaf))));
        p += __shfl_xor(p, 1); p += __shfl_xor(p, 2);
        p += __shfl_xor(p, 4); p += __shfl_xor(p, 8);
        float w = exp2f(p);
        if (eA >= m) w = 0.f;
        a0 = fmaf(v0, w, a0); a1 = fmaf(v1, w, a1);
        a2 = fmaf(v2, w, a2); a3 = fmaf(v3, w, a3);
        den += w; tl = fmaf(eaf, w, tl);
      }
      {
        float eaf = __uint_as_float((unsigned)eaBu << 16);
        float k0 = __uint_as_float(kvB.x << 16), v0 = __uint_as_float(kvB.x & 0xffff0000u);
        float k1 = __uint_as_float(kvB.y << 16), v1 = __uint_as_float(kvB.y & 0xffff0000u);
        float k2 = __uint_as_float(kvB.z << 16), v2 = __uint_as_float(kvB.z & 0xffff0000u);
        float k3 = __uint_as_float(kvB.w << 16), v3 = __uint_as_float(kvB.w & 0xffff0000u);
        float p = fmaf(q0, k0, fmaf(q1, k1, fmaf(q2, k2, fmaf(q3, k3, qel * eaf))));
        p += __shfl_xor(p, 1); p += __shfl_xor(p, 2);
        p += __shfl_xor(p, 4); p += __shfl_xor(p, 8);
        float w = exp2f(p);
        if (eB >= m) w = 0.f;
        a0 = fmaf(v0, w, a0); a1 = fmaf(v1, w, a1);
        a2 = fmaf(v2, w, a2); a3 = fmaf(v3, w, a3);
        den += w; tl = fmaf(eaf, w, tl);
      }
    }
  }
  // cross-group reduce (4 groups hold disjoint edge subsets, same channels)
  a0 += __shfl_xor(a0, 16); a0 += __shfl_xor(a0, 32);
  a1 += __shfl_xor(a1, 16); a1 += __shfl_xor(a1, 32);
  a2 += __shfl_xor(a2, 16); a2 += __shfl_xor(a2, 32);
  a3 += __shfl_xor(a3, 16); a3 += __shfl_xor(a3, 32);
  den += __shfl_xor(den, 16); den += __shfl_xor(den, 32);
  tl  += __shfl_xor(tl, 16);  tl  += __shfl_xor(tl, 32);
  // deferred edge-embedding output term: extra_c = sum_d ew[c,d] * t_d
  float e0 = 0.f, e1 = 0.f, e2 = 0.f, e3 = 0.f;
  const float* ewp = ewT + (size_t)h * 16 * 64 + 4 * l;
  #pragma unroll
  for (int d = 0; d < 16; d++){
    float td = __shfl(tl, d);
    float4 w4 = *(const float4*)(ewp + d * 64);
    e0 = fmaf(w4.x, td, e0); e1 = fmaf(w4.y, td, e1);
    e2 = fmaf(w4.z, td, e2); e3 = fmaf(w4.w, td, e3);
  }
  float inv = den > 0.f ? 1.f / den : 0.f;
  float4 o;
  o.x = (a0 + e0) * inv; o.y = (a1 + e1) * inv;
  o.z = (a2 + e2) * inv; o.w = (a3 + e3) * inv;
  *(float4*)(attn + (size_t)n * 128 + h * 64 + 4 * l) = o;
}

// beta-gate combine + [128->64] proj + leaky relu + BN partial sums.
__global__ __launch_bounds__(256) void combine_k(const float* __restrict__ attn,
    const float* __restrict__ qkvs, const float* __restrict__ bw,
    const float* __restrict__ tw, const float* __restrict__ tb,
    float* __restrict__ h2, float* __restrict__ bn_acc){
  __shared__ float twT[128][65];
  __shared__ float hcs[4][128];
  __shared__ float bsum[64], bsq[64];
  int t = threadIdx.x;
  int lane = t & 63, wv = t >> 6;
  for (int i = t; i < 64 * 128; i += 256){
    int j = i >> 7, k = i & 127;
    twT[k][j] = tw[i];
  }
  if (t < 64){ bsum[t] = 0.f; bsq[t] = 0.f; }
  __syncthreads();
  float bw0 = bw[lane],       bw1 = bw[64 + lane];
  float bwr0 = bw[128 + lane], bwr1 = bw[192 + lane];
  float bwd0 = bw[256 + lane], bwd1 = bw[320 + lane];
  float tbv = tb[lane];
  float rs = 0.f, rq = 0.f;
  int base_node = blockIdx.x * 16 + wv * 4;
  for (int it = 0; it < 4; it++){
    int n = base_node + it;
    bool valid = n < NN;
    float o0 = 0.f, o1 = 0.f, r0 = 0.f, r1 = 0.f;
    if (valid){
      o0 = attn[(size_t)n * 128 + lane];
      o1 = attn[(size_t)n * 128 + 64 + lane];
      r0 = qkvs[(size_t)n * 512 + 384 + lane];
      r1 = qkvs[(size_t)n * 512 + 448 + lane];
    }
    float p = o0 * bw0 + o1 * bw1 + r0 * bwr0 + r1 * bwr1 + (o0 - r0) * bwd0 + (o1 - r1) * bwd1;
    #pragma unroll
    for (int off = 32; off >= 1; off >>= 1) p += __shfl_xor(p, off);
    float beta = 1.f / (1.f + __expf(-p));
    float hc0 = beta * r0 + (1.f - beta) * o0;
    float hc1 = beta * r1 + (1.f - beta) * o1;
    hcs[wv][lane] = hc0;
    hcs[wv][64 + lane] = hc1;
    __syncthreads();
    float s = tbv;
    #pragma unroll 8
    for (int k = 0; k < 128; k++) s += hcs[wv][k] * twT[k][lane];
    __syncthreads();
    if (valid){
      float hv = s > 0.f ? s : 0.01f * s;
      h2[(size_t)n * 64 + lane] = hv;
      rs += hv; rq += hv * hv;
    }
  }
  atomicAdd(&bsum[lane], rs);
  atomicAdd(&bsq[lane], rq);
  __syncthreads();
  if (t < 64){
    atomicAdd(&bn_acc[t], bsum[t]);
    atomicAdd(&bn_acc[64 + t], bsq[t]);
  }
}

__global__ void bn_final_k(const float* __restrict__ bn_acc, const float* __restrict__ bnw,
                           const float* __restrict__ bnb, float* __restrict__ ss){
  int j = threadIdx.x;
  if (j < 64){
    float m = bn_acc[j] / (float)NN;
    float v = bn_acc[64 + j] / (float)NN - m * m;
    float sc = bnw[j] * rsqrtf(v + EPS_BN);
    ss[j] = sc;
    ss[64 + j] = bnb[j] - m * sc;
  }
}

// BN apply -> split bf16 h (next-layer GEMM input) + pooled max/sum (sorted batch)
__global__ __launch_bounds__(256) void bn_apply_k(const float* __restrict__ h2,
    const float* __restrict__ ss, const int* __restrict__ batch,
    unsigned short* __restrict__ hbh, unsigned short* __restrict__ hbl,
    float* __restrict__ gsum, unsigned* __restrict__ gmax,
    int do_pool){
  int wid = (blockIdx.x * 256 + threadIdx.x) >> 6;
  int lane = threadIdx.x & 63;
  const int CH = (NN + 1023) / 1024;
  int start = wid * CH;
  int end = start + CH; if (end > NN) end = NN;
  float sc = ss[lane], sh = ss[64 + lane];
  int curg = -1; float lmax = 0.f, lsum = 0.f;
  for (int n = start; n < end; n++){
    float v = h2[(size_t)n * 64 + lane] * sc + sh;
    f2bf_split(v, &hbh[(size_t)n * 64 + lane], &hbl[(size_t)n * 64 + lane]);
    if (do_pool){
      int g = batch[n];
      if (g != curg){
        if (curg >= 0){
          atomicAdd(&gsum[curg * 64 + lane], lsum);
          atomicMax(&gmax[curg * 64 + lane], encf(lmax));
        }
        curg = g; lmax = v; lsum = v;
      } else {
        lmax = fmaxf(lmax, v); lsum += v;
      }
    }
  }
  if (do_pool && curg >= 0){
    atomicAdd(&gsum[curg * 64 + lane], lsum);
    atomicMax(&gmax[curg * 64 + lane], encf(lmax));
  }
}

__global__ void pool_final_k(const float* __restrict__ gsum, const unsigned* __restrict__ gmax,
                             const int* __restrict__ counts, float* __restrict__ gr){
  int i = blockIdx.x * 256 + threadIdx.x;
  if (i < NG * 64){
    int g = i >> 6, j = i & 63;
    unsigned e = gmax[i];
    float mx = e ? decf(e) : 0.f;
    int c = counts[g]; if (c < 1) c = 1;
    gr[g * 128 + j]       += mx;
    gr[g * 128 + 64 + j]  += gsum[i] / (float)c;
  }
}

extern "C" void kernel_launch(void* const* d_in, const int* in_sizes, int n_in,
                              void* d_out, int out_size, void* d_ws, size_t ws_size,
                              hipStream_t stream){
  const float* x     = (const float*)d_in[0];
  const float* ea    = (const float*)d_in[1];
  const int*   eidx  = (const int*)d_in[2];
  const int*   batch = (const int*)d_in[3];
  const float* c1_qw = (const float*)d_in[4];
  const float* c1_qb = (const float*)d_in[5];
  const float* c1_kw = (const float*)d_in[6];
  const float* c1_kb = (const float*)d_in[7];
  const float* c1_vw = (const float*)d_in[8];
  const float* c1_vb = (const float*)d_in[9];
  const float* c1_ew = (const float*)d_in[10];
  const float* c1_skw= (const float*)d_in[11];
  const float* c1_skb= (const float*)d_in[12];
  const float* c1_bw = (const float*)d_in[13];
  const float* c1_tw = (const float*)d_in[14];
  const float* c1_tb = (const float*)d_in[15];
  const float* c1_bnw= (const float*)d_in[16];
  const float* c1_bnb= (const float*)d_in[17];
  const float* L_qw  = (const float*)d_in[18];
  const float* L_qb  = (const float*)d_in[19];
  const float* L_kw  = (const float*)d_in[20];
  const float* L_kb  = (const float*)d_in[21];
  const float* L_vw  = (const float*)d_in[22];
  const float* L_vb  = (const float*)d_in[23];
  const float* L_ew  = (const float*)d_in[24];
  const float* L_skw = (const float*)d_in[25];
  const float* L_skb = (const float*)d_in[26];
  const float* L_bw  = (const float*)d_in[27];
  const float* L_tw  = (const float*)d_in[28];
  const float* L_tb  = (const float*)d_in[29];
  const float* L_bnw = (const float*)d_in[30];
  const float* L_bnb = (const float*)d_in[31];
  const int* srcs = eidx;
  const int* dsts = eidx + NE;

  char* p = (char*)d_ws;
  auto carve = [&](size_t bytes) -> void* {
    void* r = (void*)p;
    p += (bytes + 255) & ~(size_t)255;
    return r;
  };
  unsigned short* Wh = (unsigned short*)carve(512 * 128 * sizeof(unsigned short));
  unsigned short* Wl = (unsigned short*)carve(512 * 128 * sizeof(unsigned short));
  float*    bp     = (float*)carve(512 * sizeof(float));
  float*    qkvs   = (float*)carve((size_t)NN * 512 * sizeof(float));
  unsigned* kvb    = (unsigned*)carve((size_t)NN * 128 * sizeof(unsigned));
  unsigned* eab    = (unsigned*)carve((size_t)NE * 8 * sizeof(unsigned));
  float*    qe     = (float*)carve((size_t)NN * 32 * sizeof(float));
  float*    ewT    = (float*)carve(2048 * sizeof(float));
  float*    attn   = (float*)carve((size_t)NN * 128 * sizeof(float));
  unsigned short* xbh = (unsigned short*)carve((size_t)NN * FIN * sizeof(unsigned short));
  unsigned short* xbl = (unsigned short*)carve((size_t)NN * FIN * sizeof(unsigned short));
  unsigned short* hbh = (unsigned short*)carve((size_t)NN * 64 * sizeof(unsigned short));
  unsigned short* hbl = (unsigned short*)carve((size_t)NN * 64 * sizeof(unsigned short));
  float*    h2     = (float*)carve((size_t)NN * 64 * sizeof(float));
  float*    bn_acc = (float*)carve(128 * sizeof(float));
  float*    ss     = (float*)carve(128 * sizeof(float));
  float*    gsum   = (float*)carve((size_t)NG * 64 * sizeof(float));
  unsigned* gmax   = (unsigned*)carve((size_t)NG * 64 * sizeof(unsigned));
  int*      deg    = (int*)carve(NN * sizeof(int));
  int*      row_ptr= (int*)carve((NN + 1) * sizeof(int));
  int*      eid    = (int*)carve((size_t)NE * sizeof(int));
  int*      src_s  = (int*)carve((size_t)NE * sizeof(int));
  int*      counts = (int*)carve(NG * sizeof(int));
  int*      starts = (int*)carve((NG + 1) * sizeof(int));
  int*      bsums  = (int*)carve(256 * sizeof(int));

  hipMemsetAsync(d_out, 0, (size_t)out_size * sizeof(float), stream);
  hipMemsetAsync(deg, 0, NN * sizeof(int), stream);
  hist_k<<<(NE + 255) / 256, 256, 0, stream>>>(dsts, deg);
  bounds_k<<<(NN + 255) / 256, 256, 0, stream>>>(batch, starts);
  counts_from_starts_k<<<1, 64, 0, stream>>>(starts, counts);
  scan1_k<<<SCAN_B, 256, 0, stream>>>(deg, bsums);
  scan2_k<<<1, 256, 0, stream>>>(bsums);
  scan3_k<<<SCAN_B, 256, 0, stream>>>(deg, bsums, row_ptr);
  cursor_k<<<(NN + 255) / 256, 256, 0, stream>>>(row_ptr, deg);   // reuse deg as cursor
  scatter_k<<<(NE + 255) / 256, 256, 0, stream>>>(dsts, srcs, deg, eid, src_s);
  pack_ea_k<<<(NE * 2 + 255) / 256, 256, 0, stream>>>(ea, eid, eab);
  tobf_k<<<(NN * FIN + 255) / 256, 256, 0, stream>>>(x, xbh, xbl, NN * FIN);

  const unsigned short* hin_h = xbh;
  const unsigned short* hin_l = xbl;
  for (int L = 0; L < 4; L++){
    int D = (L == 0) ? FIN : EMB;
    const float *qw,*qb,*kw,*kb,*vw,*vb,*eww,*skw,*skb,*bww,*tw,*tb,*bnw,*bnb;
    if (L == 0){
      qw=c1_qw; qb=c1_qb; kw=c1_kw; kb=c1_kb; vw=c1_vw; vb=c1_vb;
      eww=c1_ew; skw=c1_skw; skb=c1_skb; bww=c1_bw; tw=c1_tw; tb=c1_tb;
      bnw=c1_bnw; bnb=c1_bnb;
    } else {
      int i = L - 1;
      qw = L_qw + (size_t)i * HCC * EMB;  qb = L_qb + (size_t)i * HCC;
      kw = L_kw + (size_t)i * HCC * EMB;  kb = L_kb + (size_t)i * HCC;
      vw = L_vw + (size_t)i * HCC * EMB;  vb = L_vb + (size_t)i * HCC;
      eww= L_ew + (size_t)i * HCC * EDIM;
      skw= L_skw+ (size_t)i * HCC * EMB;  skb= L_skb+ (size_t)i * HCC;
      bww= L_bw + (size_t)i * 3 * HCC;
      tw = L_tw + (size_t)i * EMB * HCC;  tb = L_tb + (size_t)i * EMB;
      bnw= L_bnw+ (size_t)i * EMB;        bnb= L_bnb+ (size_t)i * EMB;
    }
    pack_k<<<(512 * D + 255) / 256, 256, 0, stream>>>(qw, kw, vw, skw, qb, kb, vb, skb, Wh, Wl, bp, D);
    dim3 gg((NN + 63) / 64, 8);
    if (D == 128) gemm_k<128><<<gg, 256, 0, stream>>>(hin_h, hin_l, Wh, Wl, bp, qkvs);
    else          gemm_k<64><<<gg, 256, 0, stream>>>(hin_h, hin_l, Wh, Wl, bp, qkvs);
    pack_kv_k<<<(NN * 128 + 255) / 256, 256, 0, stream>>>(qkvs, kvb);
    qe_k<<<(NN + 7) / 8, 256, 0, stream>>>(qkvs, eww, qe);
    ewt_k<<<8, 256, 0, stream>>>(eww, ewT);
    edge_k<<<(NN * 2 * 64 + 255) / 256, 256, 0, stream>>>(qkvs, kvb, (const unsigned short*)eab, qe, ewT, row_ptr, src_s, attn);
    hipMemsetAsync(bn_acc, 0, 128 * sizeof(float), stream);
    combine_k<<<(NN + 15) / 16, 256, 0, stream>>>(attn, qkvs, bww, tw, tb, h2, bn_acc);
    bn_final_k<<<1, 64, 0, stream>>>(bn_acc, bnw, bnb, ss);
    if (L > 0) hipMemsetAsync(gsum, 0, 2 * NG * 64 * sizeof(float), stream);
    bn_apply_k<<<256, 256, 0, stream>>>(h2, ss, batch, hbh, hbl, gsum, gmax, (L > 0) ? 1 : 0);
    if (L > 0) pool_final_k<<<(NG * 64 + 255) / 256, 256, 0, stream>>>(gsum, gmax, counts, (float*)d_out);
    hin_h = hbh; hin_l = hbl;
  }
}

// Round 8
// 1432.823 us; speedup vs baseline: 1.8362x; 1.0290x over previous
//
#include <hip/hip_runtime.h>

#define NN 50000
#define NE 800000
#define FIN 128
#define EDIM 16
#define EMB 64
#define NH 2
#define NLAYERS 3
#define NG 64
#define HCC 128
#define INV_SQRT_D 0.125f
#define EPS_BN 1e-5f
#define SCAN_B 196   // ceil(NN/256)
#define SCALE_L2E 0.18033688f   // 0.125 * log2(e)

typedef __attribute__((ext_vector_type(8))) short bf16x8;
typedef __attribute__((ext_vector_type(4))) float f32x4;

__device__ __forceinline__ unsigned encf(float f){
  unsigned u = __float_as_uint(f);
  return (u & 0x80000000u) ? ~u : (u | 0x80000000u);
}
__device__ __forceinline__ float decf(unsigned e){
  unsigned u = (e & 0x80000000u) ? (e ^ 0x80000000u) : ~e;
  return __uint_as_float(u);
}
__device__ __forceinline__ unsigned f2bf(float x){   // RNE bf16, returned in low 16
  unsigned u = __float_as_uint(x);
  return (u + 0x7fffu + ((u >> 16) & 1u)) >> 16;
}
// split fp32 -> hi + lo bf16 (a ~= hi + lo, |lo| <= 2^-9 |a|)
__device__ __forceinline__ void f2bf_split(float x, unsigned short* hi, unsigned short* lo){
  unsigned h = f2bf(x);
  float hf = __uint_as_float(h << 16);
  *hi = (unsigned short)h;
  *lo = (unsigned short)f2bf(x - hf);
}

__global__ void hist_k(const int* __restrict__ dst, int* __restrict__ deg){
  int i = blockIdx.x * 256 + threadIdx.x;
  if (i < NE) atomicAdd(&deg[dst[i]], 1);
}

// batch_index is sorted: group starts via boundary detection, no atomics.
__global__ void bounds_k(const int* __restrict__ batch, int* __restrict__ starts){
  int i = blockIdx.x * 256 + threadIdx.x;
  if (i >= NN) return;
  int g = batch[i];
  int gp = (i == 0) ? -1 : batch[i - 1];
  for (int gg = gp + 1; gg <= g; gg++) starts[gg] = i;
  if (i == NN - 1){
    for (int gg = g + 1; gg <= NG; gg++) starts[gg] = NN;
  }
}

__global__ void counts_from_starts_k(const int* __restrict__ starts, int* __restrict__ counts){
  int g = threadIdx.x;
  if (g < NG) counts[g] = starts[g + 1] - starts[g];
}

__global__ void scan1_k(const int* __restrict__ deg, int* __restrict__ bsums){
  __shared__ int lds[256];
  int b = blockIdx.x, t = threadIdx.x;
  int idx = b * 256 + t;
  lds[t] = (idx < NN) ? deg[idx] : 0;
  __syncthreads();
  for (int off = 128; off >= 1; off >>= 1){
    if (t < off) lds[t] += lds[t + off];
    __syncthreads();
  }
  if (t == 0) bsums[b] = lds[0];
}

__global__ void scan2_k(int* __restrict__ bsums){
  __shared__ int lds[256];
  int t = threadIdx.x;
  int v = (t < SCAN_B) ? bsums[t] : 0;
  int x = v;
  lds[t] = x;
  __syncthreads();
  for (int off = 1; off < 256; off <<= 1){
    int y = (t >= off) ? lds[t - off] : 0;
    __syncthreads();
    x += y;
    lds[t] = x;
    __syncthreads();
  }
  if (t < SCAN_B) bsums[t] = x - v;   // exclusive
}

__global__ void scan3_k(const int* __restrict__ deg, const int* __restrict__ bsums,
                        int* __restrict__ row_ptr){
  __shared__ int lds[256];
  int b = blockIdx.x, t = threadIdx.x;
  int idx = b * 256 + t;
  int v = (idx < NN) ? deg[idx] : 0;
  int x = v;
  lds[t] = x;
  __syncthreads();
  for (int off = 1; off < 256; off <<= 1){
    int y = (t >= off) ? lds[t - off] : 0;
    __syncthreads();
    x += y;
    lds[t] = x;
    __syncthreads();
  }
  if (idx <= NN) row_ptr[idx] = bsums[b] + x - v;
}

__global__ void cursor_k(const int* __restrict__ row_ptr, int* __restrict__ cur){
  int i = blockIdx.x * 256 + threadIdx.x;
  if (i < NN) cur[i] = row_ptr[i];
}

__global__ void scatter_k(const int* __restrict__ dst, const int* __restrict__ src,
                          int* __restrict__ cur, int* __restrict__ eid,
                          int* __restrict__ src_s){
  int i = blockIdx.x * 256 + threadIdx.x;
  if (i < NE){
    int p = atomicAdd(&cur[dst[i]], 1);
    eid[p] = i;
    src_s[p] = src[i];
  }
}

// edge_attr -> bf16, reordered into CSR position order. thread = (p, half-row)
__global__ void pack_ea_k(const float* __restrict__ ea, const int* __restrict__ eid,
                          unsigned* __restrict__ eab){
  int i = blockIdx.x * 256 + threadIdx.x;
  if (i >= NE * 2) return;
  int p = i >> 1, half = i & 1;
  int e = eid[p];
  const float* s = ea + (size_t)e * 16 + half * 8;
  float4 a = *(const float4*)(s);
  float4 b = *(const float4*)(s + 4);
  uint4 o;
  o.x = f2bf(a.x) | (f2bf(a.y) << 16);
  o.y = f2bf(a.z) | (f2bf(a.w) << 16);
  o.z = f2bf(b.x) | (f2bf(b.y) << 16);
  o.w = f2bf(b.z) | (f2bf(b.w) << 16);
  ((uint4*)eab)[(size_t)p * 2 + half] = o;
}

// fp32 -> split bf16 (x once per call)
__global__ void tobf_k(const float* __restrict__ in, unsigned short* __restrict__ hi,
                       unsigned short* __restrict__ lo, int n){
  int i = blockIdx.x * 256 + threadIdx.x;
  if (i < n) f2bf_split(in[i], &hi[i], &lo[i]);
}

// pack q/k/v/skip weights into split bf16 Wp_hi/Wp_lo[512][D] + fp32 bias bp[512]
__global__ void pack_k(const float* __restrict__ qw, const float* __restrict__ kw,
                       const float* __restrict__ vw, const float* __restrict__ skw,
                       const float* __restrict__ qb, const float* __restrict__ kb,
                       const float* __restrict__ vb, const float* __restrict__ skb,
                       unsigned short* __restrict__ Wh, unsigned short* __restrict__ Wl,
                       float* __restrict__ bp, int D){
  int i = blockIdx.x * 256 + threadIdx.x;
  if (i < 512 * D){
    int c = i / D, d = i - c * D;
    const float* w = (c < 128) ? qw : (c < 256) ? kw : (c < 384) ? vw : skw;
    f2bf_split(w[(c & 127) * D + d], &Wh[i], &Wl[i]);
  }
  if (i < 512){
    const float* b = (i < 128) ? qb : (i < 256) ? kb : (i < 384) ? vb : skb;
    bp[i] = b[i & 127];
  }
}

// qe[n, h, d] = (sum_c q[n,h,c] * ew[h*64+c, d]) * SCALE_L2E
__global__ __launch_bounds__(256) void qe_k(const float* __restrict__ qf,
    const float* __restrict__ ew, float* __restrict__ qe){
  __shared__ float ews[2048];
  int t = threadIdx.x;
  for (int i = t; i < 2048; i += 256) ews[i] = ew[i];
  __syncthreads();
  int g = t >> 5;            // node within block (8 nodes/block)
  int hd = t & 31;           // h*16 + d
  int h = hd >> 4, d = hd & 15;
  int n = blockIdx.x * 8 + g;
  if (n >= NN) return;
  const float* qp = qf + (size_t)n * 128 + h * 64;
  float s = 0.f;
  #pragma unroll 8
  for (int c = 0; c < 64; c++)
    s += qp[c] * ews[(h * 64 + c) * 16 + d];
  qe[(size_t)n * 32 + hd] = s * SCALE_L2E;
}

// ewT[h][d][c] = ew[h*64+c][d]  (transposed, for edge_k epilogue float4 loads)
__global__ void ewt_k(const float* __restrict__ ew, float* __restrict__ ewT){
  int i = blockIdx.x * 256 + threadIdx.x;
  if (i < 2048){
    int c = i >> 4, d = i & 15;          // c = h*64 + ch
    ewT[((c >> 6) * 16 + d) * 64 + (c & 63)] = ew[i];
  }
}

// Fused qkvs GEMM: block = 64 rows x ALL 512 cols (A frags register-resident,
// loaded once -> no A re-fetch across column blocks). Epilogue writes compact
// q[n][128], skip[n][128] (fp32) and kvb[n][128] (bf16 k|v packed) directly.
// Split-bf16: C ~= Ah*Wh + Al*Wh + Ah*Wl.
template<int D>
__global__ __launch_bounds__(256) void gemm2_k(const unsigned short* __restrict__ Ah,
                                               const unsigned short* __restrict__ Al,
                                               const unsigned short* __restrict__ Wh,
                                               const unsigned short* __restrict__ Wl,
                                               const float* __restrict__ bp,
                                               float* __restrict__ qf,
                                               unsigned* __restrict__ kvb,
                                               float* __restrict__ sk){
  int t = threadIdx.x;
  int w = t >> 6, lane = t & 63;
  int brow = blockIdx.x * 64 + w * 16;
  int r = lane & 15, kg = lane >> 4;
  int arow = brow + r; if (arow >= NN) arow = NN - 1;
  const int NK = D / 32;
  bf16x8 avh[NK], avl[NK];
  size_t aoff = (size_t)arow * D + kg * 8;
  #pragma unroll
  for (int kk = 0; kk < NK; kk++){
    avh[kk] = *(const bf16x8*)(Ah + aoff + kk * 32);
    avl[kk] = *(const bf16x8*)(Al + aoff + kk * 32);
  }
  f32x4 kacc[8];     // k-block results (cb=2,3), bias added, awaiting v pairing
  int rowbase = brow + kg * 4;
  #pragma unroll
  for (int cb = 0; cb < 8; cb++){
    f32x4 acc[4];
    #pragma unroll
    for (int nf = 0; nf < 4; nf++) acc[nf] = (f32x4){0.f,0.f,0.f,0.f};
    #pragma unroll
    for (int kk = 0; kk < NK; kk++){
      size_t woff = (size_t)(cb * 64 + r) * D + kg * 8 + kk * 32;
      #pragma unroll
      for (int nf = 0; nf < 4; nf++){
        bf16x8 bh = *(const bf16x8*)(Wh + woff + (size_t)nf * 16 * D);
        bf16x8 bl = *(const bf16x8*)(Wl + woff + (size_t)nf * 16 * D);
        acc[nf] = __builtin_amdgcn_mfma_f32_16x16x32_bf16(avh[kk], bh, acc[nf], 0, 0, 0);
        acc[nf] = __builtin_amdgcn_mfma_f32_16x16x32_bf16(avl[kk], bh, acc[nf], 0, 0, 0);
        acc[nf] = __builtin_amdgcn_mfma_f32_16x16x32_bf16(avh[kk], bl, acc[nf], 0, 0, 0);
      }
    }
    if (cb < 2){                     // q: cols 0..127
      #pragma unroll
      for (int nf = 0; nf < 4; nf++){
        int ch = cb * 64 + nf * 16 + r;
        float bias = bp[ch];
        #pragma unroll
        for (int j = 0; j < 4; j++){
          int row = rowbase + j;
          if (row < NN) qf[(size_t)row * 128 + ch] = acc[nf][j] + bias;
        }
      }
    } else if (cb < 4){              // k: hold with bias
      #pragma unroll
      for (int nf = 0; nf < 4; nf++){
        float bias = bp[cb * 64 + nf * 16 + r];
        f32x4 a = acc[nf];
        a[0] += bias; a[1] += bias; a[2] += bias; a[3] += bias;
        kacc[(cb - 2) * 4 + nf] = a;
      }
    } else if (cb < 6){              // v: pack with matching k
      #pragma unroll
      for (int nf = 0; nf < 4; nf++){
        int ch = (cb - 4) * 64 + nf * 16 + r;
        float bias = bp[cb * 64 + nf * 16 + r];
        f32x4 kk4 = kacc[(cb - 4) * 4 + nf];
        #pragma unroll
        for (int j = 0; j < 4; j++){
          int row = rowbase + j;
          if (row < NN){
            float vv = acc[nf][j] + bias;
            kvb[(size_t)row * 128 + ch] = f2bf(kk4[j]) | (f2bf(vv) << 16);
          }
        }
      }
    } else {                         // skip: cols 384..511
      #pragma unroll
      for (int nf = 0; nf < 4; nf++){
        int ch = (cb - 6) * 64 + nf * 16 + r;
        float bias = bp[cb * 64 + nf * 16 + r];
        #pragma unroll
        for (int j = 0; j < 4; j++){
          int row = rowbase + j;
          if (row < NN) sk[(size_t)row * 128 + ch] = acc[nf][j] + bias;
        }
      }
    }
  }
}

// One wave per (node, head). 4 edges per wave iteration: 16 lanes per edge
// (grp = lane>>4 picks the edge, l = lane&15 picks 4 channels 4l..4l+3).
__global__ __launch_bounds__(256) void edge_k(const float* __restrict__ qf,
    const unsigned* __restrict__ kvb, const unsigned short* __restrict__ eab_us,
    const float* __restrict__ qe, const float* __restrict__ ewT,
    const int* __restrict__ row_ptr, const int* __restrict__ src_s,
    float* __restrict__ attn){
  int wv = (blockIdx.x * 256 + threadIdx.x) >> 6;
  if (wv >= NN * 2) return;
  int lane = threadIdx.x & 63;
  int n = wv >> 1, h = wv & 1;
  int grp = lane >> 4, l = lane & 15;
  float4 qv = *(const float4*)(qf + (size_t)n * 128 + h * 64 + 4 * l);
  float q0 = qv.x * SCALE_L2E, q1 = qv.y * SCALE_L2E;
  float q2 = qv.z * SCALE_L2E, q3 = qv.w * SCALE_L2E;
  float qel = qe[(size_t)n * 32 + h * 16 + l];
  int beg = row_ptr[n], end = row_ptr[n + 1];
  int nb = end - beg;
  float a0 = 0.f, a1 = 0.f, a2 = 0.f, a3 = 0.f, den = 0.f, tl = 0.f;
  int hoff = h * 64 + 4 * l;
  for (int cb = 0; cb < nb; cb += 64){
    int sv = (cb + lane < nb) ? src_s[beg + cb + lane] : 0;
    int m = min(64, nb - cb);
    for (int u = 0; u < m; u += 8){
      int eA = u + grp, eB = u + 4 + grp;        // both < 64 (u <= 56)
      int sA = __shfl(sv, eA);
      int sB = __shfl(sv, eB);
      uint4 kvA = *(const uint4*)(kvb + (size_t)sA * 128 + hoff);
      uint4 kvB = *(const uint4*)(kvb + (size_t)sB * 128 + hoff);
      size_t gA = (size_t)(beg + cb + eA); if (gA >= NE) gA = NE - 1;
      size_t gB = (size_t)(beg + cb + eB); if (gB >= NE) gB = NE - 1;
      unsigned short eaAu = eab_us[gA * 16 + l];
      unsigned short eaBu = eab_us[gB * 16 + l];
      {
        float eaf = __uint_as_float((unsigned)eaAu << 16);
        float k0 = __uint_as_float(kvA.x << 16), v0 = __uint_as_float(kvA.x & 0xffff0000u);
        float k1 = __uint_as_float(kvA.y << 16), v1 = __uint_as_float(kvA.y & 0xffff0000u);
        float k2 = __uint_as_float(kvA.z << 16), v2 = __uint_as_float(kvA.z & 0xffff0000u);
        float k3 = __uint_as_float(kvA.w << 16), v3 = __uint_as_float(kvA.w & 0xffff0000u);
        float p = fmaf(q0, k0, fmaf(q1, k1, fmaf(q2, k2, fmaf(q3, k3, qel * eaf))));
        p += __shfl_xor(p, 1); p += __shfl_xor(p, 2);
        p += __shfl_xor(p, 4); p += __shfl_xor(p, 8);
        float w = exp2f(p);
        if (eA >= m) w = 0.f;
        a0 = fmaf(v0, w, a0); a1 = fmaf(v1, w, a1);
        a2 = fmaf(v2, w, a2); a3 = fmaf(v3, w, a3);
        den += w; tl = fmaf(eaf, w, tl);
      }
      {
        float eaf = __uint_as_float((unsigned)eaBu << 16);
        float k0 = __uint_as_float(kvB.x << 16), v0 = __uint_as_float(kvB.x & 0xffff0000u);
        float k1 = __uint_as_float(kvB.y << 16), v1 = __uint_as_float(kvB.y & 0xffff0000u);
        float k2 = __uint_as_float(kvB.z << 16), v2 = __uint_as_float(kvB.z & 0xffff0000u);
        float k3 = __uint_as_float(kvB.w << 16), v3 = __uint_as_float(kvB.w & 0xffff0000u);
        float p = fmaf(q0, k0, fmaf(q1, k1, fmaf(q2, k2, fmaf(q3, k3, qel * eaf))));
        p += __shfl_xor(p, 1); p += __shfl_xor(p, 2);
        p += __shfl_xor(p, 4); p += __shfl_xor(p, 8);
        float w = exp2f(p);
        if (eB >= m) w = 0.f;
        a0 = fmaf(v0, w, a0); a1 = fmaf(v1, w, a1);
        a2 = fmaf(v2, w, a2); a3 = fmaf(v3, w, a3);
        den += w; tl = fmaf(eaf, w, tl);
      }
    }
  }
  a0 += __shfl_xor(a0, 16); a0 += __shfl_xor(a0, 32);
  a1 += __shfl_xor(a1, 16); a1 += __shfl_xor(a1, 32);
  a2 += __shfl_xor(a2, 16); a2 += __shfl_xor(a2, 32);
  a3 += __shfl_xor(a3, 16); a3 += __shfl_xor(a3, 32);
  den += __shfl_xor(den, 16); den += __shfl_xor(den, 32);
  tl  += __shfl_xor(tl, 16);  tl  += __shfl_xor(tl, 32);
  float e0 = 0.f, e1 = 0.f, e2 = 0.f, e3 = 0.f;
  const float* ewp = ewT + (size_t)h * 16 * 64 + 4 * l;
  #pragma unroll
  for (int d = 0; d < 16; d++){
    float td = __shfl(tl, d);
    float4 w4 = *(const float4*)(ewp + d * 64);
    e0 = fmaf(w4.x, td, e0); e1 = fmaf(w4.y, td, e1);
    e2 = fmaf(w4.z, td, e2); e3 = fmaf(w4.w, td, e3);
  }
  float inv = den > 0.f ? 1.f / den : 0.f;
  float4 o;
  o.x = (a0 + e0) * inv; o.y = (a1 + e1) * inv;
  o.z = (a2 + e2) * inv; o.w = (a3 + e3) * inv;
  *(float4*)(attn + (size_t)n * 128 + h * 64 + 4 * l) = o;
}

// beta-gate combine + [128->64] proj + leaky relu + BN partial sums.
__global__ __launch_bounds__(256) void combine_k(const float* __restrict__ attn,
    const float* __restrict__ sk, const float* __restrict__ bw,
    const float* __restrict__ tw, const float* __restrict__ tb,
    float* __restrict__ h2, float* __restrict__ bn_acc){
  __shared__ float twT[128][65];
  __shared__ float hcs[4][128];
  __shared__ float bsum[64], bsq[64];
  int t = threadIdx.x;
  int lane = t & 63, wv = t >> 6;
  for (int i = t; i < 64 * 128; i += 256){
    int j = i >> 7, k = i & 127;
    twT[k][j] = tw[i];
  }
  if (t < 64){ bsum[t] = 0.f; bsq[t] = 0.f; }
  __syncthreads();
  float bw0 = bw[lane],       bw1 = bw[64 + lane];
  float bwr0 = bw[128 + lane], bwr1 = bw[192 + lane];
  float bwd0 = bw[256 + lane], bwd1 = bw[320 + lane];
  float tbv = tb[lane];
  float rs = 0.f, rq = 0.f;
  int base_node = blockIdx.x * 16 + wv * 4;
  for (int it = 0; it < 4; it++){
    int n = base_node + it;
    bool valid = n < NN;
    float o0 = 0.f, o1 = 0.f, r0 = 0.f, r1 = 0.f;
    if (valid){
      o0 = attn[(size_t)n * 128 + lane];
      o1 = attn[(size_t)n * 128 + 64 + lane];
      r0 = sk[(size_t)n * 128 + lane];
      r1 = sk[(size_t)n * 128 + 64 + lane];
    }
    float p = o0 * bw0 + o1 * bw1 + r0 * bwr0 + r1 * bwr1 + (o0 - r0) * bwd0 + (o1 - r1) * bwd1;
    #pragma unroll
    for (int off = 32; off >= 1; off >>= 1) p += __shfl_xor(p, off);
    float beta = 1.f / (1.f + __expf(-p));
    float hc0 = beta * r0 + (1.f - beta) * o0;
    float hc1 = beta * r1 + (1.f - beta) * o1;
    hcs[wv][lane] = hc0;
    hcs[wv][64 + lane] = hc1;
    __syncthreads();
    float s = tbv;
    #pragma unroll 8
    for (int k = 0; k < 128; k++) s += hcs[wv][k] * twT[k][lane];
    __syncthreads();
    if (valid){
      float hv = s > 0.f ? s : 0.01f * s;
      h2[(size_t)n * 64 + lane] = hv;
      rs += hv; rq += hv * hv;
    }
  }
  atomicAdd(&bsum[lane], rs);
  atomicAdd(&bsq[lane], rq);
  __syncthreads();
  if (t < 64){
    atomicAdd(&bn_acc[t], bsum[t]);
    atomicAdd(&bn_acc[64 + t], bsq[t]);
  }
}

__global__ void bn_final_k(const float* __restrict__ bn_acc, const float* __restrict__ bnw,
                           const float* __restrict__ bnb, float* __restrict__ ss){
  int j = threadIdx.x;
  if (j < 64){
    float m = bn_acc[j] / (float)NN;
    float v = bn_acc[64 + j] / (float)NN - m * m;
    float sc = bnw[j] * rsqrtf(v + EPS_BN);
    ss[j] = sc;
    ss[64 + j] = bnb[j] - m * sc;
  }
}

// BN apply -> split bf16 h (next-layer GEMM input) + pooled max/sum (sorted batch)
__global__ __launch_bounds__(256) void bn_apply_k(const float* __restrict__ h2,
    const float* __restrict__ ss, const int* __restrict__ batch,
    unsigned short* __restrict__ hbh, unsigned short* __restrict__ hbl,
    float* __restrict__ gsum, unsigned* __restrict__ gmax,
    int do_pool){
  int wid = (blockIdx.x * 256 + threadIdx.x) >> 6;
  int lane = threadIdx.x & 63;
  const int CH = (NN + 1023) / 1024;
  int start = wid * CH;
  int end = start + CH; if (end > NN) end = NN;
  float sc = ss[lane], sh = ss[64 + lane];
  int curg = -1; float lmax = 0.f, lsum = 0.f;
  for (int n = start; n < end; n++){
    float v = h2[(size_t)n * 64 + lane] * sc + sh;
    f2bf_split(v, &hbh[(size_t)n * 64 + lane], &hbl[(size_t)n * 64 + lane]);
    if (do_pool){
      int g = batch[n];
      if (g != curg){
        if (curg >= 0){
          atomicAdd(&gsum[curg * 64 + lane], lsum);
          atomicMax(&gmax[curg * 64 + lane], encf(lmax));
        }
        curg = g; lmax = v; lsum = v;
      } else {
        lmax = fmaxf(lmax, v); lsum += v;
      }
    }
  }
  if (do_pool && curg >= 0){
    atomicAdd(&gsum[curg * 64 + lane], lsum);
    atomicMax(&gmax[curg * 64 + lane], encf(lmax));
  }
}

__global__ void pool_final_k(const float* __restrict__ gsum, const unsigned* __restrict__ gmax,
                             const int* __restrict__ counts, float* __restrict__ gr){
  int i = blockIdx.x * 256 + threadIdx.x;
  if (i < NG * 64){
    int g = i >> 6, j = i & 63;
    unsigned e = gmax[i];
    float mx = e ? decf(e) : 0.f;
    int c = counts[g]; if (c < 1) c = 1;
    gr[g * 128 + j]       += mx;
    gr[g * 128 + 64 + j]  += gsum[i] / (float)c;
  }
}

extern "C" void kernel_launch(void* const* d_in, const int* in_sizes, int n_in,
                              void* d_out, int out_size, void* d_ws, size_t ws_size,
                              hipStream_t stream){
  const float* x     = (const float*)d_in[0];
  const float* ea    = (const float*)d_in[1];
  const int*   eidx  = (const int*)d_in[2];
  const int*   batch = (const int*)d_in[3];
  const float* c1_qw = (const float*)d_in[4];
  const float* c1_qb = (const float*)d_in[5];
  const float* c1_kw = (const float*)d_in[6];
  const float* c1_kb = (const float*)d_in[7];
  const float* c1_vw = (const float*)d_in[8];
  const float* c1_vb = (const float*)d_in[9];
  const float* c1_ew = (const float*)d_in[10];
  const float* c1_skw= (const float*)d_in[11];
  const float* c1_skb= (const float*)d_in[12];
  const float* c1_bw = (const float*)d_in[13];
  const float* c1_tw = (const float*)d_in[14];
  const float* c1_tb = (const float*)d_in[15];
  const float* c1_bnw= (const float*)d_in[16];
  const float* c1_bnb= (const float*)d_in[17];
  const float* L_qw  = (const float*)d_in[18];
  const float* L_qb  = (const float*)d_in[19];
  const float* L_kw  = (const float*)d_in[20];
  const float* L_kb  = (const float*)d_in[21];
  const float* L_vw  = (const float*)d_in[22];
  const float* L_vb  = (const float*)d_in[23];
  const float* L_ew  = (const float*)d_in[24];
  const float* L_skw = (const float*)d_in[25];
  const float* L_skb = (const float*)d_in[26];
  const float* L_bw  = (const float*)d_in[27];
  const float* L_tw  = (const float*)d_in[28];
  const float* L_tb  = (const float*)d_in[29];
  const float* L_bnw = (const float*)d_in[30];
  const float* L_bnb = (const float*)d_in[31];
  const int* srcs = eidx;
  const int* dsts = eidx + NE;

  char* p = (char*)d_ws;
  auto carve = [&](size_t bytes) -> void* {
    void* r = (void*)p;
    p += (bytes + 255) & ~(size_t)255;
    return r;
  };
  unsigned short* Wh = (unsigned short*)carve(512 * 128 * sizeof(unsigned short));
  unsigned short* Wl = (unsigned short*)carve(512 * 128 * sizeof(unsigned short));
  float*    bp     = (float*)carve(512 * sizeof(float));
  float*    qf     = (float*)carve((size_t)NN * 128 * sizeof(float));
  float*    skb_   = (float*)carve((size_t)NN * 128 * sizeof(float));
  unsigned* kvb    = (unsigned*)carve((size_t)NN * 128 * sizeof(unsigned));
  unsigned* eab    = (unsigned*)carve((size_t)NE * 8 * sizeof(unsigned));
  float*    qe     = (float*)carve((size_t)NN * 32 * sizeof(float));
  float*    ewT    = (float*)carve(2048 * sizeof(float));
  float*    attn   = (float*)carve((size_t)NN * 128 * sizeof(float));
  unsigned short* xbh = (unsigned short*)carve((size_t)NN * FIN * sizeof(unsigned short));
  unsigned short* xbl = (unsigned short*)carve((size_t)NN * FIN * sizeof(unsigned short));
  unsigned short* hbh = (unsigned short*)carve((size_t)NN * 64 * sizeof(unsigned short));
  unsigned short* hbl = (unsigned short*)carve((size_t)NN * 64 * sizeof(unsigned short));
  float*    h2     = (float*)carve((size_t)NN * 64 * sizeof(float));
  float*    bn_acc = (float*)carve(128 * sizeof(float));
  float*    ss     = (float*)carve(128 * sizeof(float));
  float*    gsum   = (float*)carve((size_t)NG * 64 * sizeof(float));
  unsigned* gmax   = (unsigned*)carve((size_t)NG * 64 * sizeof(unsigned));
  int*      deg    = (int*)carve(NN * sizeof(int));
  int*      row_ptr= (int*)carve((NN + 1) * sizeof(int));
  int*      eid    = (int*)carve((size_t)NE * sizeof(int));
  int*      src_s  = (int*)carve((size_t)NE * sizeof(int));
  int*      counts = (int*)carve(NG * sizeof(int));
  int*      starts = (int*)carve((NG + 1) * sizeof(int));
  int*      bsums  = (int*)carve(256 * sizeof(int));

  hipMemsetAsync(d_out, 0, (size_t)out_size * sizeof(float), stream);
  hipMemsetAsync(deg, 0, NN * sizeof(int), stream);
  hist_k<<<(NE + 255) / 256, 256, 0, stream>>>(dsts, deg);
  bounds_k<<<(NN + 255) / 256, 256, 0, stream>>>(batch, starts);
  counts_from_starts_k<<<1, 64, 0, stream>>>(starts, counts);
  scan1_k<<<SCAN_B, 256, 0, stream>>>(deg, bsums);
  scan2_k<<<1, 256, 0, stream>>>(bsums);
  scan3_k<<<SCAN_B, 256, 0, stream>>>(deg, bsums, row_ptr);
  cursor_k<<<(NN + 255) / 256, 256, 0, stream>>>(row_ptr, deg);   // reuse deg as cursor
  scatter_k<<<(NE + 255) / 256, 256, 0, stream>>>(dsts, srcs, deg, eid, src_s);
  pack_ea_k<<<(NE * 2 + 255) / 256, 256, 0, stream>>>(ea, eid, eab);
  tobf_k<<<(NN * FIN + 255) / 256, 256, 0, stream>>>(x, xbh, xbl, NN * FIN);

  const unsigned short* hin_h = xbh;
  const unsigned short* hin_l = xbl;
  for (int L = 0; L < 4; L++){
    int D = (L == 0) ? FIN : EMB;
    const float *qw,*qb,*kw,*kb,*vw,*vb,*eww,*skw,*skb,*bww,*tw,*tb,*bnw,*bnb;
    if (L == 0){
      qw=c1_qw; qb=c1_qb; kw=c1_kw; kb=c1_kb; vw=c1_vw; vb=c1_vb;
      eww=c1_ew; skw=c1_skw; skb=c1_skb; bww=c1_bw; tw=c1_tw; tb=c1_tb;
      bnw=c1_bnw; bnb=c1_bnb;
    } else {
      int i = L - 1;
      qw = L_qw + (size_t)i * HCC * EMB;  qb = L_qb + (size_t)i * HCC;
      kw = L_kw + (size_t)i * HCC * EMB;  kb = L_kb + (size_t)i * HCC;
      vw = L_vw + (size_t)i * HCC * EMB;  vb = L_vb + (size_t)i * HCC;
      eww= L_ew + (size_t)i * HCC * EDIM;
      skw= L_skw+ (size_t)i * HCC * EMB;  skb= L_skb+ (size_t)i * HCC;
      bww= L_bw + (size_t)i * 3 * HCC;
      tw = L_tw + (size_t)i * EMB * HCC;  tb = L_tb + (size_t)i * EMB;
      bnw= L_bnw+ (size_t)i * EMB;        bnb= L_bnb+ (size_t)i * EMB;
    }
    pack_k<<<(512 * D + 255) / 256, 256, 0, stream>>>(qw, kw, vw, skw, qb, kb, vb, skb, Wh, Wl, bp, D);
    int gb = (NN + 63) / 64;
    if (D == 128) gemm2_k<128><<<gb, 256, 0, stream>>>(hin_h, hin_l, Wh, Wl, bp, qf, kvb, skb_);
    else          gemm2_k<64><<<gb, 256, 0, stream>>>(hin_h, hin_l, Wh, Wl, bp, qf, kvb, skb_);
    qe_k<<<(NN + 7) / 8, 256, 0, stream>>>(qf, eww, qe);
    ewt_k<<<8, 256, 0, stream>>>(eww, ewT);
    edge_k<<<(NN * 2 * 64 + 255) / 256, 256, 0, stream>>>(qf, kvb, (const unsigned short*)eab, qe, ewT, row_ptr, src_s, attn);
    hipMemsetAsync(bn_acc, 0, 128 * sizeof(float), stream);
    combine_k<<<(NN + 15) / 16, 256, 0, stream>>>(attn, skb_, bww, tw, tb, h2, bn_acc);
    bn_final_k<<<1, 64, 0, stream>>>(bn_acc, bnw, bnb, ss);
    if (L > 0) hipMemsetAsync(gsum, 0, 2 * NG * 64 * sizeof(float), stream);
    bn_apply_k<<<256, 256, 0, stream>>>(h2, ss, batch, hbh, hbl, gsum, gmax, (L > 0) ? 1 : 0);
    if (L > 0) pool_final_k<<<(NG * 64 + 255) / 256, 256, 0, stream>>>(gsum, gmax, counts, (float*)d_out);
    hin_h = hbh; hin_l = hbl;
  }
}

// Round 9
// 1408.012 us; speedup vs baseline: 1.8685x; 1.0176x over previous
//
#include <hip/hip_runtime.h>

#define NN 50000
#define NE 800000
#define FIN 128
#define EDIM 16
#define EMB 64
#define NH 2
#define NLAYERS 3
#define NG 64
#define HCC 128
#define INV_SQRT_D 0.125f
#define EPS_BN 1e-5f
#define SCAN_B 196   // ceil(NN/256)
#define SCALE_L2E 0.18033688f   // 0.125 * log2(e)

typedef __attribute__((ext_vector_type(8))) short bf16x8;
typedef __attribute__((ext_vector_type(4))) float f32x4;

__device__ __forceinline__ unsigned encf(float f){
  unsigned u = __float_as_uint(f);
  return (u & 0x80000000u) ? ~u : (u | 0x80000000u);
}
__device__ __forceinline__ float decf(unsigned e){
  unsigned u = (e & 0x80000000u) ? (e ^ 0x80000000u) : ~e;
  return __uint_as_float(u);
}
__device__ __forceinline__ unsigned f2bf(float x){   // RNE bf16, returned in low 16
  unsigned u = __float_as_uint(x);
  return (u + 0x7fffu + ((u >> 16) & 1u)) >> 16;
}
// split fp32 -> hi + lo bf16 (a ~= hi + lo, |lo| <= 2^-9 |a|)
__device__ __forceinline__ void f2bf_split(float x, unsigned short* hi, unsigned short* lo){
  unsigned h = f2bf(x);
  float hf = __uint_as_float(h << 16);
  *hi = (unsigned short)h;
  *lo = (unsigned short)f2bf(x - hf);
}

__global__ void hist_k(const int* __restrict__ dst, int* __restrict__ deg){
  int i = blockIdx.x * 256 + threadIdx.x;
  if (i < NE) atomicAdd(&deg[dst[i]], 1);
}

// batch_index is sorted: group starts via boundary detection, no atomics.
__global__ void bounds_k(const int* __restrict__ batch, int* __restrict__ starts){
  int i = blockIdx.x * 256 + threadIdx.x;
  if (i >= NN) return;
  int g = batch[i];
  int gp = (i == 0) ? -1 : batch[i - 1];
  for (int gg = gp + 1; gg <= g; gg++) starts[gg] = i;
  if (i == NN - 1){
    for (int gg = g + 1; gg <= NG; gg++) starts[gg] = NN;
  }
}

__global__ void counts_from_starts_k(const int* __restrict__ starts, int* __restrict__ counts){
  int g = threadIdx.x;
  if (g < NG) counts[g] = starts[g + 1] - starts[g];
}

__global__ void scan1_k(const int* __restrict__ deg, int* __restrict__ bsums){
  __shared__ int lds[256];
  int b = blockIdx.x, t = threadIdx.x;
  int idx = b * 256 + t;
  lds[t] = (idx < NN) ? deg[idx] : 0;
  __syncthreads();
  for (int off = 128; off >= 1; off >>= 1){
    if (t < off) lds[t] += lds[t + off];
    __syncthreads();
  }
  if (t == 0) bsums[b] = lds[0];
}

__global__ void scan2_k(int* __restrict__ bsums){
  __shared__ int lds[256];
  int t = threadIdx.x;
  int v = (t < SCAN_B) ? bsums[t] : 0;
  int x = v;
  lds[t] = x;
  __syncthreads();
  for (int off = 1; off < 256; off <<= 1){
    int y = (t >= off) ? lds[t - off] : 0;
    __syncthreads();
    x += y;
    lds[t] = x;
    __syncthreads();
  }
  if (t < SCAN_B) bsums[t] = x - v;   // exclusive
}

__global__ void scan3_k(const int* __restrict__ deg, const int* __restrict__ bsums,
                        int* __restrict__ row_ptr){
  __shared__ int lds[256];
  int b = blockIdx.x, t = threadIdx.x;
  int idx = b * 256 + t;
  int v = (idx < NN) ? deg[idx] : 0;
  int x = v;
  lds[t] = x;
  __syncthreads();
  for (int off = 1; off < 256; off <<= 1){
    int y = (t >= off) ? lds[t - off] : 0;
    __syncthreads();
    x += y;
    lds[t] = x;
    __syncthreads();
  }
  if (idx <= NN) row_ptr[idx] = bsums[b] + x - v;
}

__global__ void cursor_k(const int* __restrict__ row_ptr, int* __restrict__ cur){
  int i = blockIdx.x * 256 + threadIdx.x;
  if (i < NN) cur[i] = row_ptr[i];
}

__global__ void scatter_k(const int* __restrict__ dst, const int* __restrict__ src,
                          int* __restrict__ cur, int* __restrict__ eid,
                          int* __restrict__ src_s){
  int i = blockIdx.x * 256 + threadIdx.x;
  if (i < NE){
    int p = atomicAdd(&cur[dst[i]], 1);
    eid[p] = i;
    src_s[p] = src[i];
  }
}

// edge_attr -> bf16, reordered into CSR position order. thread = (p, half-row)
__global__ void pack_ea_k(const float* __restrict__ ea, const int* __restrict__ eid,
                          unsigned* __restrict__ eab){
  int i = blockIdx.x * 256 + threadIdx.x;
  if (i >= NE * 2) return;
  int p = i >> 1, half = i & 1;
  int e = eid[p];
  const float* s = ea + (size_t)e * 16 + half * 8;
  float4 a = *(const float4*)(s);
  float4 b = *(const float4*)(s + 4);
  uint4 o;
  o.x = f2bf(a.x) | (f2bf(a.y) << 16);
  o.y = f2bf(a.z) | (f2bf(a.w) << 16);
  o.z = f2bf(b.x) | (f2bf(b.y) << 16);
  o.w = f2bf(b.z) | (f2bf(b.w) << 16);
  ((uint4*)eab)[(size_t)p * 2 + half] = o;
}

// fp32 -> split bf16 (x once per call)
__global__ void tobf_k(const float* __restrict__ in, unsigned short* __restrict__ hi,
                       unsigned short* __restrict__ lo, int n){
  int i = blockIdx.x * 256 + threadIdx.x;
  if (i < n) f2bf_split(in[i], &hi[i], &lo[i]);
}

// pack q/k/v/skip weights into split bf16 Wp_hi/Wp_lo[512][D] + fp32 bias bp[512]
__global__ void pack_k(const float* __restrict__ qw, const float* __restrict__ kw,
                       const float* __restrict__ vw, const float* __restrict__ skw,
                       const float* __restrict__ qb, const float* __restrict__ kb,
                       const float* __restrict__ vb, const float* __restrict__ skb,
                       unsigned short* __restrict__ Wh, unsigned short* __restrict__ Wl,
                       float* __restrict__ bp, int D){
  int i = blockIdx.x * 256 + threadIdx.x;
  if (i < 512 * D){
    int c = i / D, d = i - c * D;
    const float* w = (c < 128) ? qw : (c < 256) ? kw : (c < 384) ? vw : skw;
    f2bf_split(w[(c & 127) * D + d], &Wh[i], &Wl[i]);
  }
  if (i < 512){
    const float* b = (i < 128) ? qb : (i < 256) ? kb : (i < 384) ? vb : skb;
    bp[i] = b[i & 127];
  }
}

// qe[n, h, d] = (sum_c q[n,h,c] * ew[h*64+c, d]) * SCALE_L2E
__global__ __launch_bounds__(256) void qe_k(const float* __restrict__ qf,
    const float* __restrict__ ew, float* __restrict__ qe){
  __shared__ float ews[2048];
  int t = threadIdx.x;
  for (int i = t; i < 2048; i += 256) ews[i] = ew[i];
  __syncthreads();
  int g = t >> 5;            // node within block (8 nodes/block)
  int hd = t & 31;           // h*16 + d
  int h = hd >> 4, d = hd & 15;
  int n = blockIdx.x * 8 + g;
  if (n >= NN) return;
  const float* qp = qf + (size_t)n * 128 + h * 64;
  float s = 0.f;
  #pragma unroll 8
  for (int c = 0; c < 64; c++)
    s += qp[c] * ews[(h * 64 + c) * 16 + d];
  qe[(size_t)n * 32 + hd] = s * SCALE_L2E;
}

// ewT[h][d][c] = ew[h*64+c][d]  (transposed, for edge_k epilogue float4 loads)
__global__ void ewt_k(const float* __restrict__ ew, float* __restrict__ ewT){
  int i = blockIdx.x * 256 + threadIdx.x;
  if (i < 2048){
    int c = i >> 4, d = i & 15;          // c = h*64 + ch
    ewT[((c >> 6) * 16 + d) * 64 + (c & 63)] = ew[i];
  }
}

// Fused qkvs GEMM, 4-way column-split for occupancy:
// grid = (ceil(NN/64), 4). Each block: 64 rows x 2 column-blocks.
//   part0: q cols 0..127 -> qf ; part1: k0+v0 -> kvb ch 0..63
//   part2: k1+v1 -> kvb ch 64..127 ; part3: skip -> sk
// Split-bf16: C ~= Ah*Wh + Al*Wh + Ah*Wl.
template<int D>
__global__ __launch_bounds__(256) void gemm3_k(const unsigned short* __restrict__ Ah,
                                               const unsigned short* __restrict__ Al,
                                               const unsigned short* __restrict__ Wh,
                                               const unsigned short* __restrict__ Wl,
                                               const float* __restrict__ bp,
                                               float* __restrict__ qf,
                                               unsigned* __restrict__ kvb,
                                               float* __restrict__ sk){
  int t = threadIdx.x;
  int w = t >> 6, lane = t & 63;
  int brow = blockIdx.x * 64 + w * 16;
  int part = blockIdx.y;
  int r = lane & 15, kg = lane >> 4;
  int arow = brow + r; if (arow >= NN) arow = NN - 1;
  const int NK = D / 32;
  bf16x8 avh[NK], avl[NK];
  size_t aoff = (size_t)arow * D + kg * 8;
  #pragma unroll
  for (int kk = 0; kk < NK; kk++){
    avh[kk] = *(const bf16x8*)(Ah + aoff + kk * 32);
    avl[kk] = *(const bf16x8*)(Al + aoff + kk * 32);
  }
  int cb0 = (part == 0) ? 0 : (part == 1) ? 2 : (part == 2) ? 3 : 6;
  int cb1 = (part == 0) ? 1 : (part == 1) ? 4 : (part == 2) ? 5 : 7;
  f32x4 acc0[4], acc1[4];
  #pragma unroll
  for (int nf = 0; nf < 4; nf++){
    acc0[nf] = (f32x4){0.f,0.f,0.f,0.f};
    acc1[nf] = (f32x4){0.f,0.f,0.f,0.f};
  }
  #pragma unroll
  for (int kk = 0; kk < NK; kk++){
    size_t w0 = (size_t)(cb0 * 64 + r) * D + kg * 8 + kk * 32;
    size_t w1 = (size_t)(cb1 * 64 + r) * D + kg * 8 + kk * 32;
    #pragma unroll
    for (int nf = 0; nf < 4; nf++){
      bf16x8 bh0 = *(const bf16x8*)(Wh + w0 + (size_t)nf * 16 * D);
      bf16x8 bl0 = *(const bf16x8*)(Wl + w0 + (size_t)nf * 16 * D);
      bf16x8 bh1 = *(const bf16x8*)(Wh + w1 + (size_t)nf * 16 * D);
      bf16x8 bl1 = *(const bf16x8*)(Wl + w1 + (size_t)nf * 16 * D);
      acc0[nf] = __builtin_amdgcn_mfma_f32_16x16x32_bf16(avh[kk], bh0, acc0[nf], 0, 0, 0);
      acc1[nf] = __builtin_amdgcn_mfma_f32_16x16x32_bf16(avh[kk], bh1, acc1[nf], 0, 0, 0);
      acc0[nf] = __builtin_amdgcn_mfma_f32_16x16x32_bf16(avl[kk], bh0, acc0[nf], 0, 0, 0);
      acc1[nf] = __builtin_amdgcn_mfma_f32_16x16x32_bf16(avl[kk], bh1, acc1[nf], 0, 0, 0);
      acc0[nf] = __builtin_amdgcn_mfma_f32_16x16x32_bf16(avh[kk], bl0, acc0[nf], 0, 0, 0);
      acc1[nf] = __builtin_amdgcn_mfma_f32_16x16x32_bf16(avh[kk], bl1, acc1[nf], 0, 0, 0);
    }
  }
  int rowbase = brow + kg * 4;
  if (part == 0){
    #pragma unroll
    for (int nf = 0; nf < 4; nf++){
      int ch0 = nf * 16 + r, ch1 = 64 + nf * 16 + r;
      float b0 = bp[ch0], b1 = bp[ch1];
      #pragma unroll
      for (int j = 0; j < 4; j++){
        int row = rowbase + j;
        if (row < NN){
          qf[(size_t)row * 128 + ch0] = acc0[nf][j] + b0;
          qf[(size_t)row * 128 + ch1] = acc1[nf][j] + b1;
        }
      }
    }
  } else if (part == 3){
    #pragma unroll
    for (int nf = 0; nf < 4; nf++){
      int ch0 = nf * 16 + r, ch1 = 64 + nf * 16 + r;
      float b0 = bp[384 + ch0], b1 = bp[384 + ch1];
      #pragma unroll
      for (int j = 0; j < 4; j++){
        int row = rowbase + j;
        if (row < NN){
          sk[(size_t)row * 128 + ch0] = acc0[nf][j] + b0;
          sk[(size_t)row * 128 + ch1] = acc1[nf][j] + b1;
        }
      }
    }
  } else {
    int chbase = (part - 1) * 64;
    #pragma unroll
    for (int nf = 0; nf < 4; nf++){
      int ch = chbase + nf * 16 + r;
      float bk = bp[cb0 * 64 + nf * 16 + r];
      float bv = bp[cb1 * 64 + nf * 16 + r];
      #pragma unroll
      for (int j = 0; j < 4; j++){
        int row = rowbase + j;
        if (row < NN){
          float kk4 = acc0[nf][j] + bk;
          float vv = acc1[nf][j] + bv;
          kvb[(size_t)row * 128 + ch] = f2bf(kk4) | (f2bf(vv) << 16);
        }
      }
    }
  }
}

// One wave per (node, head). 4 edges per wave iteration: 16 lanes per edge
// (grp = lane>>4 picks the edge, l = lane&15 picks 4 channels 4l..4l+3).
__global__ __launch_bounds__(256) void edge_k(const float* __restrict__ qf,
    const unsigned* __restrict__ kvb, const unsigned short* __restrict__ eab_us,
    const float* __restrict__ qe, const float* __restrict__ ewT,
    const int* __restrict__ row_ptr, const int* __restrict__ src_s,
    float* __restrict__ attn){
  int wv = (blockIdx.x * 256 + threadIdx.x) >> 6;
  if (wv >= NN * 2) return;
  int lane = threadIdx.x & 63;
  int n = wv >> 1, h = wv & 1;
  int grp = lane >> 4, l = lane & 15;
  float4 qv = *(const float4*)(qf + (size_t)n * 128 + h * 64 + 4 * l);
  float q0 = qv.x * SCALE_L2E, q1 = qv.y * SCALE_L2E;
  float q2 = qv.z * SCALE_L2E, q3 = qv.w * SCALE_L2E;
  float qel = qe[(size_t)n * 32 + h * 16 + l];
  int beg = row_ptr[n], end = row_ptr[n + 1];
  int nb = end - beg;
  float a0 = 0.f, a1 = 0.f, a2 = 0.f, a3 = 0.f, den = 0.f, tl = 0.f;
  int hoff = h * 64 + 4 * l;
  for (int cb = 0; cb < nb; cb += 64){
    int sv = (cb + lane < nb) ? src_s[beg + cb + lane] : 0;
    int m = min(64, nb - cb);
    for (int u = 0; u < m; u += 8){
      int eA = u + grp, eB = u + 4 + grp;        // both < 64 (u <= 56)
      int sA = __shfl(sv, eA);
      int sB = __shfl(sv, eB);
      uint4 kvA = *(const uint4*)(kvb + (size_t)sA * 128 + hoff);
      uint4 kvB = *(const uint4*)(kvb + (size_t)sB * 128 + hoff);
      size_t gA = (size_t)(beg + cb + eA); if (gA >= NE) gA = NE - 1;
      size_t gB = (size_t)(beg + cb + eB); if (gB >= NE) gB = NE - 1;
      unsigned short eaAu = eab_us[gA * 16 + l];
      unsigned short eaBu = eab_us[gB * 16 + l];
      {
        float eaf = __uint_as_float((unsigned)eaAu << 16);
        float k0 = __uint_as_float(kvA.x << 16), v0 = __uint_as_float(kvA.x & 0xffff0000u);
        float k1 = __uint_as_float(kvA.y << 16), v1 = __uint_as_float(kvA.y & 0xffff0000u);
        float k2 = __uint_as_float(kvA.z << 16), v2 = __uint_as_float(kvA.z & 0xffff0000u);
        float k3 = __uint_as_float(kvA.w << 16), v3 = __uint_as_float(kvA.w & 0xffff0000u);
        float p = fmaf(q0, k0, fmaf(q1, k1, fmaf(q2, k2, fmaf(q3, k3, qel * eaf))));
        p += __shfl_xor(p, 1); p += __shfl_xor(p, 2);
        p += __shfl_xor(p, 4); p += __shfl_xor(p, 8);
        float w = exp2f(p);
        if (eA >= m) w = 0.f;
        a0 = fmaf(v0, w, a0); a1 = fmaf(v1, w, a1);
        a2 = fmaf(v2, w, a2); a3 = fmaf(v3, w, a3);
        den += w; tl = fmaf(eaf, w, tl);
      }
      {
        float eaf = __uint_as_float((unsigned)eaBu << 16);
        float k0 = __uint_as_float(kvB.x << 16), v0 = __uint_as_float(kvB.x & 0xffff0000u);
        float k1 = __uint_as_float(kvB.y << 16), v1 = __uint_as_float(kvB.y & 0xffff0000u);
        float k2 = __uint_as_float(kvB.z << 16), v2 = __uint_as_float(kvB.z & 0xffff0000u);
        float k3 = __uint_as_float(kvB.w << 16), v3 = __uint_as_float(kvB.w & 0xffff0000u);
        float p = fmaf(q0, k0, fmaf(q1, k1, fmaf(q2, k2, fmaf(q3, k3, qel * eaf))));
        p += __shfl_xor(p, 1); p += __shfl_xor(p, 2);
        p += __shfl_xor(p, 4); p += __shfl_xor(p, 8);
        float w = exp2f(p);
        if (eB >= m) w = 0.f;
        a0 = fmaf(v0, w, a0); a1 = fmaf(v1, w, a1);
        a2 = fmaf(v2, w, a2); a3 = fmaf(v3, w, a3);
        den += w; tl = fmaf(eaf, w, tl);
      }
    }
  }
  a0 += __shfl_xor(a0, 16); a0 += __shfl_xor(a0, 32);
  a1 += __shfl_xor(a1, 16); a1 += __shfl_xor(a1, 32);
  a2 += __shfl_xor(a2, 16); a2 += __shfl_xor(a2, 32);
  a3 += __shfl_xor(a3, 16); a3 += __shfl_xor(a3, 32);
  den += __shfl_xor(den, 16); den += __shfl_xor(den, 32);
  tl  += __shfl_xor(tl, 16);  tl  += __shfl_xor(tl, 32);
  float e0 = 0.f, e1 = 0.f, e2 = 0.f, e3 = 0.f;
  const float* ewp = ewT + (size_t)h * 16 * 64 + 4 * l;
  #pragma unroll
  for (int d = 0; d < 16; d++){
    float td = __shfl(tl, d);
    float4 w4 = *(const float4*)(ewp + d * 64);
    e0 = fmaf(w4.x, td, e0); e1 = fmaf(w4.y, td, e1);
    e2 = fmaf(w4.z, td, e2); e3 = fmaf(w4.w, td, e3);
  }
  float inv = den > 0.f ? 1.f / den : 0.f;
  float4 o;
  o.x = (a0 + e0) * inv; o.y = (a1 + e1) * inv;
  o.z = (a2 + e2) * inv; o.w = (a3 + e3) * inv;
  *(float4*)(attn + (size_t)n * 128 + h * 64 + 4 * l) = o;
}

// beta-gate combine + [128->64] proj + leaky relu + BN partial sums.
__global__ __launch_bounds__(256) void combine_k(const float* __restrict__ attn,
    const float* __restrict__ sk, const float* __restrict__ bw,
    const float* __restrict__ tw, const float* __restrict__ tb,
    float* __restrict__ h2, float* __restrict__ bn_acc){
  __shared__ float twT[128][65];
  __shared__ float hcs[4][128];
  __shared__ float bsum[64], bsq[64];
  int t = threadIdx.x;
  int lane = t & 63, wv = t >> 6;
  for (int i = t; i < 64 * 128; i += 256){
    int j = i >> 7, k = i & 127;
    twT[k][j] = tw[i];
  }
  if (t < 64){ bsum[t] = 0.f; bsq[t] = 0.f; }
  __syncthreads();
  float bw0 = bw[lane],       bw1 = bw[64 + lane];
  float bwr0 = bw[128 + lane], bwr1 = bw[192 + lane];
  float bwd0 = bw[256 + lane], bwd1 = bw[320 + lane];
  float tbv = tb[lane];
  float rs = 0.f, rq = 0.f;
  int base_node = blockIdx.x * 16 + wv * 4;
  for (int it = 0; it < 4; it++){
    int n = base_node + it;
    bool valid = n < NN;
    float o0 = 0.f, o1 = 0.f, r0 = 0.f, r1 = 0.f;
    if (valid){
      o0 = attn[(size_t)n * 128 + lane];
      o1 = attn[(size_t)n * 128 + 64 + lane];
      r0 = sk[(size_t)n * 128 + lane];
      r1 = sk[(size_t)n * 128 + 64 + lane];
    }
    float p = o0 * bw0 + o1 * bw1 + r0 * bwr0 + r1 * bwr1 + (o0 - r0) * bwd0 + (o1 - r1) * bwd1;
    #pragma unroll
    for (int off = 32; off >= 1; off >>= 1) p += __shfl_xor(p, off);
    float beta = 1.f / (1.f + __expf(-p));
    float hc0 = beta * r0 + (1.f - beta) * o0;
    float hc1 = beta * r1 + (1.f - beta) * o1;
    hcs[wv][lane] = hc0;
    hcs[wv][64 + lane] = hc1;
    __syncthreads();
    float s = tbv;
    #pragma unroll 8
    for (int k = 0; k < 128; k++) s += hcs[wv][k] * twT[k][lane];
    __syncthreads();
    if (valid){
      float hv = s > 0.f ? s : 0.01f * s;
      h2[(size_t)n * 64 + lane] = hv;
      rs += hv; rq += hv * hv;
    }
  }
  atomicAdd(&bsum[lane], rs);
  atomicAdd(&bsq[lane], rq);
  __syncthreads();
  if (t < 64){
    atomicAdd(&bn_acc[t], bsum[t]);
    atomicAdd(&bn_acc[64 + t], bsq[t]);
  }
}

__global__ void bn_final_k(const float* __restrict__ bn_acc, const float* __restrict__ bnw,
                           const float* __restrict__ bnb, float* __restrict__ ss){
  int j = threadIdx.x;
  if (j < 64){
    float m = bn_acc[j] / (float)NN;
    float v = bn_acc[64 + j] / (float)NN - m * m;
    float sc = bnw[j] * rsqrtf(v + EPS_BN);
    ss[j] = sc;
    ss[64 + j] = bnb[j] - m * sc;
  }
}

// BN apply -> split bf16 h (next-layer GEMM input) + pooled max/sum (sorted batch)
__global__ __launch_bounds__(256) void bn_apply_k(const float* __restrict__ h2,
    const float* __restrict__ ss, const int* __restrict__ batch,
    unsigned short* __restrict__ hbh, unsigned short* __restrict__ hbl,
    float* __restrict__ gsum, unsigned* __restrict__ gmax,
    int do_pool){
  int wid = (blockIdx.x * 256 + threadIdx.x) >> 6;
  int lane = threadIdx.x & 63;
  const int CH = (NN + 1023) / 1024;
  int start = wid * CH;
  int end = start + CH; if (end > NN) end = NN;
  float sc = ss[lane], sh = ss[64 + lane];
  int curg = -1; float lmax = 0.f, lsum = 0.f;
  for (int n = start; n < end; n++){
    float v = h2[(size_t)n * 64 + lane] * sc + sh;
    f2bf_split(v, &hbh[(size_t)n * 64 + lane], &hbl[(size_t)n * 64 + lane]);
    if (do_pool){
      int g = batch[n];
      if (g != curg){
        if (curg >= 0){
          atomicAdd(&gsum[curg * 64 + lane], lsum);
          atomicMax(&gmax[curg * 64 + lane], encf(lmax));
        }
        curg = g; lmax = v; lsum = v;
      } else {
        lmax = fmaxf(lmax, v); lsum += v;
      }
    }
  }
  if (do_pool && curg >= 0){
    atomicAdd(&gsum[curg * 64 + lane], lsum);
    atomicMax(&gmax[curg * 64 + lane], encf(lmax));
  }
}

__global__ void pool_final_k(const float* __restrict__ gsum, const unsigned* __restrict__ gmax,
                             const int* __restrict__ counts, float* __restrict__ gr){
  int i = blockIdx.x * 256 + threadIdx.x;
  if (i < NG * 64){
    int g = i >> 6, j = i & 63;
    unsigned e = gmax[i];
    float mx = e ? decf(e) : 0.f;
    int c = counts[g]; if (c < 1) c = 1;
    gr[g * 128 + j]       += mx;
    gr[g * 128 + 64 + j]  += gsum[i] / (float)c;
  }
}

extern "C" void kernel_launch(void* const* d_in, const int* in_sizes, int n_in,
                              void* d_out, int out_size, void* d_ws, size_t ws_size,
                              hipStream_t stream){
  const float* x     = (const float*)d_in[0];
  const float* ea    = (const float*)d_in[1];
  const int*   eidx  = (const int*)d_in[2];
  const int*   batch = (const int*)d_in[3];
  const float* c1_qw = (const float*)d_in[4];
  const float* c1_qb = (const float*)d_in[5];
  const float* c1_kw = (const float*)d_in[6];
  const float* c1_kb = (const float*)d_in[7];
  const float* c1_vw = (const float*)d_in[8];
  const float* c1_vb = (const float*)d_in[9];
  const float* c1_ew = (const float*)d_in[10];
  const float* c1_skw= (const float*)d_in[11];
  const float* c1_skb= (const float*)d_in[12];
  const float* c1_bw = (const float*)d_in[13];
  const float* c1_tw = (const float*)d_in[14];
  const float* c1_tb = (const float*)d_in[15];
  const float* c1_bnw= (const float*)d_in[16];
  const float* c1_bnb= (const float*)d_in[17];
  const float* L_qw  = (const float*)d_in[18];
  const float* L_qb  = (const float*)d_in[19];
  const float* L_kw  = (const float*)d_in[20];
  const float* L_kb  = (const float*)d_in[21];
  const float* L_vw  = (const float*)d_in[22];
  const float* L_vb  = (const float*)d_in[23];
  const float* L_ew  = (const float*)d_in[24];
  const float* L_skw = (const float*)d_in[25];
  const float* L_skb = (const float*)d_in[26];
  const float* L_bw  = (const float*)d_in[27];
  const float* L_tw  = (const float*)d_in[28];
  const float* L_tb  = (const float*)d_in[29];
  const float* L_bnw = (const float*)d_in[30];
  const float* L_bnb = (const float*)d_in[31];
  const int* srcs = eidx;
  const int* dsts = eidx + NE;

  char* p = (char*)d_ws;
  auto carve = [&](size_t bytes) -> void* {
    void* r = (void*)p;
    p += (bytes + 255) & ~(size_t)255;
    return r;
  };
  unsigned short* Wh = (unsigned short*)carve(512 * 128 * sizeof(unsigned short));
  unsigned short* Wl = (unsigned short*)carve(512 * 128 * sizeof(unsigned short));
  float*    bp     = (float*)carve(512 * sizeof(float));
  float*    qf     = (float*)carve((size_t)NN * 128 * sizeof(float));
  float*    skb_   = (float*)carve((size_t)NN * 128 * sizeof(float));
  unsigned* kvb    = (unsigned*)carve((size_t)NN * 128 * sizeof(unsigned));
  unsigned* eab    = (unsigned*)carve((size_t)NE * 8 * sizeof(unsigned));
  float*    qe     = (float*)carve((size_t)NN * 32 * sizeof(float));
  float*    ewT    = (float*)carve(2048 * sizeof(float));
  float*    attn   = (float*)carve((size_t)NN * 128 * sizeof(float));
  unsigned short* xbh = (unsigned short*)carve((size_t)NN * FIN * sizeof(unsigned short));
  unsigned short* xbl = (unsigned short*)carve((size_t)NN * FIN * sizeof(unsigned short));
  unsigned short* hbh = (unsigned short*)carve((size_t)NN * 64 * sizeof(unsigned short));
  unsigned short* hbl = (unsigned short*)carve((size_t)NN * 64 * sizeof(unsigned short));
  float*    h2     = (float*)carve((size_t)NN * 64 * sizeof(float));
  float*    bn_acc = (float*)carve(128 * sizeof(float));
  float*    ss     = (float*)carve(128 * sizeof(float));
  float*    gsum   = (float*)carve((size_t)NG * 64 * sizeof(float));
  unsigned* gmax   = (unsigned*)carve((size_t)NG * 64 * sizeof(unsigned));
  int*      deg    = (int*)carve(NN * sizeof(int));
  int*      row_ptr= (int*)carve((NN + 1) * sizeof(int));
  int*      eid    = (int*)carve((size_t)NE * sizeof(int));
  int*      src_s  = (int*)carve((size_t)NE * sizeof(int));
  int*      counts = (int*)carve(NG * sizeof(int));
  int*      starts = (int*)carve((NG + 1) * sizeof(int));
  int*      bsums  = (int*)carve(256 * sizeof(int));

  hipMemsetAsync(d_out, 0, (size_t)out_size * sizeof(float), stream);
  hipMemsetAsync(deg, 0, NN * sizeof(int), stream);
  hist_k<<<(NE + 255) / 256, 256, 0, stream>>>(dsts, deg);
  bounds_k<<<(NN + 255) / 256, 256, 0, stream>>>(batch, starts);
  counts_from_starts_k<<<1, 64, 0, stream>>>(starts, counts);
  scan1_k<<<SCAN_B, 256, 0, stream>>>(deg, bsums);
  scan2_k<<<1, 256, 0, stream>>>(bsums);
  scan3_k<<<SCAN_B, 256, 0, stream>>>(deg, bsums, row_ptr);
  cursor_k<<<(NN + 255) / 256, 256, 0, stream>>>(row_ptr, deg);   // reuse deg as cursor
  scatter_k<<<(NE + 255) / 256, 256, 0, stream>>>(dsts, srcs, deg, eid, src_s);
  pack_ea_k<<<(NE * 2 + 255) / 256, 256, 0, stream>>>(ea, eid, eab);
  tobf_k<<<(NN * FIN + 255) / 256, 256, 0, stream>>>(x, xbh, xbl, NN * FIN);

  const unsigned short* hin_h = xbh;
  const unsigned short* hin_l = xbl;
  for (int L = 0; L < 4; L++){
    int D = (L == 0) ? FIN : EMB;
    const float *qw,*qb,*kw,*kb,*vw,*vb,*eww,*skw,*skb,*bww,*tw,*tb,*bnw,*bnb;
    if (L == 0){
      qw=c1_qw; qb=c1_qb; kw=c1_kw; kb=c1_kb; vw=c1_vw; vb=c1_vb;
      eww=c1_ew; skw=c1_skw; skb=c1_skb; bww=c1_bw; tw=c1_tw; tb=c1_tb;
      bnw=c1_bnw; bnb=c1_bnb;
    } else {
      int i = L - 1;
      qw = L_qw + (size_t)i * HCC * EMB;  qb = L_qb + (size_t)i * HCC;
      kw = L_kw + (size_t)i * HCC * EMB;  kb = L_kb + (size_t)i * HCC;
      vw = L_vw + (size_t)i * HCC * EMB;  vb = L_vb + (size_t)i * HCC;
      eww= L_ew + (size_t)i * HCC * EDIM;
      skw= L_skw+ (size_t)i * HCC * EMB;  skb= L_skb+ (size_t)i * HCC;
      bww= L_bw + (size_t)i * 3 * HCC;
      tw = L_tw + (size_t)i * EMB * HCC;  tb = L_tb + (size_t)i * EMB;
      bnw= L_bnw+ (size_t)i * EMB;        bnb= L_bnb+ (size_t)i * EMB;
    }
    pack_k<<<(512 * D + 255) / 256, 256, 0, stream>>>(qw, kw, vw, skw, qb, kb, vb, skb, Wh, Wl, bp, D);
    dim3 gg((NN + 63) / 64, 4);
    if (D == 128) gemm3_k<128><<<gg, 256, 0, stream>>>(hin_h, hin_l, Wh, Wl, bp, qf, kvb, skb_);
    else          gemm3_k<64><<<gg, 256, 0, stream>>>(hin_h, hin_l, Wh, Wl, bp, qf, kvb, skb_);
    qe_k<<<(NN + 7) / 8, 256, 0, stream>>>(qf, eww, qe);
    ewt_k<<<8, 256, 0, stream>>>(eww, ewT);
    edge_k<<<(NN * 2 * 64 + 255) / 256, 256, 0, stream>>>(qf, kvb, (const unsigned short*)eab, qe, ewT, row_ptr, src_s, attn);
    hipMemsetAsync(bn_acc, 0, 128 * sizeof(float), stream);
    combine_k<<<(NN + 15) / 16, 256, 0, stream>>>(attn, skb_, bww, tw, tb, h2, bn_acc);
    bn_final_k<<<1, 64, 0, stream>>>(bn_acc, bnw, bnb, ss);
    if (L > 0) hipMemsetAsync(gsum, 0, 2 * NG * 64 * sizeof(float), stream);
    bn_apply_k<<<256, 256, 0, stream>>>(h2, ss, batch, hbh, hbl, gsum, gmax, (L > 0) ? 1 : 0);
    if (L > 0) pool_final_k<<<(NG * 64 + 255) / 256, 256, 0, stream>>>(gsum, gmax, counts, (float*)d_out);
    hin_h = hbh; hin_l = hbl;
  }
}